// Round 1
// baseline (770.655 us; speedup 1.0000x reference)
//
#include <hip/hip_runtime.h>
#include <cstdint>
#include <cstddef>

typedef __bf16 bf16;
typedef __bf16 bf16x4 __attribute__((ext_vector_type(4)));
typedef __bf16 bf16x8 __attribute__((ext_vector_type(8)));
typedef float  f32x4  __attribute__((ext_vector_type(4)));

#define GLD_LDS16(gp, lp) \
  __builtin_amdgcn_global_load_lds((__attribute__((address_space(1))) void*)(gp), \
                                   (__attribute__((address_space(3))) void*)(lp), 16, 0, 0)

__device__ __forceinline__ f32x4 f32x4_zero(){ f32x4 v; v[0]=0.f; v[1]=0.f; v[2]=0.f; v[3]=0.f; return v; }

__device__ __forceinline__ f32x4 mfma16x16x32(bf16x8 a, bf16x8 b, f32x4 c){
  return __builtin_amdgcn_mfma_f32_16x16x32_bf16(a, b, c, 0, 0, 0);
}
// fragment of a 64-col bf16 LDS array (stride 64), LINEAR layout (phaseB kernels)
__device__ __forceinline__ bf16x8 frag64(const bf16* base, int row0, int kk, int lane){
  return *(const bf16x8*)&base[(row0 + (lane&15))*64 + kk*32 + (lane>>4)*8];
}
// fragment of a 64-col bf16 LDS array with XOR bank-swizzle: elem ^= (row&7)<<3
// (16B-granular swizzle; keeps ds_read_b128 16B-aligned; 16-way conflict -> 2-way)
__device__ __forceinline__ bf16x8 fragSwz(const bf16* base, int row0, int kk, int lane){
  const int row = row0 + (lane&15);
  const int off = (kk*32 + (lane>>4)*8) ^ ((row&7)<<3);
  return *(const bf16x8*)&base[row*64 + off];
}
struct bf2 { bf16 h, l; };
__device__ __forceinline__ bf2 split2(float v){
  bf2 r; r.h = (bf16)v; r.l = (bf16)(v - (float)r.h); return r;
}

// ---------------------------------------------------------------- K0a: x -> hi/lo bf16 planes
__global__ __launch_bounds__(256) void k_cvt_x(const float* __restrict__ x,
                                               bf16* __restrict__ xh, bf16* __restrict__ xl, int n4){
  int i = blockIdx.x*256 + threadIdx.x;
  if (i < n4){
    float4 v = ((const float4*)x)[i];
    bf16x4 h, l;
    bf2 t0 = split2(v.x); h[0]=t0.h; l[0]=t0.l;
    bf2 t1 = split2(v.y); h[1]=t1.h; l[1]=t1.l;
    bf2 t2 = split2(v.z); h[2]=t2.h; l[2]=t2.l;
    bf2 t3 = split2(v.w); h[3]=t3.h; l[3]=t3.l;
    ((bf16x4*)xh)[i] = h;
    ((bf16x4*)xl)[i] = l;
  }
}

// ---------------------------------------------------------------- K0b: W[k][n] -> Wt hi/lo [n][k]
__global__ __launch_bounds__(256) void k_transpose_w(const float* __restrict__ W,
                                                     bf16* __restrict__ Wth, bf16* __restrict__ Wtl){
  __shared__ float tile[32][33];
  const int k0 = blockIdx.x*32, n0 = blockIdx.y*32;
  const int r = threadIdx.x >> 3, c4 = (threadIdx.x & 7)*4;
  float4 v = *(const float4*)&W[(size_t)(k0+r)*1024 + n0 + c4];
  tile[r][c4+0]=v.x; tile[r][c4+1]=v.y; tile[r][c4+2]=v.z; tile[r][c4+3]=v.w;
  __syncthreads();
  bf16x4 h, l;
  bf2 t0 = split2(tile[c4+0][r]); h[0]=t0.h; l[0]=t0.l;
  bf2 t1 = split2(tile[c4+1][r]); h[1]=t1.h; l[1]=t1.l;
  bf2 t2 = split2(tile[c4+2][r]); h[2]=t2.h; l[2]=t2.l;
  bf2 t3 = split2(tile[c4+3][r]); h[3]=t3.h; l[3]=t3.l;
  *(bf16x4*)&Wth[(size_t)(n0+r)*1024 + k0 + c4] = h;
  *(bf16x4*)&Wtl[(size_t)(n0+r)*1024 + k0 + c4] = l;
}

// ---------------------------------------------------------------- K0c: Walpha/Wbeta [1024][16] -> [16][1024] fp32
__global__ __launch_bounds__(256) void k_transpose_ab(const float* __restrict__ Wa, const float* __restrict__ Wb,
                                                      float* __restrict__ WaT, float* __restrict__ WbT){
  int p = blockIdx.x*256 + threadIdx.x;
  if (p < 16384){
    int o = p >> 10, k = p & 1023;
    WaT[p] = Wa[k*16 + o];
    WbT[p] = Wb[k*16 + o];
  }
}

// ---------------------------------------------------------------- K1: split-bf16 MFMA GEMM (3-product), K=1024
__global__ __launch_bounds__(256) void k_gemm3(const bf16* __restrict__ Ah, const bf16* __restrict__ Al,
                                               const bf16* __restrict__ Bth, const bf16* __restrict__ Btl,
                                               bf16* __restrict__ Cb, float* __restrict__ Cf){
  __shared__ bf16 Ash[128*32], Asl[128*32];
  __shared__ bf16 Bsh[128*32], Bsl[128*32];
  const int tid = threadIdx.x, lane = tid & 63, w = tid >> 6;
  const int wm = w >> 1, wn = w & 1;
  const size_t m0 = (size_t)blockIdx.x * 128;
  const size_t n0 = (size_t)blockIdx.y * 128;
  f32x4 acc[4][4];
  #pragma unroll
  for (int i=0;i<4;++i)
    #pragma unroll
    for (int j=0;j<4;++j) acc[i][j] = f32x4_zero();

  for (int k0 = 0; k0 < 1024; k0 += 32){
    __syncthreads();
    #pragma unroll
    for (int j = 0; j < 2; ++j){
      const int rbase = 32*w + 16*j;
      const int r = rbase + (lane >> 2);
      const int kk = k0 + (lane & 3)*8;
      GLD_LDS16(&Ah [(m0 + r)*1024 + kk], &Ash[rbase*32]);
      GLD_LDS16(&Al [(m0 + r)*1024 + kk], &Asl[rbase*32]);
      GLD_LDS16(&Bth[(n0 + r)*1024 + kk], &Bsh[rbase*32]);
      GLD_LDS16(&Btl[(n0 + r)*1024 + kk], &Bsl[rbase*32]);
    }
    __syncthreads();
    bf16x8 ah[4], al[4], bh[4], bl[4];
    #pragma unroll
    for (int t=0;t<4;++t){
      ah[t] = *(const bf16x8*)&Ash[(64*wm + 16*t + (lane&15))*32 + (lane>>4)*8];
      al[t] = *(const bf16x8*)&Asl[(64*wm + 16*t + (lane&15))*32 + (lane>>4)*8];
      bh[t] = *(const bf16x8*)&Bsh[(64*wn + 16*t + (lane&15))*32 + (lane>>4)*8];
      bl[t] = *(const bf16x8*)&Bsl[(64*wn + 16*t + (lane&15))*32 + (lane>>4)*8];
    }
    #pragma unroll
    for (int i=0;i<4;++i)
      #pragma unroll
      for (int j=0;j<4;++j){
        f32x4 t = acc[i][j];
        t = mfma16x16x32(ah[i], bh[j], t);
        t = mfma16x16x32(ah[i], bl[j], t);
        t = mfma16x16x32(al[i], bh[j], t);
        acc[i][j] = t;
      }
  }
  #pragma unroll
  for (int i=0;i<4;++i)
    #pragma unroll
    for (int j=0;j<4;++j)
      #pragma unroll
      for (int r=0;r<4;++r){
        size_t row = m0 + 64*wm + 16*i + (lane>>4)*4 + r;
        size_t col = n0 + 64*wn + 16*j + (lane&15);
        float v = acc[i][j][r];
        if (Cf) Cf[row*1024 + col] = v;
        else    Cb[row*1024 + col] = (bf16)v;
      }
}

// ---------------------------------------------------------------- K1b: single-bf16 MFMA GEMM, K=1024
__global__ __launch_bounds__(256) void k_gemm1(const bf16* __restrict__ Ah, const bf16* __restrict__ Bth,
                                               bf16* __restrict__ Cb, float* __restrict__ Cf){
  __shared__ bf16 Ash[128*32];
  __shared__ bf16 Bsh[128*32];
  const int tid = threadIdx.x, lane = tid & 63, w = tid >> 6;
  const int wm = w >> 1, wn = w & 1;
  const size_t m0 = (size_t)blockIdx.x * 128;
  const size_t n0 = (size_t)blockIdx.y * 128;
  f32x4 acc[4][4];
  #pragma unroll
  for (int i=0;i<4;++i)
    #pragma unroll
    for (int j=0;j<4;++j) acc[i][j] = f32x4_zero();

  for (int k0 = 0; k0 < 1024; k0 += 32){
    __syncthreads();
    #pragma unroll
    for (int j = 0; j < 2; ++j){
      const int rbase = 32*w + 16*j;
      const int r = rbase + (lane >> 2);
      const int kk = k0 + (lane & 3)*8;
      GLD_LDS16(&Ah [(m0 + r)*1024 + kk], &Ash[rbase*32]);
      GLD_LDS16(&Bth[(n0 + r)*1024 + kk], &Bsh[rbase*32]);
    }
    __syncthreads();
    bf16x8 ah[4], bh[4];
    #pragma unroll
    for (int t=0;t<4;++t){
      ah[t] = *(const bf16x8*)&Ash[(64*wm + 16*t + (lane&15))*32 + (lane>>4)*8];
      bh[t] = *(const bf16x8*)&Bsh[(64*wn + 16*t + (lane&15))*32 + (lane>>4)*8];
    }
    #pragma unroll
    for (int i=0;i<4;++i)
      #pragma unroll
      for (int j=0;j<4;++j)
        acc[i][j] = mfma16x16x32(ah[i], bh[j], acc[i][j]);
  }
  #pragma unroll
  for (int i=0;i<4;++i)
    #pragma unroll
    for (int j=0;j<4;++j)
      #pragma unroll
      for (int r=0;r<4;++r){
        size_t row = m0 + 64*wm + 16*i + (lane>>4)*4 + r;
        size_t col = n0 + 64*wn + 16*j + (lane&15);
        float v = acc[i][j][r];
        if (Cf) Cf[row*1024 + col] = v;
        else    Cb[row*1024 + col] = (bf16)v;
      }
}

// ---------------------------------------------------------------- K2: dt/alpha/beta projections (fp32)
__global__ __launch_bounds__(256) void k_alphabeta(const float* __restrict__ x,
    const float* __restrict__ WaT, const float* __restrict__ WbT,
    const float* __restrict__ A_log, const float* __restrict__ dt_bias,
    float* __restrict__ logA, float* __restrict__ betap){
  __shared__ float xl[8*1024];
  const int tid = threadIdx.x;
  const size_t base4 = (size_t)blockIdx.x * 2048;
  #pragma unroll
  for (int j=0;j<8;++j)
    ((float4*)xl)[tid + j*256] = ((const float4*)x)[base4 + tid + j*256];
  __syncthreads();
  const int r = tid >> 5, o = tid & 31;
  const float4* wrow = (const float4*)((o < 16) ? (WaT + (size_t)o*1024) : (WbT + (size_t)(o-16)*1024));
  const float4* xr = (const float4*)(xl + r*1024);
  float a0=0,a1=0,a2=0,a3=0;
  for (int j=0;j<256;++j){
    float4 xv = xr[j]; float4 wv = wrow[j];
    a0 += xv.x*wv.x; a1 += xv.y*wv.y; a2 += xv.z*wv.z; a3 += xv.w*wv.w;
  }
  float dot = (a0+a1)+(a2+a3);
  const size_t t = (size_t)blockIdx.x*8 + r;
  if (o < 16){
    float z = dot + dt_bias[o];
    float dt = (z > 20.f) ? z : log1pf(expf(z));
    logA[t*16 + o] = -expf(A_log[o]) * dt;          // log(alpha_t)
  } else {
    betap[t*16 + (o-16)] = 1.f/(1.f + expf(-dot));  // beta_t
  }
}

// ---------------------------------------------------------------- K2b (BIG): in-place fp32 l2norm of q (/8) and k
__global__ __launch_bounds__(256) void k_norm_f32(float* __restrict__ qf, float* __restrict__ kf){
  const size_t p = (size_t)blockIdx.x*256 + threadIdx.x;  // (token,head)
  {
    float4* q4 = (float4*)(qf + p*64);
    float4 v[16]; float s = 0.f;
    #pragma unroll
    for (int i=0;i<16;++i){ v[i]=q4[i]; s += v[i].x*v[i].x + v[i].y*v[i].y + v[i].z*v[i].z + v[i].w*v[i].w; }
    float sc = 0.125f / fmaxf(sqrtf(s), 1e-12f);
    #pragma unroll
    for (int i=0;i<16;++i){ v[i].x*=sc; v[i].y*=sc; v[i].z*=sc; v[i].w*=sc; q4[i]=v[i]; }
  }
  {
    float4* k4 = (float4*)(kf + p*64);
    float4 v[16]; float s = 0.f;
    #pragma unroll
    for (int i=0;i<16;++i){ v[i]=k4[i]; s += v[i].x*v[i].x + v[i].y*v[i].y + v[i].z*v[i].z + v[i].w*v[i].w; }
    float sc = 1.0f / fmaxf(sqrtf(s), 1e-12f);
    #pragma unroll
    for (int i=0;i<16;++i){ v[i].x*=sc; v[i].y*=sc; v[i].z*=sc; v[i].w*=sc; k4[i]=v[i]; }
  }
}

// ---------------------------------------------------------------- K2b (SMALL): in-place bf16 l2norm
__global__ __launch_bounds__(256) void k_norm_b16(bf16* __restrict__ qb, bf16* __restrict__ kb){
  const size_t p = (size_t)blockIdx.x*256 + threadIdx.x;
  bf16* q = qb + p*64;
  bf16* k = kb + p*64;
  bf16x8 qv[8], kv[8];
  float sq = 0.f, sk = 0.f;
  #pragma unroll
  for (int i=0;i<8;++i){
    qv[i] = ((const bf16x8*)q)[i];
    kv[i] = ((const bf16x8*)k)[i];
    #pragma unroll
    for (int j=0;j<8;++j){ float a=(float)qv[i][j]; sq+=a*a; float b=(float)kv[i][j]; sk+=b*b; }
  }
  float scq = 0.125f / fmaxf(sqrtf(sq), 1e-12f);
  float sck = 1.0f   / fmaxf(sqrtf(sk), 1e-12f);
  #pragma unroll
  for (int i=0;i<8;++i){
    bf16x8 oq, ok;
    #pragma unroll
    for (int j=0;j<8;++j){ oq[j]=(bf16)((float)qv[i][j]*scq); ok[j]=(bf16)((float)kv[i][j]*sck); }
    ((bf16x8*)q)[i] = oq; ((bf16x8*)k)[i] = ok;
  }
}

// helper: load a 64x64 head-tile (fp32 or bf16 source) and split into hi/lo bf16 LDS planes,
// stride 64, XOR-swizzled: elem_off ^= (row&7)<<3  (matches fragSwz)
__device__ __forceinline__ void load_split_tile(const float* f32, const bf16* b16,
                                                size_t tokbase, int h,
                                                bf16* Lh, bf16* Ll, int tid, int nthr){
  for (int i = tid; i < 1024; i += nthr){
    int t = i >> 4, c4 = (i & 15)*4;
    const size_t g = (tokbase + t)*1024 + (size_t)h*64 + c4;
    float4 v;
    if (f32) v = *(const float4*)&f32[g];
    else { bf16x4 b = *(const bf16x4*)&b16[g]; v.x=(float)b[0]; v.y=(float)b[1]; v.z=(float)b[2]; v.w=(float)b[3]; }
    bf16x4 hh, ll;
    bf2 s0 = split2(v.x); hh[0]=s0.h; ll[0]=s0.l;
    bf2 s1 = split2(v.y); hh[1]=s1.h; ll[1]=s1.l;
    bf2 s2 = split2(v.z); hh[2]=s2.h; ll[2]=s2.l;
    bf2 s3 = split2(v.w); hh[3]=s3.h; ll[3]=s3.l;
    const int off = c4 ^ ((t&7)<<3);
    *(bf16x4*)&Lh[t*64 + off] = hh;
    *(bf16x4*)&Ll[t*64 + off] = ll;
  }
}

// ---------------------------------------------------------------- K3: phase A (2048 blocks, 128 thr)
// LDS = 40960 B exactly -> 4 blocks/CU (2 waves/SIMD). All 64-wide bf16 tiles XOR-swizzled.
// Ef row 0 stores the lg cumsum (row 0 / col 63 of E are never read by the solve);
// after the solve, Ef's 16 KiB are overlaid by DT (bytes 0..8191) and WT (8192..16383).
__global__ __launch_bounds__(128, 2) void k_phaseA(const float* __restrict__ kf32, const bf16* __restrict__ kb16,
    const float* __restrict__ vf, const float* __restrict__ logA, const float* __restrict__ betap,
    bf16* __restrict__ Wg, bf16* __restrict__ Dg, float* __restrict__ Pg, bf16* __restrict__ Bg){
  __shared__ bf16  Kh[64*64], Kl_[64*64];
  __shared__ float Ef[64*64];
  __shared__ bf16  KtT[64*64];   // K_til^T [j][t], swizzled
  bf16* DT = (bf16*)Ef;          // Dsol^T [i][t], swizzled (overlay after solve)
  bf16* WT = ((bf16*)Ef) + 4096; // Wsol^T [i][t], swizzled (overlay after solve)
  const int tid = threadIdx.x, lane = tid & 63, wid = tid >> 6;
  const int c = blockIdx.x, h = blockIdx.y, b = blockIdx.z;
  const size_t tokbase = (size_t)b*4096 + (size_t)c*64;
  const size_t cbase = ((size_t)((b*16 + h)*64 + c)) * 4096;

  load_split_tile(kf32, kb16, tokbase, h, Kh, Kl_, tid, 128);
  const float bet = betap[(tokbase + lane)*16 + h];   // per-lane beta_t, t = lane
  if (tid < 64){
    float la = logA[(tokbase + tid)*16 + h];
    #pragma unroll
    for (int dlt = 1; dlt < 64; dlt <<= 1){
      float o = __shfl_up(la, dlt);
      if (lane >= dlt) la += o;
    }
    Ef[tid] = la;                // lg cumsum lives in (never-read) E row 0
  }
  __syncthreads();

  // E[t][tau] = (gamma_t/gamma_tau)*(k_t . k_tau), strictly lower; else 0  (3-product MFMA)
  #pragma unroll
  for (int tt = 0; tt < 2; ++tt){
    const int t0 = 32*wid + 16*tt;
    #pragma unroll
    for (int tu = 0; tu < 4; ++tu){
      f32x4 accm = f32x4_zero();
      #pragma unroll
      for (int kk = 0; kk < 2; ++kk){
        bf16x8 aH = fragSwz(Kh,  t0,    kk, lane);
        bf16x8 aL = fragSwz(Kl_, t0,    kk, lane);
        bf16x8 bH = fragSwz(Kh,  16*tu, kk, lane);
        bf16x8 bL = fragSwz(Kl_, 16*tu, kk, lane);
        accm = mfma16x16x32(aH, bH, accm);
        accm = mfma16x16x32(aH, bL, accm);
        accm = mfma16x16x32(aL, bH, accm);
      }
      #pragma unroll
      for (int r = 0; r < 4; ++r){
        int row = t0 + (lane>>4)*4 + r, col = 16*tu + (lane&15);
        float ev = (col < row) ? accm[r]*__expf(Ef[row] - Ef[col]) : 0.f;
        if (row > 0) Ef[row*64 + col] = ev;   // row 0 never read; keeps lg intact
      }
    }
  }
  // K_til^T[j][t] = (gamma_L/gamma_t) * k[t][j]  (single bf16, swizzled store)
  {
    const float lgL = Ef[63];
    for (int i = tid; i < 4096; i += 128){
      int t = i & 63, j = i >> 6;
      int ks = j ^ ((t&7)<<3);
      float kv = (float)Kh[t*64 + ks] + (float)Kl_[t*64 + ks];
      KtT[j*64 + (t ^ ((j&7)<<3))] = (bf16)(__expf(lgL - Ef[t]) * kv);
    }
  }
  __syncthreads();

  const float gL = __expf(Ef[63]);   // hoisted: Ef row 0 is clobbered by the WT/DT overlay below

  // blocked forward substitution: (I + diag(beta)E) X = diag(beta) R
  {
    float Xv[64], d[64];
    if (wid == 0){
      #pragma unroll
      for (int t = 0; t < 64; ++t)
        Xv[t] = vf[(tokbase + t)*1024 + h*64 + lane];
    } else {
      #pragma unroll
      for (int t = 0; t < 64; ++t){
        int ks = lane ^ ((t&7)<<3);
        Xv[t] = __expf(Ef[t]) * ((float)Kh[t*64 + ks] + (float)Kl_[t*64 + ks]);
      }
    }
    #pragma unroll
    for (int bi = 0; bi < 4; ++bi){
      float pre[16];
      #pragma unroll
      for (int tt = 0; tt < 16; ++tt){
        const int t = 16*bi + tt;
        float a0=0.f,a1=0.f,a2=0.f,a3=0.f;
        #pragma unroll
        for (int r4 = 0; r4 < 4*bi; ++r4){
          float4 e = *(const float4*)&Ef[t*64 + r4*4];
          a0 += e.x * d[r4*4+0];
          a1 += e.y * d[r4*4+1];
          a2 += e.z * d[r4*4+2];
          a3 += e.w * d[r4*4+3];
        }
        pre[tt] = (a0+a1)+(a2+a3);
      }
      #pragma unroll
      for (int tt = 0; tt < 16; ++tt){
        const int t = 16*bi + tt;
        float s = pre[tt];
        #pragma unroll
        for (int j = 0; j < 16; ++j)
          if (j < tt) s += Ef[t*64 + 16*bi + j] * d[16*bi + j];
        d[t] = __shfl(bet, t) * (Xv[t] - s);
      }
    }
    __syncthreads();    // all Ef reads done (both waves) -> safe to overlay WT/DT onto Ef
    bf16* myT = wid ? WT : DT;
    #pragma unroll
    for (int s4 = 0; s4 < 16; ++s4){
      bf16x4 v4;
      v4[0]=(bf16)d[s4*4+0]; v4[1]=(bf16)d[s4*4+1];
      v4[2]=(bf16)d[s4*4+2]; v4[3]=(bf16)d[s4*4+3];
      *(bf16x4*)&myT[lane*64 + ((s4*4) ^ ((lane&7)<<3))] = v4;
    }
    bf16* myG = wid ? Wg : Dg;
    #pragma unroll
    for (int t = 0; t < 64; ++t)
      myG[cbase + (size_t)t*64 + lane] = (bf16)d[t];
  }
  __syncthreads();

  // P^T[j][i] = gamma_L*I - sum_t K_til[t][j]*Wsol[t][i]  (wave0, MFMA, fp32 out)
  // B[i][j]   =              sum_t Dsol[t][i]*K_til[t][j]  (wave1, MFMA, bf16 out)
  if (wid == 0){
    #pragma unroll
    for (int tj = 0; tj < 4; ++tj)
      #pragma unroll
      for (int ti = 0; ti < 4; ++ti){
        f32x4 acc = f32x4_zero();
        #pragma unroll
        for (int kk = 0; kk < 2; ++kk)
          acc = mfma16x16x32(fragSwz(KtT, 16*tj, kk, lane), fragSwz(WT, 16*ti, kk, lane), acc);
        #pragma unroll
        for (int r = 0; r < 4; ++r){
          int row = 16*tj + (lane>>4)*4 + r, col = 16*ti + (lane&15);
          Pg[cbase + (size_t)row*64 + col] = ((row == col) ? gL : 0.f) - acc[r];
        }
      }
  } else {
    #pragma unroll
    for (int ti = 0; ti < 4; ++ti)
      #pragma unroll
      for (int tj = 0; tj < 4; ++tj){
        f32x4 acc = f32x4_zero();
        #pragma unroll
        for (int kk = 0; kk < 2; ++kk)
          acc = mfma16x16x32(fragSwz(DT, 16*ti, kk, lane), fragSwz(KtT, 16*tj, kk, lane), acc);
        #pragma unroll
        for (int r = 0; r < 4; ++r){
          int row = 16*ti + (lane>>4)*4 + r, col = 16*tj + (lane&15);
          Bg[cbase + (size_t)row*64 + col] = (bf16)acc[r];
        }
      }
  }
}

// ---------------------------------------------------------------- K4a: segment composition (256 blocks: 8 seg x 32 chains)
// (Pseg, Bseg) = (P_{c0},B_{c0}) ∘ ... ∘ (P_{c7},B_{c7});  Pacc/Bacc fp32 in registers.
__global__ __launch_bounds__(256) void k_phaseB1(const float* __restrict__ Pg, const bf16* __restrict__ Bg,
                                                 float* __restrict__ PsegT, float* __restrict__ BsegF){
  __shared__ bf16 PaccH[4096], PaccL[4096], BaccH[4096], BaccL[4096];
  __shared__ bf16 PcH[4096], PcL[4096];
  __shared__ bf16 BcS[4096];
  const int tid = threadIdx.x, lane = tid & 63, w = tid >> 6;
  const int seg = blockIdx.x;
  const size_t chain = blockIdx.y;
  f32x4 Pr[4], Br[4];
  #pragma unroll
  for (int it = 0; it < 4; ++it){
    #pragma unroll
    for (int r = 0; r < 4; ++r){
      int row = 16*w + (lane>>4)*4 + r, col = 16*it + (lane&15);
      Pr[it][r] = (row == col) ? 1.f : 0.f;   // Pacc = I
      Br[it][r] = 0.f;                        // Bacc = 0
    }
  }
  for (int i = 0; i < 8; ++i){
    const size_t cb = (chain*64 + (size_t)seg*8 + i)*4096;
    // write own-wave rows of Pacc/Bacc split planes
    #pragma unroll
    for (int it = 0; it < 4; ++it)
      #pragma unroll
      for (int r = 0; r < 4; ++r){
        int row = 16*w + (lane>>4)*4 + r, col = 16*it + (lane&15);
        bf2 sp = split2(Pr[it][r]); PaccH[row*64+col] = sp.h; PaccL[row*64+col] = sp.l;
        bf2 sb = split2(Br[it][r]); BaccH[row*64+col] = sb.h; BaccL[row*64+col] = sb.l;
      }
    __syncthreads();   // prev iter's MFMA done -> safe to overwrite PcH/L
    for (int j = tid; j < 1024; j += 256){
      float4 pv = ((const float4*)(Pg + cb))[j];
      bf16x4 ph, pl;
      bf2 u0 = split2(pv.x); ph[0]=u0.h; pl[0]=u0.l;
      bf2 u1 = split2(pv.y); ph[1]=u1.h; pl[1]=u1.l;
      bf2 u2 = split2(pv.z); ph[2]=u2.h; pl[2]=u2.l;
      bf2 u3 = split2(pv.w); ph[3]=u3.h; pl[3]=u3.l;
      ((bf16x4*)PcH)[j] = ph; ((bf16x4*)PcL)[j] = pl;
    }
    for (int j = tid; j < 512; j += 256)
      ((uint4*)BcS)[j] = ((const uint4*)(Bg + cb))[j];
    __syncthreads();
    f32x4 nP[4], nB[4];
    #pragma unroll
    for (int it = 0; it < 4; ++it){ nP[it] = f32x4_zero(); nB[it] = f32x4_zero(); }
    #pragma unroll
    for (int kk = 0; kk < 2; ++kk){
      bf16x8 aPH = frag64(PaccH, 16*w, kk, lane), aPL = frag64(PaccL, 16*w, kk, lane);
      bf16x8 aBH = frag64(BaccH, 16*w, kk, lane), aBL = frag64(BaccL, 16*w, kk, lane);
      #pragma unroll
      for (int it = 0; it < 4; ++it){
        bf16x8 bH = frag64(PcH, 16*it, kk, lane), bL = frag64(PcL, 16*it, kk, lane);
        nP[it] = mfma16x16x32(aPH, bH, nP[it]);
        nP[it] = mfma16x16x32(aPH, bL, nP[it]);
        nP[it] = mfma16x16x32(aPL, bH, nP[it]);
        nB[it] = mfma16x16x32(aBH, bH, nB[it]);
        nB[it] = mfma16x16x32(aBH, bL, nB[it]);
        nB[it] = mfma16x16x32(aBL, bH, nB[it]);
      }
    }
    #pragma unroll
    for (int it = 0; it < 4; ++it)
      #pragma unroll
      for (int r = 0; r < 4; ++r){
        int row = 16*w + (lane>>4)*4 + r, col = 16*it + (lane&15);
        Pr[it][r] = nP[it][r];
        Br[it][r] = nB[it][r] + (float)BcS[row*64 + col];
      }
  }
  const size_t sb = (chain*8 + seg)*4096;
  #pragma unroll
  for (int it = 0; it < 4; ++it)
    #pragma unroll
    for (int r = 0; r < 4; ++r){
      int row = 16*w + (lane>>4)*4 + r, col = 16*it + (lane&15);
      PsegT[sb + (size_t)col*64 + row] = Pr[it][r];   // transposed (B-operand layout)
      BsegF[sb + (size_t)row*64 + col] = Br[it][r];   // natural
    }
}

// ---------------------------------------------------------------- K4b: segment-level scan (32 blocks, 8 steps)
__global__ __launch_bounds__(256) void k_phaseB2(const float* __restrict__ PsegT, const float* __restrict__ BsegF,
                                                 float* __restrict__ S0g){
  __shared__ bf16 Sh[4096], Sl[4096], Ph[4096], Pl[4096];
  __shared__ float Bf[4096];
  const int tid = threadIdx.x, lane = tid & 63, w = tid >> 6;
  const size_t bid = blockIdx.x;
  f32x4 Sr[4];
  #pragma unroll
  for (int it = 0; it < 4; ++it) Sr[it] = f32x4_zero();
  for (int seg = 0; seg < 8; ++seg){
    const size_t sb  = (bid*8 + seg)*4096;
    const size_t s0b = (bid*64 + (size_t)seg*8)*4096;
    // store entry state (fp32) + write own-rows split planes
    #pragma unroll
    for (int it = 0; it < 4; ++it)
      #pragma unroll
      for (int r = 0; r < 4; ++r){
        int row = 16*w + (lane>>4)*4 + r, col = 16*it + (lane&15);
        S0g[s0b + (size_t)row*64 + col] = Sr[it][r];
        bf2 sp = split2(Sr[it][r]); Sh[row*64+col] = sp.h; Sl[row*64+col] = sp.l;
      }
    __syncthreads();
    for (int j = tid; j < 1024; j += 256){
      float4 pv = ((const float4*)(PsegT + sb))[j];
      bf16x4 ph, pl;
      bf2 u0 = split2(pv.x); ph[0]=u0.h; pl[0]=u0.l;
      bf2 u1 = split2(pv.y); ph[1]=u1.h; pl[1]=u1.l;
      bf2 u2 = split2(pv.z); ph[2]=u2.h; pl[2]=u2.l;
      bf2 u3 = split2(pv.w); ph[3]=u3.h; pl[3]=u3.l;
      ((bf16x4*)Ph)[j] = ph; ((bf16x4*)Pl)[j] = pl;
      ((float4*)Bf)[j] = ((const float4*)(BsegF + sb))[j];
    }
    __syncthreads();
    f32x4 nS[4];
    #pragma unroll
    for (int it = 0; it < 4; ++it) nS[it] = f32x4_zero();
    #pragma unroll
    for (int kk = 0; kk < 2; ++kk){
      bf16x8 aH = frag64(Sh, 16*w, kk, lane), aL = frag64(Sl, 16*w, kk, lane);
      #pragma unroll
      for (int it = 0; it < 4; ++it){
        bf16x8 bH = frag64(Ph, 16*it, kk, lane), bL = frag64(Pl, 16*it, kk, lane);
        nS[it] = mfma16x16x32(aH, bH, nS[it]);
        nS[it] = mfma16x16x32(aH, bL, nS[it]);
        nS[it] = mfma16x16x32(aL, bH, nS[it]);
      }
    }
    #pragma unroll
    for (int it = 0; it < 4; ++it)
      #pragma unroll
      for (int r = 0; r < 4; ++r){
        int row = 16*w + (lane>>4)*4 + r, col = 16*it + (lane&15);
        Sr[it][r] = nS[it][r] + Bf[row*64 + col];
      }
  }
}

// ---------------------------------------------------------------- K4c: within-segment replay (256 blocks, 7 steps)
__global__ __launch_bounds__(256) void k_phaseB3(const float* __restrict__ Pg, const bf16* __restrict__ Bg,
                                                 float* __restrict__ S0g){
  __shared__ bf16 Sh[4096], Sl[4096], Ph[4096], Pl[4096];
  __shared__ bf16 BcS[4096];
  const int tid = threadIdx.x, lane = tid & 63, w = tid >> 6;
  const int seg = blockIdx.x;
  const size_t chain = blockIdx.y;
  const size_t segbase = chain*64 + (size_t)seg*8;
  f32x4 Sr[4];
  // load segment entry state (written by B2)
  #pragma unroll
  for (int it = 0; it < 4; ++it)
    #pragma unroll
    for (int r = 0; r < 4; ++r){
      int row = 16*w + (lane>>4)*4 + r, col = 16*it + (lane&15);
      Sr[it][r] = S0g[segbase*4096 + (size_t)row*64 + col];
    }
  for (int i = 0; i < 7; ++i){
    const size_t cb = (segbase + i)*4096;
    #pragma unroll
    for (int it = 0; it < 4; ++it)
      #pragma unroll
      for (int r = 0; r < 4; ++r){
        int row = 16*w + (lane>>4)*4 + r, col = 16*it + (lane&15);
        bf2 sp = split2(Sr[it][r]); Sh[row*64+col] = sp.h; Sl[row*64+col] = sp.l;
      }
    __syncthreads();
    for (int j = tid; j < 1024; j += 256){
      float4 pv = ((const float4*)(Pg + cb))[j];
      bf16x4 ph, pl;
      bf2 u0 = split2(pv.x); ph[0]=u0.h; pl[0]=u0.l;
      bf2 u1 = split2(pv.y); ph[1]=u1.h; pl[1]=u1.l;
      bf2 u2 = split2(pv.z); ph[2]=u2.h; pl[2]=u2.l;
      bf2 u3 = split2(pv.w); ph[3]=u3.h; pl[3]=u3.l;
      ((bf16x4*)Ph)[j] = ph; ((bf16x4*)Pl)[j] = pl;
    }
    for (int j = tid; j < 512; j += 256)
      ((uint4*)BcS)[j] = ((const uint4*)(Bg + cb))[j];
    __syncthreads();
    f32x4 nS[4];
    #pragma unroll
    for (int it = 0; it < 4; ++it) nS[it] = f32x4_zero();
    #pragma unroll
    for (int kk = 0; kk < 2; ++kk){
      bf16x8 aH = frag64(Sh, 16*w, kk, lane), aL = frag64(Sl, 16*w, kk, lane);
      #pragma unroll
      for (int it = 0; it < 4; ++it){
        bf16x8 bH = frag64(Ph, 16*it, kk, lane), bL = frag64(Pl, 16*it, kk, lane);
        nS[it] = mfma16x16x32(aH, bH, nS[it]);
        nS[it] = mfma16x16x32(aH, bL, nS[it]);
        nS[it] = mfma16x16x32(aL, bH, nS[it]);
      }
    }
    const size_t outb = (segbase + i + 1)*4096;
    #pragma unroll
    for (int it = 0; it < 4; ++it)
      #pragma unroll
      for (int r = 0; r < 4; ++r){
        int row = 16*w + (lane>>4)*4 + r, col = 16*it + (lane&15);
        float v = nS[it][r] + (float)BcS[row*64 + col];
        Sr[it][r] = v;
        S0g[outb + (size_t)row*64 + col] = v;
      }
  }
}

// ---------------------------------------------------------------- K5: phase C, outputs + fused RMSNorm/gate (2048 blocks)
// LDS = 81920 B exactly -> 2 blocks/CU (2 waves/SIMD). All tiles XOR-swizzled; lg cumsum in registers.
__global__ __launch_bounds__(256, 2) void k_phaseC(
    const float* __restrict__ qf32, const bf16* __restrict__ qb16,
    const float* __restrict__ kf32, const bf16* __restrict__ kb16,
    const bf16* __restrict__ gf, const float* __restrict__ logA,
    const float* __restrict__ S0g, const bf16* __restrict__ Wg, const bf16* __restrict__ Dg,
    const float* __restrict__ rms_w, bf16* __restrict__ yh, bf16* __restrict__ yl){
  __shared__ bf16 Qh[4096], Ql[4096], Kh[4096], Klo[4096];
  __shared__ bf16 Wl_[4096], Dl_[4096];
  __shared__ bf16 S0h[4096], S0l[4096];
  __shared__ bf16 AAg[4096];
  __shared__ bf16 BDt[4096];
  const int tid = threadIdx.x, lane = tid & 63, w = tid >> 6;
  const int c = blockIdx.x, h = blockIdx.y, b = blockIdx.z;
  const size_t tokbase = (size_t)b*4096 + (size_t)c*64;
  const size_t cbase = ((size_t)((b*16 + h)*64 + c)) * 4096;

  load_split_tile(qf32, qb16, tokbase, h, Qh, Ql, tid, 256);
  load_split_tile(kf32, kb16, tokbase, h, Kh, Klo, tid, 256);
  for (int i = tid; i < 512; i += 256){
    int r = i >> 3, d = r*8 + ((i&7) ^ (r&7));   // 16B-granular swizzle on the 8-elem block index
    ((uint4*)Wl_)[d] = ((const uint4*)(Wg + cbase))[i];
    ((uint4*)Dl_)[d] = ((const uint4*)(Dg + cbase))[i];
  }
  for (int i = tid; i < 1024; i += 256){
    float4 v = ((const float4*)(S0g + cbase))[i];
    bf16x4 sh, sl;
    bf2 t0 = split2(v.x); sh[0]=t0.h; sl[0]=t0.l;
    bf2 t1 = split2(v.y); sh[1]=t1.h; sl[1]=t1.l;
    bf2 t2 = split2(v.z); sh[2]=t2.h; sl[2]=t2.l;
    bf2 t3 = split2(v.w); sh[3]=t3.h; sl[3]=t3.l;
    int t = i >> 4, off = ((i&15)*4) ^ ((t&7)<<3);
    *(bf16x4*)&S0h[t*64 + off] = sh;
    *(bf16x4*)&S0l[t*64 + off] = sl;
  }
  // per-wave redundant lg cumsum (replaces lg_s/gq_s LDS)
  float la = logA[(tokbase + lane)*16 + h];
  #pragma unroll
  for (int dlt = 1; dlt < 64; dlt <<= 1){
    float o = __shfl_up(la, dlt);
    if (lane >= dlt) la += o;
  }
  __syncthreads();

  { // AAg = mask_incl(Gamma .* QK^T), 3-product
    const int t0 = 16*w;
    #pragma unroll
    for (int tu = 0; tu < 4; ++tu){
      f32x4 accm = f32x4_zero();
      #pragma unroll
      for (int kk = 0; kk < 2; ++kk){
        bf16x8 aH = fragSwz(Qh,  t0,    kk, lane);
        bf16x8 aL = fragSwz(Ql,  t0,    kk, lane);
        bf16x8 bH = fragSwz(Kh,  16*tu, kk, lane);
        bf16x8 bL = fragSwz(Klo, 16*tu, kk, lane);
        accm = mfma16x16x32(aH, bH, accm);
        accm = mfma16x16x32(aH, bL, accm);
        accm = mfma16x16x32(aL, bH, accm);
      }
      #pragma unroll
      for (int r = 0; r < 4; ++r){
        int row = t0 + (lane>>4)*4 + r, col = 16*tu + (lane&15);
        float lgr = __shfl(la, row), lgc = __shfl(la, col);
        float v = (col <= row) ? accm[r]*__expf(lgr - lgc) : 0.f;
        AAg[row*64 + (col ^ ((row&7)<<3))] = (bf16)v;
      }
    }
  }
  { // BDt[i][tau] = Dloc[tau][i] - (S0 W_hat^T)[i][tau]
    const int i0 = 16*w;
    #pragma unroll
    for (int tu = 0; tu < 4; ++tu){
      f32x4 accm = f32x4_zero();
      #pragma unroll
      for (int kk = 0; kk < 2; ++kk){
        bf16x8 aH = fragSwz(S0h, i0,    kk, lane);
        bf16x8 aL = fragSwz(S0l, i0,    kk, lane);
        bf16x8 bb = fragSwz(Wl_, 16*tu, kk, lane);
        accm = mfma16x16x32(aH, bb, accm);
        accm = mfma16x16x32(aL, bb, accm);
      }
      #pragma unroll
      for (int r = 0; r < 4; ++r){
        int row = i0 + (lane>>4)*4 + r, col = 16*tu + (lane&15);
        float v = (float)Dl_[col*64 + (row ^ ((col&7)<<3))] - accm[r];
        BDt[row*64 + (col ^ ((row&7)<<3))] = (bf16)v;
      }
    }
  }
  __syncthreads();
  for (int i = tid; i < 4096; i += 256){
    int t = i >> 6;                              // uniform per wave per iteration
    float gq = __expf(__shfl(la, t));
    float v = gq * ((float)Qh[i] + (float)Ql[i]);  // swizzle is within-row: row scale is layout-agnostic
    bf2 sp = split2(v);
    Qh[i] = sp.h; Ql[i] = sp.l;
  }
  __syncthreads();
  {
    const int t0 = 16*w;
    f32x4 o_acc[4];
    #pragma unroll
    for (int it = 0; it < 4; ++it) o_acc[it] = f32x4_zero();
    #pragma unroll
    for (int kk = 0; kk < 2; ++kk){
      bf16x8 aQh = fragSwz(Qh, t0, kk, lane);
      bf16x8 aQl = fragSwz(Ql, t0, kk, lane);
      bf16x8 aA  = fragSwz(AAg, t0, kk, lane);
      #pragma unroll
      for (int it = 0; it < 4; ++it){
        bf16x8 bSh = fragSwz(S0h, 16*it, kk, lane);
        bf16x8 bSl = fragSwz(S0l, 16*it, kk, lane);
        bf16x8 bD  = fragSwz(BDt, 16*it, kk, lane);
        f32x4 t = o_acc[it];
        t = mfma16x16x32(aQh, bSh, t);
        t = mfma16x16x32(aQh, bSl, t);
        t = mfma16x16x32(aQl, bSh, t);
        t = mfma16x16x32(aA,  bD,  t);
        o_acc[it] = t;
      }
    }
    float rw[4];
    #pragma unroll
    for (int it = 0; it < 4; ++it) rw[it] = rms_w[16*it + (lane&15)];
    #pragma unroll
    for (int r = 0; r < 4; ++r){
      float ss = 0.f;
      #pragma unroll
      for (int it = 0; it < 4; ++it) ss += o_acc[it][r]*o_acc[it][r];
      ss += __shfl_xor(ss, 1); ss += __shfl_xor(ss, 2);
      ss += __shfl_xor(ss, 4); ss += __shfl_xor(ss, 8);
      const float scale = rsqrtf(ss*(1.f/64.f) + 1e-6f);
      const int row = t0 + (lane>>4)*4 + r;
      const size_t tok = tokbase + row;
      #pragma unroll
      for (int it = 0; it < 4; ++it){
        const int col = 16*it + (lane&15);
        float g = (float)gf[tok*1024 + h*64 + col];
        float sg = g / (1.f + __expf(-g));
        float v = o_acc[it][r]*scale*rw[it]*sg;
        bf2 sp = split2(v);
        yh[tok*1024 + h*64 + col] = sp.h;
        yl[tok*1024 + h*64 + col] = sp.l;
      }
    }
  }
}

// ---------------------------------------------------------------- launcher
extern "C" void kernel_launch(void* const* d_in, const int* in_sizes, int n_in,
                              void* d_out, int out_size, void* d_ws, size_t ws_size,
                              hipStream_t stream){
  const float* x     = (const float*)d_in[0];
  const float* Wq    = (const float*)d_in[1];
  const float* Wk    = (const float*)d_in[2];
  const float* Wv    = (const float*)d_in[3];
  const float* Wa    = (const float*)d_in[4];
  const float* Wb    = (const float*)d_in[5];
  const float* A_log = (const float*)d_in[6];
  const float* dt_b  = (const float*)d_in[7];
  const float* Wgt   = (const float*)d_in[8];
  const float* Wo    = (const float*)d_in[9];
  const float* rms_w = (const float*)d_in[10];

  const bool BIG = ws_size >= (size_t)215000000;

  char* ws = (char*)d_ws;
  size_t off = 0;
  auto alloc = [&](size_t bytes)->char*{
    char* p = ws + off;
    off += (bytes + 255) & ~(size_t)255;
    return p;
  };
  const size_t PLANE = (size_t)8192*1024*2;   // bf16 activation plane (16 MiB)
  const size_t WPL   = (size_t)1024*1024*2;   // bf16 weight plane (2 MiB)
  bf16* xh  = (bf16*)alloc(PLANE);            // region also hosts Pg (A->B3), then yh
  bf16* xl  = (bf16*)alloc(PLANE);
  bf16* wqh = (bf16*)alloc(WPL); bf16* wql = (bf16*)alloc(WPL);   // wqh..wgl also hosts Bg
  bf16* wkh = (bf16*)alloc(WPL); bf16* wkl = (bf16*)alloc(WPL);
  bf16* wvh = (bf16*)alloc(WPL); bf16* wvl = (bf16*)alloc(WPL);
  bf16* wgh = (bf16*)alloc(WPL); bf16* wgl = (bf16*)alloc(WPL);
  bf16* woh = (bf16*)alloc(WPL); bf16* wol = (bf16*)alloc(WPL);
  float* WaT = (float*)alloc((size_t)16*1024*4);
  float* WbT = (float*)alloc((size_t)16*1024*4);
  float* qf = nullptr; bf16* qb = nullptr;
  float* kf = nullptr; bf16* kb = nullptr;
  if (BIG){ qf = (float*)alloc((size_t)8192*1024*4); kf = (float*)alloc((size_t)8192*1024*4); }
  else    { qb = (bf16*) alloc(PLANE);               kb = (bf16*) alloc(PLANE); }
  float* vf  = (float*)alloc((size_t)8192*1024*4);  // dead after phase A -> hosts S0g
  bf16* gfb  = (bf16*)alloc(PLANE);
  float* logA  = (float*)alloc((size_t)8192*16*4);
  float* betap = (float*)alloc((size_t)8192*16*4);
  bf16* Wg  = (bf16*)alloc((size_t)2048*4096*2);
  bf16* Dg  = (bf16*)alloc((size_t)2048*4096*2);
  float* Pg  = (float*)xh;            // 33.5 MiB fp32 in xh+xl (dead between GEMMs and phase C)
  float* S0g = vf;                    // 33.5 MiB fp32 (vf dead after phase A)
  bf16* Bg   = wqh;                   // 16 MiB bf16 (projection weights dead)
  float* PsegT = (float*)d_out;       // 4 MiB scratch in d_out (overwritten by final GEMM)
  float* BsegF = (float*)d_out + 1048576;  // next 4 MiB
  bf16* yh = xh;                      // phase C outputs (Pg dead after B3)
  bf16* yl = xl;

  k_cvt_x<<<8192, 256, 0, stream>>>(x, xh, xl, 2097152);
  k_transpose_w<<<dim3(32,32), 256, 0, stream>>>(Wq,  wqh, wql);
  k_transpose_w<<<dim3(32,32), 256, 0, stream>>>(Wk,  wkh, wkl);
  k_transpose_w<<<dim3(32,32), 256, 0, stream>>>(Wv,  wvh, wvl);
  k_transpose_w<<<dim3(32,32), 256, 0, stream>>>(Wgt, wgh, wgl);
  k_transpose_w<<<dim3(32,32), 256, 0, stream>>>(Wo,  woh, wol);
  k_transpose_ab<<<64, 256, 0, stream>>>(Wa, Wb, WaT, WbT);

  if (BIG){
    k_gemm1<<<dim3(64,8), 256, 0, stream>>>(xh, wqh, nullptr, qf);
    k_gemm1<<<dim3(64,8), 256, 0, stream>>>(xh, wkh, nullptr, kf);
  } else {
    k_gemm1<<<dim3(64,8), 256, 0, stream>>>(xh, wqh, qb, nullptr);
    k_gemm1<<<dim3(64,8), 256, 0, stream>>>(xh, wkh, kb, nullptr);
  }
  k_gemm1<<<dim3(64,8), 256, 0, stream>>>(xh, wvh, nullptr, vf);
  k_gemm1<<<dim3(64,8), 256, 0, stream>>>(xh, wgh, gfb, nullptr);

  k_alphabeta<<<1024, 256, 0, stream>>>(x, WaT, WbT, A_log, dt_b, logA, betap);
  if (BIG) k_norm_f32<<<512, 256, 0, stream>>>(qf, kf);
  else     k_norm_b16<<<512, 256, 0, stream>>>(qb, kb);

  k_phaseA<<<dim3(64,16,2), 128, 0, stream>>>(kf, kb, vf, logA, betap, Wg, Dg, Pg, Bg);
  k_phaseB1<<<dim3(8,32), 256, 0, stream>>>(Pg, Bg, PsegT, BsegF);
  k_phaseB2<<<32, 256, 0, stream>>>(PsegT, BsegF, S0g);
  k_phaseB3<<<dim3(8,32), 256, 0, stream>>>(Pg, Bg, S0g);
  k_phaseC<<<dim3(64,16,2), 256, 0, stream>>>(qf, qb, kf, kb, gfb, logA, S0g, Wg, Dg, rms_w, yh, yl);

  k_gemm3<<<dim3(64,8), 256, 0, stream>>>(yh, yl, woh, wol, nullptr, (float*)d_out);
}

// Round 2
// 689.875 us; speedup vs baseline: 1.1171x; 1.1171x over previous
//
#include <hip/hip_runtime.h>
#include <cstdint>
#include <cstddef>

typedef __bf16 bf16;
typedef __bf16 bf16x4 __attribute__((ext_vector_type(4)));
typedef __bf16 bf16x8 __attribute__((ext_vector_type(8)));
typedef float  f32x4  __attribute__((ext_vector_type(4)));

#define GLD_LDS16(gp, lp) \
  __builtin_amdgcn_global_load_lds((__attribute__((address_space(1))) void*)(gp), \
                                   (__attribute__((address_space(3))) void*)(lp), 16, 0, 0)

__device__ __forceinline__ f32x4 f32x4_zero(){ f32x4 v; v[0]=0.f; v[1]=0.f; v[2]=0.f; v[3]=0.f; return v; }

__device__ __forceinline__ f32x4 mfma16x16x32(bf16x8 a, bf16x8 b, f32x4 c){
  return __builtin_amdgcn_mfma_f32_16x16x32_bf16(a, b, c, 0, 0, 0);
}
// fragment of a 64-col bf16 LDS array (stride 64), LINEAR layout (phaseB kernels)
__device__ __forceinline__ bf16x8 frag64(const bf16* base, int row0, int kk, int lane){
  return *(const bf16x8*)&base[(row0 + (lane&15))*64 + kk*32 + (lane>>4)*8];
}
// fragment of a 64-col bf16 LDS array with XOR bank-swizzle: elem ^= (row&7)<<3
// (16B-granular swizzle; keeps ds_read_b128 16B-aligned; 16-way conflict -> 2-way)
__device__ __forceinline__ bf16x8 fragSwz(const bf16* base, int row0, int kk, int lane){
  const int row = row0 + (lane&15);
  const int off = (kk*32 + (lane>>4)*8) ^ ((row&7)<<3);
  return *(const bf16x8*)&base[row*64 + off];
}
struct bf2 { bf16 h, l; };
__device__ __forceinline__ bf2 split2(float v){
  bf2 r; r.h = (bf16)v; r.l = (bf16)(v - (float)r.h); return r;
}

// ---------------------------------------------------------------- K0a: x -> hi/lo bf16 planes
__global__ __launch_bounds__(256) void k_cvt_x(const float* __restrict__ x,
                                               bf16* __restrict__ xh, bf16* __restrict__ xl, int n4){
  int i = blockIdx.x*256 + threadIdx.x;
  if (i < n4){
    float4 v = ((const float4*)x)[i];
    bf16x4 h, l;
    bf2 t0 = split2(v.x); h[0]=t0.h; l[0]=t0.l;
    bf2 t1 = split2(v.y); h[1]=t1.h; l[1]=t1.l;
    bf2 t2 = split2(v.z); h[2]=t2.h; l[2]=t2.l;
    bf2 t3 = split2(v.w); h[3]=t3.h; l[3]=t3.l;
    ((bf16x4*)xh)[i] = h;
    ((bf16x4*)xl)[i] = l;
  }
}

// ---------------------------------------------------------------- K0b: W[k][n] -> Wt hi/lo [n][k]
__global__ __launch_bounds__(256) void k_transpose_w(const float* __restrict__ W,
                                                     bf16* __restrict__ Wth, bf16* __restrict__ Wtl){
  __shared__ float tile[32][33];
  const int k0 = blockIdx.x*32, n0 = blockIdx.y*32;
  const int r = threadIdx.x >> 3, c4 = (threadIdx.x & 7)*4;
  float4 v = *(const float4*)&W[(size_t)(k0+r)*1024 + n0 + c4];
  tile[r][c4+0]=v.x; tile[r][c4+1]=v.y; tile[r][c4+2]=v.z; tile[r][c4+3]=v.w;
  __syncthreads();
  bf16x4 h, l;
  bf2 t0 = split2(tile[c4+0][r]); h[0]=t0.h; l[0]=t0.l;
  bf2 t1 = split2(tile[c4+1][r]); h[1]=t1.h; l[1]=t1.l;
  bf2 t2 = split2(tile[c4+2][r]); h[2]=t2.h; l[2]=t2.l;
  bf2 t3 = split2(tile[c4+3][r]); h[3]=t3.h; l[3]=t3.l;
  *(bf16x4*)&Wth[(size_t)(n0+r)*1024 + k0 + c4] = h;
  *(bf16x4*)&Wtl[(size_t)(n0+r)*1024 + k0 + c4] = l;
}

// ---------------------------------------------------------------- K0c: Walpha/Wbeta [1024][16] -> [16][1024] fp32
__global__ __launch_bounds__(256) void k_transpose_ab(const float* __restrict__ Wa, const float* __restrict__ Wb,
                                                      float* __restrict__ WaT, float* __restrict__ WbT){
  int p = blockIdx.x*256 + threadIdx.x;
  if (p < 16384){
    int o = p >> 10, k = p & 1023;
    WaT[p] = Wa[k*16 + o];
    WbT[p] = Wb[k*16 + o];
  }
}

// ---------------------------------------------------------------- K1: split-bf16 MFMA GEMM (3-product), K=1024
__global__ __launch_bounds__(256) void k_gemm3(const bf16* __restrict__ Ah, const bf16* __restrict__ Al,
                                               const bf16* __restrict__ Bth, const bf16* __restrict__ Btl,
                                               bf16* __restrict__ Cb, float* __restrict__ Cf){
  __shared__ bf16 Ash[128*32], Asl[128*32];
  __shared__ bf16 Bsh[128*32], Bsl[128*32];
  const int tid = threadIdx.x, lane = tid & 63, w = tid >> 6;
  const int wm = w >> 1, wn = w & 1;
  const size_t m0 = (size_t)blockIdx.x * 128;
  const size_t n0 = (size_t)blockIdx.y * 128;
  f32x4 acc[4][4];
  #pragma unroll
  for (int i=0;i<4;++i)
    #pragma unroll
    for (int j=0;j<4;++j) acc[i][j] = f32x4_zero();

  for (int k0 = 0; k0 < 1024; k0 += 32){
    __syncthreads();
    #pragma unroll
    for (int j = 0; j < 2; ++j){
      const int rbase = 32*w + 16*j;
      const int r = rbase + (lane >> 2);
      const int kk = k0 + (lane & 3)*8;
      GLD_LDS16(&Ah [(m0 + r)*1024 + kk], &Ash[rbase*32]);
      GLD_LDS16(&Al [(m0 + r)*1024 + kk], &Asl[rbase*32]);
      GLD_LDS16(&Bth[(n0 + r)*1024 + kk], &Bsh[rbase*32]);
      GLD_LDS16(&Btl[(n0 + r)*1024 + kk], &Bsl[rbase*32]);
    }
    __syncthreads();
    bf16x8 ah[4], al[4], bh[4], bl[4];
    #pragma unroll
    for (int t=0;t<4;++t){
      ah[t] = *(const bf16x8*)&Ash[(64*wm + 16*t + (lane&15))*32 + (lane>>4)*8];
      al[t] = *(const bf16x8*)&Asl[(64*wm + 16*t + (lane&15))*32 + (lane>>4)*8];
      bh[t] = *(const bf16x8*)&Bsh[(64*wn + 16*t + (lane&15))*32 + (lane>>4)*8];
      bl[t] = *(const bf16x8*)&Bsl[(64*wn + 16*t + (lane&15))*32 + (lane>>4)*8];
    }
    #pragma unroll
    for (int i=0;i<4;++i)
      #pragma unroll
      for (int j=0;j<4;++j){
        f32x4 t = acc[i][j];
        t = mfma16x16x32(ah[i], bh[j], t);
        t = mfma16x16x32(ah[i], bl[j], t);
        t = mfma16x16x32(al[i], bh[j], t);
        acc[i][j] = t;
      }
  }
  #pragma unroll
  for (int i=0;i<4;++i)
    #pragma unroll
    for (int j=0;j<4;++j)
      #pragma unroll
      for (int r=0;r<4;++r){
        size_t row = m0 + 64*wm + 16*i + (lane>>4)*4 + r;
        size_t col = n0 + 64*wn + 16*j + (lane&15);
        float v = acc[i][j][r];
        if (Cf) Cf[row*1024 + col] = v;
        else    Cb[row*1024 + col] = (bf16)v;
      }
}

// ---------------------------------------------------------------- K1b: single-bf16 MFMA GEMM, K=1024
__global__ __launch_bounds__(256) void k_gemm1(const bf16* __restrict__ Ah, const bf16* __restrict__ Bth,
                                               bf16* __restrict__ Cb, float* __restrict__ Cf){
  __shared__ bf16 Ash[128*32];
  __shared__ bf16 Bsh[128*32];
  const int tid = threadIdx.x, lane = tid & 63, w = tid >> 6;
  const int wm = w >> 1, wn = w & 1;
  const size_t m0 = (size_t)blockIdx.x * 128;
  const size_t n0 = (size_t)blockIdx.y * 128;
  f32x4 acc[4][4];
  #pragma unroll
  for (int i=0;i<4;++i)
    #pragma unroll
    for (int j=0;j<4;++j) acc[i][j] = f32x4_zero();

  for (int k0 = 0; k0 < 1024; k0 += 32){
    __syncthreads();
    #pragma unroll
    for (int j = 0; j < 2; ++j){
      const int rbase = 32*w + 16*j;
      const int r = rbase + (lane >> 2);
      const int kk = k0 + (lane & 3)*8;
      GLD_LDS16(&Ah [(m0 + r)*1024 + kk], &Ash[rbase*32]);
      GLD_LDS16(&Bth[(n0 + r)*1024 + kk], &Bsh[rbase*32]);
    }
    __syncthreads();
    bf16x8 ah[4], bh[4];
    #pragma unroll
    for (int t=0;t<4;++t){
      ah[t] = *(const bf16x8*)&Ash[(64*wm + 16*t + (lane&15))*32 + (lane>>4)*8];
      bh[t] = *(const bf16x8*)&Bsh[(64*wn + 16*t + (lane&15))*32 + (lane>>4)*8];
    }
    #pragma unroll
    for (int i=0;i<4;++i)
      #pragma unroll
      for (int j=0;j<4;++j)
        acc[i][j] = mfma16x16x32(ah[i], bh[j], acc[i][j]);
  }
  #pragma unroll
  for (int i=0;i<4;++i)
    #pragma unroll
    for (int j=0;j<4;++j)
      #pragma unroll
      for (int r=0;r<4;++r){
        size_t row = m0 + 64*wm + 16*i + (lane>>4)*4 + r;
        size_t col = n0 + 64*wn + 16*j + (lane&15);
        float v = acc[i][j][r];
        if (Cf) Cf[row*1024 + col] = v;
        else    Cb[row*1024 + col] = (bf16)v;
      }
}

// ---------------------------------------------------------------- K2: dt/alpha/beta projections (fp32)
__global__ __launch_bounds__(256) void k_alphabeta(const float* __restrict__ x,
    const float* __restrict__ WaT, const float* __restrict__ WbT,
    const float* __restrict__ A_log, const float* __restrict__ dt_bias,
    float* __restrict__ logA, float* __restrict__ betap){
  __shared__ float xl[8*1024];
  const int tid = threadIdx.x;
  const size_t base4 = (size_t)blockIdx.x * 2048;
  #pragma unroll
  for (int j=0;j<8;++j)
    ((float4*)xl)[tid + j*256] = ((const float4*)x)[base4 + tid + j*256];
  __syncthreads();
  const int r = tid >> 5, o = tid & 31;
  const float4* wrow = (const float4*)((o < 16) ? (WaT + (size_t)o*1024) : (WbT + (size_t)(o-16)*1024));
  const float4* xr = (const float4*)(xl + r*1024);
  float a0=0,a1=0,a2=0,a3=0;
  for (int j=0;j<256;++j){
    float4 xv = xr[j]; float4 wv = wrow[j];
    a0 += xv.x*wv.x; a1 += xv.y*wv.y; a2 += xv.z*wv.z; a3 += xv.w*wv.w;
  }
  float dot = (a0+a1)+(a2+a3);
  const size_t t = (size_t)blockIdx.x*8 + r;
  if (o < 16){
    float z = dot + dt_bias[o];
    float dt = (z > 20.f) ? z : log1pf(expf(z));
    logA[t*16 + o] = -expf(A_log[o]) * dt;          // log(alpha_t)
  } else {
    betap[t*16 + (o-16)] = 1.f/(1.f + expf(-dot));  // beta_t
  }
}

// ---------------------------------------------------------------- K2b (BIG): in-place fp32 l2norm of q (/8) and k
__global__ __launch_bounds__(256) void k_norm_f32(float* __restrict__ qf, float* __restrict__ kf){
  const size_t p = (size_t)blockIdx.x*256 + threadIdx.x;  // (token,head)
  {
    float4* q4 = (float4*)(qf + p*64);
    float4 v[16]; float s = 0.f;
    #pragma unroll
    for (int i=0;i<16;++i){ v[i]=q4[i]; s += v[i].x*v[i].x + v[i].y*v[i].y + v[i].z*v[i].z + v[i].w*v[i].w; }
    float sc = 0.125f / fmaxf(sqrtf(s), 1e-12f);
    #pragma unroll
    for (int i=0;i<16;++i){ v[i].x*=sc; v[i].y*=sc; v[i].z*=sc; v[i].w*=sc; q4[i]=v[i]; }
  }
  {
    float4* k4 = (float4*)(kf + p*64);
    float4 v[16]; float s = 0.f;
    #pragma unroll
    for (int i=0;i<16;++i){ v[i]=k4[i]; s += v[i].x*v[i].x + v[i].y*v[i].y + v[i].z*v[i].z + v[i].w*v[i].w; }
    float sc = 1.0f / fmaxf(sqrtf(s), 1e-12f);
    #pragma unroll
    for (int i=0;i<16;++i){ v[i].x*=sc; v[i].y*=sc; v[i].z*=sc; v[i].w*=sc; k4[i]=v[i]; }
  }
}

// ---------------------------------------------------------------- K2b (SMALL): in-place bf16 l2norm
__global__ __launch_bounds__(256) void k_norm_b16(bf16* __restrict__ qb, bf16* __restrict__ kb){
  const size_t p = (size_t)blockIdx.x*256 + threadIdx.x;
  bf16* q = qb + p*64;
  bf16* k = kb + p*64;
  bf16x8 qv[8], kv[8];
  float sq = 0.f, sk = 0.f;
  #pragma unroll
  for (int i=0;i<8;++i){
    qv[i] = ((const bf16x8*)q)[i];
    kv[i] = ((const bf16x8*)k)[i];
    #pragma unroll
    for (int j=0;j<8;++j){ float a=(float)qv[i][j]; sq+=a*a; float b=(float)kv[i][j]; sk+=b*b; }
  }
  float scq = 0.125f / fmaxf(sqrtf(sq), 1e-12f);
  float sck = 1.0f   / fmaxf(sqrtf(sk), 1e-12f);
  #pragma unroll
  for (int i=0;i<8;++i){
    bf16x8 oq, ok;
    #pragma unroll
    for (int j=0;j<8;++j){ oq[j]=(bf16)((float)qv[i][j]*scq); ok[j]=(bf16)((float)kv[i][j]*sck); }
    ((bf16x8*)q)[i] = oq; ((bf16x8*)k)[i] = ok;
  }
}

// helper: load a 64x64 head-tile (fp32 or bf16 source) and split into hi/lo bf16 LDS planes,
// stride 64, XOR-swizzled: elem_off ^= (row&7)<<3  (matches fragSwz)
__device__ __forceinline__ void load_split_tile(const float* f32, const bf16* b16,
                                                size_t tokbase, int h,
                                                bf16* Lh, bf16* Ll, int tid, int nthr){
  for (int i = tid; i < 1024; i += nthr){
    int t = i >> 4, c4 = (i & 15)*4;
    const size_t g = (tokbase + t)*1024 + (size_t)h*64 + c4;
    float4 v;
    if (f32) v = *(const float4*)&f32[g];
    else { bf16x4 b = *(const bf16x4*)&b16[g]; v.x=(float)b[0]; v.y=(float)b[1]; v.z=(float)b[2]; v.w=(float)b[3]; }
    bf16x4 hh, ll;
    bf2 s0 = split2(v.x); hh[0]=s0.h; ll[0]=s0.l;
    bf2 s1 = split2(v.y); hh[1]=s1.h; ll[1]=s1.l;
    bf2 s2 = split2(v.z); hh[2]=s2.h; ll[2]=s2.l;
    bf2 s3 = split2(v.w); hh[3]=s3.h; ll[3]=s3.l;
    const int off = c4 ^ ((t&7)<<3);
    *(bf16x4*)&Lh[t*64 + off] = hh;
    *(bf16x4*)&Ll[t*64 + off] = ll;
  }
}

// ---------------------------------------------------------------- K3: phase A (2048 blocks, 128 thr)
// LDS = 40960 B -> 4 blocks/CU possible. NO min-waves clause: the solve holds Xv[64]+d[64]
// (128 floats) live per thread; capping VGPRs to 128 (round 1) spilled ~96 floats/thread to
// scratch (+98 MB HBM writes, +49 MB reads, dur 129->177us). VGPR ~184 still gives
// 2 waves/SIMD (<=256) = 4 blocks/CU with this LDS footprint.
__global__ __launch_bounds__(128) void k_phaseA(const float* __restrict__ kf32, const bf16* __restrict__ kb16,
    const float* __restrict__ vf, const float* __restrict__ logA, const float* __restrict__ betap,
    bf16* __restrict__ Wg, bf16* __restrict__ Dg, float* __restrict__ Pg, bf16* __restrict__ Bg){
  __shared__ bf16  Kh[64*64], Kl_[64*64];
  __shared__ float Ef[64*64];
  __shared__ bf16  KtT[64*64];   // K_til^T [j][t], swizzled
  bf16* DT = (bf16*)Ef;          // Dsol^T [i][t], swizzled (overlay after solve)
  bf16* WT = ((bf16*)Ef) + 4096; // Wsol^T [i][t], swizzled (overlay after solve)
  const int tid = threadIdx.x, lane = tid & 63, wid = tid >> 6;
  const int c = blockIdx.x, h = blockIdx.y, b = blockIdx.z;
  const size_t tokbase = (size_t)b*4096 + (size_t)c*64;
  const size_t cbase = ((size_t)((b*16 + h)*64 + c)) * 4096;

  load_split_tile(kf32, kb16, tokbase, h, Kh, Kl_, tid, 128);
  const float bet = betap[(tokbase + lane)*16 + h];   // per-lane beta_t, t = lane
  if (tid < 64){
    float la = logA[(tokbase + tid)*16 + h];
    #pragma unroll
    for (int dlt = 1; dlt < 64; dlt <<= 1){
      float o = __shfl_up(la, dlt);
      if (lane >= dlt) la += o;
    }
    Ef[tid] = la;                // lg cumsum lives in (never-read) E row 0
  }
  __syncthreads();

  // E[t][tau] = (gamma_t/gamma_tau)*(k_t . k_tau), strictly lower; else 0  (3-product MFMA)
  #pragma unroll
  for (int tt = 0; tt < 2; ++tt){
    const int t0 = 32*wid + 16*tt;
    #pragma unroll
    for (int tu = 0; tu < 4; ++tu){
      f32x4 accm = f32x4_zero();
      #pragma unroll
      for (int kk = 0; kk < 2; ++kk){
        bf16x8 aH = fragSwz(Kh,  t0,    kk, lane);
        bf16x8 aL = fragSwz(Kl_, t0,    kk, lane);
        bf16x8 bH = fragSwz(Kh,  16*tu, kk, lane);
        bf16x8 bL = fragSwz(Kl_, 16*tu, kk, lane);
        accm = mfma16x16x32(aH, bH, accm);
        accm = mfma16x16x32(aH, bL, accm);
        accm = mfma16x16x32(aL, bH, accm);
      }
      #pragma unroll
      for (int r = 0; r < 4; ++r){
        int row = t0 + (lane>>4)*4 + r, col = 16*tu + (lane&15);
        float ev = (col < row) ? accm[r]*__expf(Ef[row] - Ef[col]) : 0.f;
        if (row > 0) Ef[row*64 + col] = ev;   // row 0 never read; keeps lg intact
      }
    }
  }
  // K_til^T[j][t] = (gamma_L/gamma_t) * k[t][j]  (single bf16, swizzled store)
  {
    const float lgL = Ef[63];
    for (int i = tid; i < 4096; i += 128){
      int t = i & 63, j = i >> 6;
      int ks = j ^ ((t&7)<<3);
      float kv = (float)Kh[t*64 + ks] + (float)Kl_[t*64 + ks];
      KtT[j*64 + (t ^ ((j&7)<<3))] = (bf16)(__expf(lgL - Ef[t]) * kv);
    }
  }
  __syncthreads();

  const float gL = __expf(Ef[63]);   // hoisted: Ef row 0 is clobbered by the WT/DT overlay below

  // blocked forward substitution: (I + diag(beta)E) X = diag(beta) R
  {
    float Xv[64], d[64];
    if (wid == 0){
      #pragma unroll
      for (int t = 0; t < 64; ++t)
        Xv[t] = vf[(tokbase + t)*1024 + h*64 + lane];
    } else {
      #pragma unroll
      for (int t = 0; t < 64; ++t){
        int ks = lane ^ ((t&7)<<3);
        Xv[t] = __expf(Ef[t]) * ((float)Kh[t*64 + ks] + (float)Kl_[t*64 + ks]);
      }
    }
    #pragma unroll
    for (int bi = 0; bi < 4; ++bi){
      float pre[16];
      #pragma unroll
      for (int tt = 0; tt < 16; ++tt){
        const int t = 16*bi + tt;
        float a0=0.f,a1=0.f,a2=0.f,a3=0.f;
        #pragma unroll
        for (int r4 = 0; r4 < 4*bi; ++r4){
          float4 e = *(const float4*)&Ef[t*64 + r4*4];
          a0 += e.x * d[r4*4+0];
          a1 += e.y * d[r4*4+1];
          a2 += e.z * d[r4*4+2];
          a3 += e.w * d[r4*4+3];
        }
        pre[tt] = (a0+a1)+(a2+a3);
      }
      #pragma unroll
      for (int tt = 0; tt < 16; ++tt){
        const int t = 16*bi + tt;
        float s = pre[tt];
        #pragma unroll
        for (int j = 0; j < 16; ++j)
          if (j < tt) s += Ef[t*64 + 16*bi + j] * d[16*bi + j];
        d[t] = __shfl(bet, t) * (Xv[t] - s);
      }
    }
    __syncthreads();    // all Ef reads done (both waves) -> safe to overlay WT/DT onto Ef
    bf16* myT = wid ? WT : DT;
    #pragma unroll
    for (int s4 = 0; s4 < 16; ++s4){
      bf16x4 v4;
      v4[0]=(bf16)d[s4*4+0]; v4[1]=(bf16)d[s4*4+1];
      v4[2]=(bf16)d[s4*4+2]; v4[3]=(bf16)d[s4*4+3];
      *(bf16x4*)&myT[lane*64 + ((s4*4) ^ ((lane&7)<<3))] = v4;
    }
    bf16* myG = wid ? Wg : Dg;
    #pragma unroll
    for (int t = 0; t < 64; ++t)
      myG[cbase + (size_t)t*64 + lane] = (bf16)d[t];
  }
  __syncthreads();

  // P^T[j][i] = gamma_L*I - sum_t K_til[t][j]*Wsol[t][i]  (wave0, MFMA, fp32 out)
  // B[i][j]   =              sum_t Dsol[t][i]*K_til[t][j]  (wave1, MFMA, bf16 out)
  if (wid == 0){
    #pragma unroll
    for (int tj = 0; tj < 4; ++tj)
      #pragma unroll
      for (int ti = 0; ti < 4; ++ti){
        f32x4 acc = f32x4_zero();
        #pragma unroll
        for (int kk = 0; kk < 2; ++kk)
          acc = mfma16x16x32(fragSwz(KtT, 16*tj, kk, lane), fragSwz(WT, 16*ti, kk, lane), acc);
        #pragma unroll
        for (int r = 0; r < 4; ++r){
          int row = 16*tj + (lane>>4)*4 + r, col = 16*ti + (lane&15);
          Pg[cbase + (size_t)row*64 + col] = ((row == col) ? gL : 0.f) - acc[r];
        }
      }
  } else {
    #pragma unroll
    for (int ti = 0; ti < 4; ++ti)
      #pragma unroll
      for (int tj = 0; tj < 4; ++tj){
        f32x4 acc = f32x4_zero();
        #pragma unroll
        for (int kk = 0; kk < 2; ++kk)
          acc = mfma16x16x32(fragSwz(DT, 16*ti, kk, lane), fragSwz(KtT, 16*tj, kk, lane), acc);
        #pragma unroll
        for (int r = 0; r < 4; ++r){
          int row = 16*ti + (lane>>4)*4 + r, col = 16*tj + (lane&15);
          Bg[cbase + (size_t)row*64 + col] = (bf16)acc[r];
        }
      }
  }
}

// ---------------------------------------------------------------- K4a: segment composition (256 blocks: 8 seg x 32 chains)
// (Pseg, Bseg) = (P_{c0},B_{c0}) ∘ ... ∘ (P_{c7},B_{c7});  Pacc/Bacc fp32 in registers.
__global__ __launch_bounds__(256) void k_phaseB1(const float* __restrict__ Pg, const bf16* __restrict__ Bg,
                                                 float* __restrict__ PsegT, float* __restrict__ BsegF){
  __shared__ bf16 PaccH[4096], PaccL[4096], BaccH[4096], BaccL[4096];
  __shared__ bf16 PcH[4096], PcL[4096];
  __shared__ bf16 BcS[4096];
  const int tid = threadIdx.x, lane = tid & 63, w = tid >> 6;
  const int seg = blockIdx.x;
  const size_t chain = blockIdx.y;
  f32x4 Pr[4], Br[4];
  #pragma unroll
  for (int it = 0; it < 4; ++it){
    #pragma unroll
    for (int r = 0; r < 4; ++r){
      int row = 16*w + (lane>>4)*4 + r, col = 16*it + (lane&15);
      Pr[it][r] = (row == col) ? 1.f : 0.f;   // Pacc = I
      Br[it][r] = 0.f;                        // Bacc = 0
    }
  }
  for (int i = 0; i < 8; ++i){
    const size_t cb = (chain*64 + (size_t)seg*8 + i)*4096;
    // write own-wave rows of Pacc/Bacc split planes
    #pragma unroll
    for (int it = 0; it < 4; ++it)
      #pragma unroll
      for (int r = 0; r < 4; ++r){
        int row = 16*w + (lane>>4)*4 + r, col = 16*it + (lane&15);
        bf2 sp = split2(Pr[it][r]); PaccH[row*64+col] = sp.h; PaccL[row*64+col] = sp.l;
        bf2 sb = split2(Br[it][r]); BaccH[row*64+col] = sb.h; BaccL[row*64+col] = sb.l;
      }
    __syncthreads();   // prev iter's MFMA done -> safe to overwrite PcH/L
    for (int j = tid; j < 1024; j += 256){
      float4 pv = ((const float4*)(Pg + cb))[j];
      bf16x4 ph, pl;
      bf2 u0 = split2(pv.x); ph[0]=u0.h; pl[0]=u0.l;
      bf2 u1 = split2(pv.y); ph[1]=u1.h; pl[1]=u1.l;
      bf2 u2 = split2(pv.z); ph[2]=u2.h; pl[2]=u2.l;
      bf2 u3 = split2(pv.w); ph[3]=u3.h; pl[3]=u3.l;
      ((bf16x4*)PcH)[j] = ph; ((bf16x4*)PcL)[j] = pl;
    }
    for (int j = tid; j < 512; j += 256)
      ((uint4*)BcS)[j] = ((const uint4*)(Bg + cb))[j];
    __syncthreads();
    f32x4 nP[4], nB[4];
    #pragma unroll
    for (int it = 0; it < 4; ++it){ nP[it] = f32x4_zero(); nB[it] = f32x4_zero(); }
    #pragma unroll
    for (int kk = 0; kk < 2; ++kk){
      bf16x8 aPH = frag64(PaccH, 16*w, kk, lane), aPL = frag64(PaccL, 16*w, kk, lane);
      bf16x8 aBH = frag64(BaccH, 16*w, kk, lane), aBL = frag64(BaccL, 16*w, kk, lane);
      #pragma unroll
      for (int it = 0; it < 4; ++it){
        bf16x8 bH = frag64(PcH, 16*it, kk, lane), bL = frag64(PcL, 16*it, kk, lane);
        nP[it] = mfma16x16x32(aPH, bH, nP[it]);
        nP[it] = mfma16x16x32(aPH, bL, nP[it]);
        nP[it] = mfma16x16x32(aPL, bH, nP[it]);
        nB[it] = mfma16x16x32(aBH, bH, nB[it]);
        nB[it] = mfma16x16x32(aBH, bL, nB[it]);
        nB[it] = mfma16x16x32(aBL, bH, nB[it]);
      }
    }
    #pragma unroll
    for (int it = 0; it < 4; ++it)
      #pragma unroll
      for (int r = 0; r < 4; ++r){
        int row = 16*w + (lane>>4)*4 + r, col = 16*it + (lane&15);
        Pr[it][r] = nP[it][r];
        Br[it][r] = nB[it][r] + (float)BcS[row*64 + col];
      }
  }
  const size_t sb = (chain*8 + seg)*4096;
  #pragma unroll
  for (int it = 0; it < 4; ++it)
    #pragma unroll
    for (int r = 0; r < 4; ++r){
      int row = 16*w + (lane>>4)*4 + r, col = 16*it + (lane&15);
      PsegT[sb + (size_t)col*64 + row] = Pr[it][r];   // transposed (B-operand layout)
      BsegF[sb + (size_t)row*64 + col] = Br[it][r];   // natural
    }
}

// ---------------------------------------------------------------- K4b: segment-level scan (32 blocks, 8 steps)
__global__ __launch_bounds__(256) void k_phaseB2(const float* __restrict__ PsegT, const float* __restrict__ BsegF,
                                                 float* __restrict__ S0g){
  __shared__ bf16 Sh[4096], Sl[4096], Ph[4096], Pl[4096];
  __shared__ float Bf[4096];
  const int tid = threadIdx.x, lane = tid & 63, w = tid >> 6;
  const size_t bid = blockIdx.x;
  f32x4 Sr[4];
  #pragma unroll
  for (int it = 0; it < 4; ++it) Sr[it] = f32x4_zero();
  for (int seg = 0; seg < 8; ++seg){
    const size_t sb  = (bid*8 + seg)*4096;
    const size_t s0b = (bid*64 + (size_t)seg*8)*4096;
    // store entry state (fp32) + write own-rows split planes
    #pragma unroll
    for (int it = 0; it < 4; ++it)
      #pragma unroll
      for (int r = 0; r < 4; ++r){
        int row = 16*w + (lane>>4)*4 + r, col = 16*it + (lane&15);
        S0g[s0b + (size_t)row*64 + col] = Sr[it][r];
        bf2 sp = split2(Sr[it][r]); Sh[row*64+col] = sp.h; Sl[row*64+col] = sp.l;
      }
    __syncthreads();
    for (int j = tid; j < 1024; j += 256){
      float4 pv = ((const float4*)(PsegT + sb))[j];
      bf16x4 ph, pl;
      bf2 u0 = split2(pv.x); ph[0]=u0.h; pl[0]=u0.l;
      bf2 u1 = split2(pv.y); ph[1]=u1.h; pl[1]=u1.l;
      bf2 u2 = split2(pv.z); ph[2]=u2.h; pl[2]=u2.l;
      bf2 u3 = split2(pv.w); ph[3]=u3.h; pl[3]=u3.l;
      ((bf16x4*)Ph)[j] = ph; ((bf16x4*)Pl)[j] = pl;
      ((float4*)Bf)[j] = ((const float4*)(BsegF + sb))[j];
    }
    __syncthreads();
    f32x4 nS[4];
    #pragma unroll
    for (int it = 0; it < 4; ++it) nS[it] = f32x4_zero();
    #pragma unroll
    for (int kk = 0; kk < 2; ++kk){
      bf16x8 aH = frag64(Sh, 16*w, kk, lane), aL = frag64(Sl, 16*w, kk, lane);
      #pragma unroll
      for (int it = 0; it < 4; ++it){
        bf16x8 bH = frag64(Ph, 16*it, kk, lane), bL = frag64(Pl, 16*it, kk, lane);
        nS[it] = mfma16x16x32(aH, bH, nS[it]);
        nS[it] = mfma16x16x32(aH, bL, nS[it]);
        nS[it] = mfma16x16x32(aL, bH, nS[it]);
      }
    }
    #pragma unroll
    for (int it = 0; it < 4; ++it)
      #pragma unroll
      for (int r = 0; r < 4; ++r){
        int row = 16*w + (lane>>4)*4 + r, col = 16*it + (lane&15);
        Sr[it][r] = nS[it][r] + Bf[row*64 + col];
      }
  }
}

// ---------------------------------------------------------------- K4c: within-segment replay (256 blocks, 7 steps)
__global__ __launch_bounds__(256) void k_phaseB3(const float* __restrict__ Pg, const bf16* __restrict__ Bg,
                                                 float* __restrict__ S0g){
  __shared__ bf16 Sh[4096], Sl[4096], Ph[4096], Pl[4096];
  __shared__ bf16 BcS[4096];
  const int tid = threadIdx.x, lane = tid & 63, w = tid >> 6;
  const int seg = blockIdx.x;
  const size_t chain = blockIdx.y;
  const size_t segbase = chain*64 + (size_t)seg*8;
  f32x4 Sr[4];
  // load segment entry state (written by B2)
  #pragma unroll
  for (int it = 0; it < 4; ++it)
    #pragma unroll
    for (int r = 0; r < 4; ++r){
      int row = 16*w + (lane>>4)*4 + r, col = 16*it + (lane&15);
      Sr[it][r] = S0g[segbase*4096 + (size_t)row*64 + col];
    }
  for (int i = 0; i < 7; ++i){
    const size_t cb = (segbase + i)*4096;
    #pragma unroll
    for (int it = 0; it < 4; ++it)
      #pragma unroll
      for (int r = 0; r < 4; ++r){
        int row = 16*w + (lane>>4)*4 + r, col = 16*it + (lane&15);
        bf2 sp = split2(Sr[it][r]); Sh[row*64+col] = sp.h; Sl[row*64+col] = sp.l;
      }
    __syncthreads();
    for (int j = tid; j < 1024; j += 256){
      float4 pv = ((const float4*)(Pg + cb))[j];
      bf16x4 ph, pl;
      bf2 u0 = split2(pv.x); ph[0]=u0.h; pl[0]=u0.l;
      bf2 u1 = split2(pv.y); ph[1]=u1.h; pl[1]=u1.l;
      bf2 u2 = split2(pv.z); ph[2]=u2.h; pl[2]=u2.l;
      bf2 u3 = split2(pv.w); ph[3]=u3.h; pl[3]=u3.l;
      ((bf16x4*)Ph)[j] = ph; ((bf16x4*)Pl)[j] = pl;
    }
    for (int j = tid; j < 512; j += 256)
      ((uint4*)BcS)[j] = ((const uint4*)(Bg + cb))[j];
    __syncthreads();
    f32x4 nS[4];
    #pragma unroll
    for (int it = 0; it < 4; ++it) nS[it] = f32x4_zero();
    #pragma unroll
    for (int kk = 0; kk < 2; ++kk){
      bf16x8 aH = frag64(Sh, 16*w, kk, lane), aL = frag64(Sl, 16*w, kk, lane);
      #pragma unroll
      for (int it = 0; it < 4; ++it){
        bf16x8 bH = frag64(Ph, 16*it, kk, lane), bL = frag64(Pl, 16*it, kk, lane);
        nS[it] = mfma16x16x32(aH, bH, nS[it]);
        nS[it] = mfma16x16x32(aH, bL, nS[it]);
        nS[it] = mfma16x16x32(aL, bH, nS[it]);
      }
    }
    const size_t outb = (segbase + i + 1)*4096;
    #pragma unroll
    for (int it = 0; it < 4; ++it)
      #pragma unroll
      for (int r = 0; r < 4; ++r){
        int row = 16*w + (lane>>4)*4 + r, col = 16*it + (lane&15);
        float v = nS[it][r] + (float)BcS[row*64 + col];
        Sr[it][r] = v;
        S0g[outb + (size_t)row*64 + col] = v;
      }
  }
}

// ---------------------------------------------------------------- K5: phase C, outputs + fused RMSNorm/gate (2048 blocks)
// LDS = 81920 B exactly -> 2 blocks/CU (2 waves/SIMD). All tiles XOR-swizzled; lg cumsum in registers.
__global__ __launch_bounds__(256, 2) void k_phaseC(
    const float* __restrict__ qf32, const bf16* __restrict__ qb16,
    const float* __restrict__ kf32, const bf16* __restrict__ kb16,
    const bf16* __restrict__ gf, const float* __restrict__ logA,
    const float* __restrict__ S0g, const bf16* __restrict__ Wg, const bf16* __restrict__ Dg,
    const float* __restrict__ rms_w, bf16* __restrict__ yh, bf16* __restrict__ yl){
  __shared__ bf16 Qh[4096], Ql[4096], Kh[4096], Klo[4096];
  __shared__ bf16 Wl_[4096], Dl_[4096];
  __shared__ bf16 S0h[4096], S0l[4096];
  __shared__ bf16 AAg[4096];
  __shared__ bf16 BDt[4096];
  const int tid = threadIdx.x, lane = tid & 63, w = tid >> 6;
  const int c = blockIdx.x, h = blockIdx.y, b = blockIdx.z;
  const size_t tokbase = (size_t)b*4096 + (size_t)c*64;
  const size_t cbase = ((size_t)((b*16 + h)*64 + c)) * 4096;

  load_split_tile(qf32, qb16, tokbase, h, Qh, Ql, tid, 256);
  load_split_tile(kf32, kb16, tokbase, h, Kh, Klo, tid, 256);
  for (int i = tid; i < 512; i += 256){
    int r = i >> 3, d = r*8 + ((i&7) ^ (r&7));   // 16B-granular swizzle on the 8-elem block index
    ((uint4*)Wl_)[d] = ((const uint4*)(Wg + cbase))[i];
    ((uint4*)Dl_)[d] = ((const uint4*)(Dg + cbase))[i];
  }
  for (int i = tid; i < 1024; i += 256){
    float4 v = ((const float4*)(S0g + cbase))[i];
    bf16x4 sh, sl;
    bf2 t0 = split2(v.x); sh[0]=t0.h; sl[0]=t0.l;
    bf2 t1 = split2(v.y); sh[1]=t1.h; sl[1]=t1.l;
    bf2 t2 = split2(v.z); sh[2]=t2.h; sl[2]=t2.l;
    bf2 t3 = split2(v.w); sh[3]=t3.h; sl[3]=t3.l;
    int t = i >> 4, off = ((i&15)*4) ^ ((t&7)<<3);
    *(bf16x4*)&S0h[t*64 + off] = sh;
    *(bf16x4*)&S0l[t*64 + off] = sl;
  }
  // per-wave redundant lg cumsum (replaces lg_s/gq_s LDS)
  float la = logA[(tokbase + lane)*16 + h];
  #pragma unroll
  for (int dlt = 1; dlt < 64; dlt <<= 1){
    float o = __shfl_up(la, dlt);
    if (lane >= dlt) la += o;
  }
  __syncthreads();

  { // AAg = mask_incl(Gamma .* QK^T), 3-product
    const int t0 = 16*w;
    #pragma unroll
    for (int tu = 0; tu < 4; ++tu){
      f32x4 accm = f32x4_zero();
      #pragma unroll
      for (int kk = 0; kk < 2; ++kk){
        bf16x8 aH = fragSwz(Qh,  t0,    kk, lane);
        bf16x8 aL = fragSwz(Ql,  t0,    kk, lane);
        bf16x8 bH = fragSwz(Kh,  16*tu, kk, lane);
        bf16x8 bL = fragSwz(Klo, 16*tu, kk, lane);
        accm = mfma16x16x32(aH, bH, accm);
        accm = mfma16x16x32(aH, bL, accm);
        accm = mfma16x16x32(aL, bH, accm);
      }
      #pragma unroll
      for (int r = 0; r < 4; ++r){
        int row = t0 + (lane>>4)*4 + r, col = 16*tu + (lane&15);
        float lgr = __shfl(la, row), lgc = __shfl(la, col);
        float v = (col <= row) ? accm[r]*__expf(lgr - lgc) : 0.f;
        AAg[row*64 + (col ^ ((row&7)<<3))] = (bf16)v;
      }
    }
  }
  { // BDt[i][tau] = Dloc[tau][i] - (S0 W_hat^T)[i][tau]
    const int i0 = 16*w;
    #pragma unroll
    for (int tu = 0; tu < 4; ++tu){
      f32x4 accm = f32x4_zero();
      #pragma unroll
      for (int kk = 0; kk < 2; ++kk){
        bf16x8 aH = fragSwz(S0h, i0,    kk, lane);
        bf16x8 aL = fragSwz(S0l, i0,    kk, lane);
        bf16x8 bb = fragSwz(Wl_, 16*tu, kk, lane);
        accm = mfma16x16x32(aH, bb, accm);
        accm = mfma16x16x32(aL, bb, accm);
      }
      #pragma unroll
      for (int r = 0; r < 4; ++r){
        int row = i0 + (lane>>4)*4 + r, col = 16*tu + (lane&15);
        float v = (float)Dl_[col*64 + (row ^ ((col&7)<<3))] - accm[r];
        BDt[row*64 + (col ^ ((row&7)<<3))] = (bf16)v;
      }
    }
  }
  __syncthreads();
  for (int i = tid; i < 4096; i += 256){
    int t = i >> 6;                              // uniform per wave per iteration
    float gq = __expf(__shfl(la, t));
    float v = gq * ((float)Qh[i] + (float)Ql[i]);  // swizzle is within-row: row scale is layout-agnostic
    bf2 sp = split2(v);
    Qh[i] = sp.h; Ql[i] = sp.l;
  }
  __syncthreads();
  {
    const int t0 = 16*w;
    f32x4 o_acc[4];
    #pragma unroll
    for (int it = 0; it < 4; ++it) o_acc[it] = f32x4_zero();
    #pragma unroll
    for (int kk = 0; kk < 2; ++kk){
      bf16x8 aQh = fragSwz(Qh, t0, kk, lane);
      bf16x8 aQl = fragSwz(Ql, t0, kk, lane);
      bf16x8 aA  = fragSwz(AAg, t0, kk, lane);
      #pragma unroll
      for (int it = 0; it < 4; ++it){
        bf16x8 bSh = fragSwz(S0h, 16*it, kk, lane);
        bf16x8 bSl = fragSwz(S0l, 16*it, kk, lane);
        bf16x8 bD  = fragSwz(BDt, 16*it, kk, lane);
        f32x4 t = o_acc[it];
        t = mfma16x16x32(aQh, bSh, t);
        t = mfma16x16x32(aQh, bSl, t);
        t = mfma16x16x32(aQl, bSh, t);
        t = mfma16x16x32(aA,  bD,  t);
        o_acc[it] = t;
      }
    }
    float rw[4];
    #pragma unroll
    for (int it = 0; it < 4; ++it) rw[it] = rms_w[16*it + (lane&15)];
    #pragma unroll
    for (int r = 0; r < 4; ++r){
      float ss = 0.f;
      #pragma unroll
      for (int it = 0; it < 4; ++it) ss += o_acc[it][r]*o_acc[it][r];
      ss += __shfl_xor(ss, 1); ss += __shfl_xor(ss, 2);
      ss += __shfl_xor(ss, 4); ss += __shfl_xor(ss, 8);
      const float scale = rsqrtf(ss*(1.f/64.f) + 1e-6f);
      const int row = t0 + (lane>>4)*4 + r;
      const size_t tok = tokbase + row;
      #pragma unroll
      for (int it = 0; it < 4; ++it){
        const int col = 16*it + (lane&15);
        float g = (float)gf[tok*1024 + h*64 + col];
        float sg = g / (1.f + __expf(-g));
        float v = o_acc[it][r]*scale*rw[it]*sg;
        bf2 sp = split2(v);
        yh[tok*1024 + h*64 + col] = sp.h;
        yl[tok*1024 + h*64 + col] = sp.l;
      }
    }
  }
}

// ---------------------------------------------------------------- launcher
extern "C" void kernel_launch(void* const* d_in, const int* in_sizes, int n_in,
                              void* d_out, int out_size, void* d_ws, size_t ws_size,
                              hipStream_t stream){
  const float* x     = (const float*)d_in[0];
  const float* Wq    = (const float*)d_in[1];
  const float* Wk    = (const float*)d_in[2];
  const float* Wv    = (const float*)d_in[3];
  const float* Wa    = (const float*)d_in[4];
  const float* Wb    = (const float*)d_in[5];
  const float* A_log = (const float*)d_in[6];
  const float* dt_b  = (const float*)d_in[7];
  const float* Wgt   = (const float*)d_in[8];
  const float* Wo    = (const float*)d_in[9];
  const float* rms_w = (const float*)d_in[10];

  const bool BIG = ws_size >= (size_t)215000000;

  char* ws = (char*)d_ws;
  size_t off = 0;
  auto alloc = [&](size_t bytes)->char*{
    char* p = ws + off;
    off += (bytes + 255) & ~(size_t)255;
    return p;
  };
  const size_t PLANE = (size_t)8192*1024*2;   // bf16 activation plane (16 MiB)
  const size_t WPL   = (size_t)1024*1024*2;   // bf16 weight plane (2 MiB)
  bf16* xh  = (bf16*)alloc(PLANE);            // region also hosts Pg (A->B3), then yh
  bf16* xl  = (bf16*)alloc(PLANE);
  bf16* wqh = (bf16*)alloc(WPL); bf16* wql = (bf16*)alloc(WPL);   // wqh..wgl also hosts Bg
  bf16* wkh = (bf16*)alloc(WPL); bf16* wkl = (bf16*)alloc(WPL);
  bf16* wvh = (bf16*)alloc(WPL); bf16* wvl = (bf16*)alloc(WPL);
  bf16* wgh = (bf16*)alloc(WPL); bf16* wgl = (bf16*)alloc(WPL);
  bf16* woh = (bf16*)alloc(WPL); bf16* wol = (bf16*)alloc(WPL);
  float* WaT = (float*)alloc((size_t)16*1024*4);
  float* WbT = (float*)alloc((size_t)16*1024*4);
  float* qf = nullptr; bf16* qb = nullptr;
  float* kf = nullptr; bf16* kb = nullptr;
  if (BIG){ qf = (float*)alloc((size_t)8192*1024*4); kf = (float*)alloc((size_t)8192*1024*4); }
  else    { qb = (bf16*) alloc(PLANE);               kb = (bf16*) alloc(PLANE); }
  float* vf  = (float*)alloc((size_t)8192*1024*4);  // dead after phase A -> hosts S0g
  bf16* gfb  = (bf16*)alloc(PLANE);
  float* logA  = (float*)alloc((size_t)8192*16*4);
  float* betap = (float*)alloc((size_t)8192*16*4);
  bf16* Wg  = (bf16*)alloc((size_t)2048*4096*2);
  bf16* Dg  = (bf16*)alloc((size_t)2048*4096*2);
  float* Pg  = (float*)xh;            // 33.5 MiB fp32 in xh+xl (dead between GEMMs and phase C)
  float* S0g = vf;                    // 33.5 MiB fp32 (vf dead after phase A)
  bf16* Bg   = wqh;                   // 16 MiB bf16 (projection weights dead)
  float* PsegT = (float*)d_out;       // 4 MiB scratch in d_out (overwritten by final GEMM)
  float* BsegF = (float*)d_out + 1048576;  // next 4 MiB
  bf16* yh = xh;                      // phase C outputs (Pg dead after B3)
  bf16* yl = xl;

  k_cvt_x<<<8192, 256, 0, stream>>>(x, xh, xl, 2097152);
  k_transpose_w<<<dim3(32,32), 256, 0, stream>>>(Wq,  wqh, wql);
  k_transpose_w<<<dim3(32,32), 256, 0, stream>>>(Wk,  wkh, wkl);
  k_transpose_w<<<dim3(32,32), 256, 0, stream>>>(Wv,  wvh, wvl);
  k_transpose_w<<<dim3(32,32), 256, 0, stream>>>(Wgt, wgh, wgl);
  k_transpose_w<<<dim3(32,32), 256, 0, stream>>>(Wo,  woh, wol);
  k_transpose_ab<<<64, 256, 0, stream>>>(Wa, Wb, WaT, WbT);

  if (BIG){
    k_gemm1<<<dim3(64,8), 256, 0, stream>>>(xh, wqh, nullptr, qf);
    k_gemm1<<<dim3(64,8), 256, 0, stream>>>(xh, wkh, nullptr, kf);
  } else {
    k_gemm1<<<dim3(64,8), 256, 0, stream>>>(xh, wqh, qb, nullptr);
    k_gemm1<<<dim3(64,8), 256, 0, stream>>>(xh, wkh, kb, nullptr);
  }
  k_gemm1<<<dim3(64,8), 256, 0, stream>>>(xh, wvh, nullptr, vf);
  k_gemm1<<<dim3(64,8), 256, 0, stream>>>(xh, wgh, gfb, nullptr);

  k_alphabeta<<<1024, 256, 0, stream>>>(x, WaT, WbT, A_log, dt_b, logA, betap);
  if (BIG) k_norm_f32<<<512, 256, 0, stream>>>(qf, kf);
  else     k_norm_b16<<<512, 256, 0, stream>>>(qb, kb);

  k_phaseA<<<dim3(64,16,2), 128, 0, stream>>>(kf, kb, vf, logA, betap, Wg, Dg, Pg, Bg);
  k_phaseB1<<<dim3(8,32), 256, 0, stream>>>(Pg, Bg, PsegT, BsegF);
  k_phaseB2<<<32, 256, 0, stream>>>(PsegT, BsegF, S0g);
  k_phaseB3<<<dim3(8,32), 256, 0, stream>>>(Pg, Bg, S0g);
  k_phaseC<<<dim3(64,16,2), 256, 0, stream>>>(qf, qb, kf, kb, gfb, logA, S0g, Wg, Dg, rms_w, yh, yl);

  k_gemm3<<<dim3(64,8), 256, 0, stream>>>(yh, yl, woh, wol, nullptr, (float*)d_out);
}

// Round 3
// 594.185 us; speedup vs baseline: 1.2970x; 1.1610x over previous
//
#include <hip/hip_runtime.h>
#include <cstdint>
#include <cstddef>

typedef __bf16 bf16;
typedef __bf16 bf16x4 __attribute__((ext_vector_type(4)));
typedef __bf16 bf16x8 __attribute__((ext_vector_type(8)));
typedef float  f32x4  __attribute__((ext_vector_type(4)));

#define GLD_LDS16(gp, lp) \
  __builtin_amdgcn_global_load_lds((__attribute__((address_space(1))) void*)(gp), \
                                   (__attribute__((address_space(3))) void*)(lp), 16, 0, 0)

__device__ __forceinline__ f32x4 f32x4_zero(){ f32x4 v; v[0]=0.f; v[1]=0.f; v[2]=0.f; v[3]=0.f; return v; }

__device__ __forceinline__ f32x4 mfma16x16x32(bf16x8 a, bf16x8 b, f32x4 c){
  return __builtin_amdgcn_mfma_f32_16x16x32_bf16(a, b, c, 0, 0, 0);
}
// fragment of a 64-col bf16 LDS array (stride 64), LINEAR layout (phaseB kernels)
__device__ __forceinline__ bf16x8 frag64(const bf16* base, int row0, int kk, int lane){
  return *(const bf16x8*)&base[(row0 + (lane&15))*64 + kk*32 + (lane>>4)*8];
}
// fragment of a 64-col bf16 LDS array with XOR bank-swizzle: elem ^= (row&7)<<3
// (16B-granular swizzle; keeps ds_read_b128 16B-aligned; 16-way conflict -> 2-way)
__device__ __forceinline__ bf16x8 fragSwz(const bf16* base, int row0, int kk, int lane){
  const int row = row0 + (lane&15);
  const int off = (kk*32 + (lane>>4)*8) ^ ((row&7)<<3);
  return *(const bf16x8*)&base[row*64 + off];
}
struct bf2 { bf16 h, l; };
__device__ __forceinline__ bf2 split2(float v){
  bf2 r; r.h = (bf16)v; r.l = (bf16)(v - (float)r.h); return r;
}

// ---------------------------------------------------------------- K0a: x -> hi/lo bf16 planes
__global__ __launch_bounds__(256) void k_cvt_x(const float* __restrict__ x,
                                               bf16* __restrict__ xh, bf16* __restrict__ xl, int n4){
  int i = blockIdx.x*256 + threadIdx.x;
  if (i < n4){
    float4 v = ((const float4*)x)[i];
    bf16x4 h, l;
    bf2 t0 = split2(v.x); h[0]=t0.h; l[0]=t0.l;
    bf2 t1 = split2(v.y); h[1]=t1.h; l[1]=t1.l;
    bf2 t2 = split2(v.z); h[2]=t2.h; l[2]=t2.l;
    bf2 t3 = split2(v.w); h[3]=t3.h; l[3]=t3.l;
    ((bf16x4*)xh)[i] = h;
    ((bf16x4*)xl)[i] = l;
  }
}

// ---------------------------------------------------------------- K0b: W[k][n] -> Wt hi/lo [n][k]
__global__ __launch_bounds__(256) void k_transpose_w(const float* __restrict__ W,
                                                     bf16* __restrict__ Wth, bf16* __restrict__ Wtl){
  __shared__ float tile[32][33];
  const int k0 = blockIdx.x*32, n0 = blockIdx.y*32;
  const int r = threadIdx.x >> 3, c4 = (threadIdx.x & 7)*4;
  float4 v = *(const float4*)&W[(size_t)(k0+r)*1024 + n0 + c4];
  tile[r][c4+0]=v.x; tile[r][c4+1]=v.y; tile[r][c4+2]=v.z; tile[r][c4+3]=v.w;
  __syncthreads();
  bf16x4 h, l;
  bf2 t0 = split2(tile[c4+0][r]); h[0]=t0.h; l[0]=t0.l;
  bf2 t1 = split2(tile[c4+1][r]); h[1]=t1.h; l[1]=t1.l;
  bf2 t2 = split2(tile[c4+2][r]); h[2]=t2.h; l[2]=t2.l;
  bf2 t3 = split2(tile[c4+3][r]); h[3]=t3.h; l[3]=t3.l;
  *(bf16x4*)&Wth[(size_t)(n0+r)*1024 + k0 + c4] = h;
  *(bf16x4*)&Wtl[(size_t)(n0+r)*1024 + k0 + c4] = l;
}

// ---------------------------------------------------------------- K0c: Walpha/Wbeta [1024][16] -> WabT hi/lo bf16 [32][1024]
__global__ __launch_bounds__(256) void k_transpose_ab(const float* __restrict__ Wa, const float* __restrict__ Wb,
                                                      bf16* __restrict__ WabTh, bf16* __restrict__ WabTl){
  int p = blockIdx.x*256 + threadIdx.x;
  if (p < 32768){
    int o = p >> 10, k = p & 1023;
    float v = (o < 16) ? Wa[k*16 + o] : Wb[k*16 + (o-16)];
    bf2 s = split2(v);
    WabTh[p] = s.h;
    WabTl[p] = s.l;
  }
}

// ---------------------------------------------------------------- K1: split-bf16 MFMA GEMM (3-product), K=1024
__global__ __launch_bounds__(256) void k_gemm3(const bf16* __restrict__ Ah, const bf16* __restrict__ Al,
                                               const bf16* __restrict__ Bth, const bf16* __restrict__ Btl,
                                               bf16* __restrict__ Cb, float* __restrict__ Cf){
  __shared__ bf16 Ash[128*32], Asl[128*32];
  __shared__ bf16 Bsh[128*32], Bsl[128*32];
  const int tid = threadIdx.x, lane = tid & 63, w = tid >> 6;
  const int wm = w >> 1, wn = w & 1;
  const size_t m0 = (size_t)blockIdx.x * 128;
  const size_t n0 = (size_t)blockIdx.y * 128;
  f32x4 acc[4][4];
  #pragma unroll
  for (int i=0;i<4;++i)
    #pragma unroll
    for (int j=0;j<4;++j) acc[i][j] = f32x4_zero();

  for (int k0 = 0; k0 < 1024; k0 += 32){
    __syncthreads();
    #pragma unroll
    for (int j = 0; j < 2; ++j){
      const int rbase = 32*w + 16*j;
      const int r = rbase + (lane >> 2);
      const int kk = k0 + (lane & 3)*8;
      GLD_LDS16(&Ah [(m0 + r)*1024 + kk], &Ash[rbase*32]);
      GLD_LDS16(&Al [(m0 + r)*1024 + kk], &Asl[rbase*32]);
      GLD_LDS16(&Bth[(n0 + r)*1024 + kk], &Bsh[rbase*32]);
      GLD_LDS16(&Btl[(n0 + r)*1024 + kk], &Bsl[rbase*32]);
    }
    __syncthreads();
    bf16x8 ah[4], al[4], bh[4], bl[4];
    #pragma unroll
    for (int t=0;t<4;++t){
      ah[t] = *(const bf16x8*)&Ash[(64*wm + 16*t + (lane&15))*32 + (lane>>4)*8];
      al[t] = *(const bf16x8*)&Asl[(64*wm + 16*t + (lane&15))*32 + (lane>>4)*8];
      bh[t] = *(const bf16x8*)&Bsh[(64*wn + 16*t + (lane&15))*32 + (lane>>4)*8];
      bl[t] = *(const bf16x8*)&Bsl[(64*wn + 16*t + (lane&15))*32 + (lane>>4)*8];
    }
    #pragma unroll
    for (int i=0;i<4;++i)
      #pragma unroll
      for (int j=0;j<4;++j){
        f32x4 t = acc[i][j];
        t = mfma16x16x32(ah[i], bh[j], t);
        t = mfma16x16x32(ah[i], bl[j], t);
        t = mfma16x16x32(al[i], bh[j], t);
        acc[i][j] = t;
      }
  }
  #pragma unroll
  for (int i=0;i<4;++i)
    #pragma unroll
    for (int j=0;j<4;++j)
      #pragma unroll
      for (int r=0;r<4;++r){
        size_t row = m0 + 64*wm + 16*i + (lane>>4)*4 + r;
        size_t col = n0 + 64*wn + 16*j + (lane&15);
        float v = acc[i][j][r];
        if (Cf) Cf[row*1024 + col] = v;
        else    Cb[row*1024 + col] = (bf16)v;
      }
}

// ---------------------------------------------------------------- K1b: single-bf16 MFMA GEMM, K=1024
__global__ __launch_bounds__(256) void k_gemm1(const bf16* __restrict__ Ah, const bf16* __restrict__ Bth,
                                               bf16* __restrict__ Cb, float* __restrict__ Cf){
  __shared__ bf16 Ash[128*32];
  __shared__ bf16 Bsh[128*32];
  const int tid = threadIdx.x, lane = tid & 63, w = tid >> 6;
  const int wm = w >> 1, wn = w & 1;
  const size_t m0 = (size_t)blockIdx.x * 128;
  const size_t n0 = (size_t)blockIdx.y * 128;
  f32x4 acc[4][4];
  #pragma unroll
  for (int i=0;i<4;++i)
    #pragma unroll
    for (int j=0;j<4;++j) acc[i][j] = f32x4_zero();

  for (int k0 = 0; k0 < 1024; k0 += 32){
    __syncthreads();
    #pragma unroll
    for (int j = 0; j < 2; ++j){
      const int rbase = 32*w + 16*j;
      const int r = rbase + (lane >> 2);
      const int kk = k0 + (lane & 3)*8;
      GLD_LDS16(&Ah [(m0 + r)*1024 + kk], &Ash[rbase*32]);
      GLD_LDS16(&Bth[(n0 + r)*1024 + kk], &Bsh[rbase*32]);
    }
    __syncthreads();
    bf16x8 ah[4], bh[4];
    #pragma unroll
    for (int t=0;t<4;++t){
      ah[t] = *(const bf16x8*)&Ash[(64*wm + 16*t + (lane&15))*32 + (lane>>4)*8];
      bh[t] = *(const bf16x8*)&Bsh[(64*wn + 16*t + (lane&15))*32 + (lane>>4)*8];
    }
    #pragma unroll
    for (int i=0;i<4;++i)
      #pragma unroll
      for (int j=0;j<4;++j)
        acc[i][j] = mfma16x16x32(ah[i], bh[j], acc[i][j]);
  }
  #pragma unroll
  for (int i=0;i<4;++i)
    #pragma unroll
    for (int j=0;j<4;++j)
      #pragma unroll
      for (int r=0;r<4;++r){
        size_t row = m0 + 64*wm + 16*i + (lane>>4)*4 + r;
        size_t col = n0 + 64*wn + 16*j + (lane&15);
        float v = acc[i][j][r];
        if (Cf) Cf[row*1024 + col] = v;
        else    Cb[row*1024 + col] = (bf16)v;
      }
}

// ---------------------------------------------------------------- K2: alpha/beta projections as split-bf16 MFMA GEMM
// M=8192, N=32 (16 alpha | 16 beta), K=1024. 256 blocks x 32 rows, 4 waves (1 16x16 tile each),
// K-step 64, double-buffered LDS via global_load_lds with pre-swizzled global source (linear
// LDS dest + swizzled read). B frags (128 KB total, shared by all blocks) read straight from
// global -> L2-hot. Fused softplus/sigmoid epilogue. Replaces the latency-bound scalar GEMV
// (per-lane 4KB-strided W rows, 256-deep dependent load chain -> 120us @ 4% VALUBusy).
__global__ __launch_bounds__(256) void k_ab_gemm(const bf16* __restrict__ xh, const bf16* __restrict__ xl,
    const bf16* __restrict__ WabTh, const bf16* __restrict__ WabTl,
    const float* __restrict__ A_log, const float* __restrict__ dt_bias,
    float* __restrict__ logA, float* __restrict__ betap){
  __shared__ bf16 Ash[2][2048], Asl[2][2048];   // 32 rows x 64 k per buffer
  const int tid = threadIdx.x, lane = tid & 63, w = tid >> 6;
  const int mt = w >> 1, nt = w & 1;
  const size_t m0 = (size_t)blockIdx.x * 32;
  // staging source: thread t -> LDS bytes t*16.. (linear); logical row = t>>3,
  // logical col = 8*((t&7)^(row&7))  (inverse of fragSwz's XOR)
  const int srow = tid >> 3;
  const int scol = 8*((tid & 7) ^ (srow & 7));
  const size_t sg = (m0 + srow)*1024 + scol;

  f32x4 acc = f32x4_zero();
  GLD_LDS16(&xh[sg], &Ash[0][w*512]);
  GLD_LDS16(&xl[sg], &Asl[0][w*512]);
  for (int s = 0; s < 16; ++s){
    const int cur = s & 1;
    __syncthreads();                    // implicit vmcnt(0): buf[cur] staged
    if (s + 1 < 16){
      const size_t g = sg + (size_t)(s+1)*64;
      GLD_LDS16(&xh[g], &Ash[cur^1][w*512]);
      GLD_LDS16(&xl[g], &Asl[cur^1][w*512]);
    }
    const int k0 = s*64;
    #pragma unroll
    for (int kk = 0; kk < 2; ++kk){
      bf16x8 aH = fragSwz(Ash[cur], 16*mt, kk, lane);
      bf16x8 aL = fragSwz(Asl[cur], 16*mt, kk, lane);
      const size_t bo = (size_t)(16*nt + (lane&15))*1024 + k0 + kk*32 + (lane>>4)*8;
      bf16x8 bH = *(const bf16x8*)&WabTh[bo];
      bf16x8 bL = *(const bf16x8*)&WabTl[bo];
      acc = mfma16x16x32(aH, bH, acc);
      acc = mfma16x16x32(aH, bL, acc);
      acc = mfma16x16x32(aL, bH, acc);
    }
  }
  const int col = lane & 15;
  #pragma unroll
  for (int r = 0; r < 4; ++r){
    const size_t row = m0 + 16*mt + (lane>>4)*4 + r;
    float v = acc[r];
    if (nt == 0){
      float z = v + dt_bias[col];
      float dt = (z > 20.f) ? z : log1pf(expf(z));
      logA[row*16 + col] = -expf(A_log[col]) * dt;   // log(alpha_t)
    } else {
      betap[row*16 + col] = 1.f/(1.f + expf(-v));    // beta_t
    }
  }
}

// ---------------------------------------------------------------- K2b (BIG): in-place fp32 l2norm of q (/8) and k
__global__ __launch_bounds__(256) void k_norm_f32(float* __restrict__ qf, float* __restrict__ kf){
  const size_t p = (size_t)blockIdx.x*256 + threadIdx.x;  // (token,head)
  {
    float4* q4 = (float4*)(qf + p*64);
    float4 v[16]; float s = 0.f;
    #pragma unroll
    for (int i=0;i<16;++i){ v[i]=q4[i]; s += v[i].x*v[i].x + v[i].y*v[i].y + v[i].z*v[i].z + v[i].w*v[i].w; }
    float sc = 0.125f / fmaxf(sqrtf(s), 1e-12f);
    #pragma unroll
    for (int i=0;i<16;++i){ v[i].x*=sc; v[i].y*=sc; v[i].z*=sc; v[i].w*=sc; q4[i]=v[i]; }
  }
  {
    float4* k4 = (float4*)(kf + p*64);
    float4 v[16]; float s = 0.f;
    #pragma unroll
    for (int i=0;i<16;++i){ v[i]=k4[i]; s += v[i].x*v[i].x + v[i].y*v[i].y + v[i].z*v[i].z + v[i].w*v[i].w; }
    float sc = 1.0f / fmaxf(sqrtf(s), 1e-12f);
    #pragma unroll
    for (int i=0;i<16;++i){ v[i].x*=sc; v[i].y*=sc; v[i].z*=sc; v[i].w*=sc; k4[i]=v[i]; }
  }
}

// ---------------------------------------------------------------- K2b (SMALL): in-place bf16 l2norm
__global__ __launch_bounds__(256) void k_norm_b16(bf16* __restrict__ qb, bf16* __restrict__ kb){
  const size_t p = (size_t)blockIdx.x*256 + threadIdx.x;
  bf16* q = qb + p*64;
  bf16* k = kb + p*64;
  bf16x8 qv[8], kv[8];
  float sq = 0.f, sk = 0.f;
  #pragma unroll
  for (int i=0;i<8;++i){
    qv[i] = ((const bf16x8*)q)[i];
    kv[i] = ((const bf16x8*)k)[i];
    #pragma unroll
    for (int j=0;j<8;++j){ float a=(float)qv[i][j]; sq+=a*a; float b=(float)kv[i][j]; sk+=b*b; }
  }
  float scq = 0.125f / fmaxf(sqrtf(sq), 1e-12f);
  float sck = 1.0f   / fmaxf(sqrtf(sk), 1e-12f);
  #pragma unroll
  for (int i=0;i<8;++i){
    bf16x8 oq, ok;
    #pragma unroll
    for (int j=0;j<8;++j){ oq[j]=(bf16)((float)qv[i][j]*scq); ok[j]=(bf16)((float)kv[i][j]*sck); }
    ((bf16x8*)q)[i] = oq; ((bf16x8*)k)[i] = ok;
  }
}

// helper: load a 64x64 head-tile (fp32 or bf16 source) and split into hi/lo bf16 LDS planes,
// stride 64, XOR-swizzled: elem_off ^= (row&7)<<3  (matches fragSwz)
__device__ __forceinline__ void load_split_tile(const float* f32, const bf16* b16,
                                                size_t tokbase, int h,
                                                bf16* Lh, bf16* Ll, int tid, int nthr){
  for (int i = tid; i < 1024; i += nthr){
    int t = i >> 4, c4 = (i & 15)*4;
    const size_t g = (tokbase + t)*1024 + (size_t)h*64 + c4;
    float4 v;
    if (f32) v = *(const float4*)&f32[g];
    else { bf16x4 b = *(const bf16x4*)&b16[g]; v.x=(float)b[0]; v.y=(float)b[1]; v.z=(float)b[2]; v.w=(float)b[3]; }
    bf16x4 hh, ll;
    bf2 s0 = split2(v.x); hh[0]=s0.h; ll[0]=s0.l;
    bf2 s1 = split2(v.y); hh[1]=s1.h; ll[1]=s1.l;
    bf2 s2 = split2(v.z); hh[2]=s2.h; ll[2]=s2.l;
    bf2 s3 = split2(v.w); hh[3]=s3.h; ll[3]=s3.l;
    const int off = c4 ^ ((t&7)<<3);
    *(bf16x4*)&Lh[t*64 + off] = hh;
    *(bf16x4*)&Ll[t*64 + off] = ll;
  }
}

// ---------------------------------------------------------------- K3: phase A (2048 blocks, 128 thr)
// LDS = 40960 B -> 4 blocks/CU possible. NO min-waves clause: the solve holds Xv[64]+d[64]
// (128 floats) live per thread; capping VGPRs to 128 (round 1) spilled ~96 floats/thread to
// scratch (+98 MB HBM writes, +49 MB reads, dur 129->177us). VGPR ~184 still gives
// 2 waves/SIMD (<=256) = 4 blocks/CU with this LDS footprint.
__global__ __launch_bounds__(128) void k_phaseA(const float* __restrict__ kf32, const bf16* __restrict__ kb16,
    const float* __restrict__ vf, const float* __restrict__ logA, const float* __restrict__ betap,
    bf16* __restrict__ Wg, bf16* __restrict__ Dg, float* __restrict__ Pg, bf16* __restrict__ Bg){
  __shared__ bf16  Kh[64*64], Kl_[64*64];
  __shared__ float Ef[64*64];
  __shared__ bf16  KtT[64*64];   // K_til^T [j][t], swizzled
  bf16* DT = (bf16*)Ef;          // Dsol^T [i][t], swizzled (overlay after solve)
  bf16* WT = ((bf16*)Ef) + 4096; // Wsol^T [i][t], swizzled (overlay after solve)
  const int tid = threadIdx.x, lane = tid & 63, wid = tid >> 6;
  const int c = blockIdx.x, h = blockIdx.y, b = blockIdx.z;
  const size_t tokbase = (size_t)b*4096 + (size_t)c*64;
  const size_t cbase = ((size_t)((b*16 + h)*64 + c)) * 4096;

  load_split_tile(kf32, kb16, tokbase, h, Kh, Kl_, tid, 128);
  const float bet = betap[(tokbase + lane)*16 + h];   // per-lane beta_t, t = lane
  if (tid < 64){
    float la = logA[(tokbase + tid)*16 + h];
    #pragma unroll
    for (int dlt = 1; dlt < 64; dlt <<= 1){
      float o = __shfl_up(la, dlt);
      if (lane >= dlt) la += o;
    }
    Ef[tid] = la;                // lg cumsum lives in (never-read) E row 0
  }
  __syncthreads();

  // E[t][tau] = (gamma_t/gamma_tau)*(k_t . k_tau), strictly lower; else 0  (3-product MFMA)
  #pragma unroll
  for (int tt = 0; tt < 2; ++tt){
    const int t0 = 32*wid + 16*tt;
    #pragma unroll
    for (int tu = 0; tu < 4; ++tu){
      f32x4 accm = f32x4_zero();
      #pragma unroll
      for (int kk = 0; kk < 2; ++kk){
        bf16x8 aH = fragSwz(Kh,  t0,    kk, lane);
        bf16x8 aL = fragSwz(Kl_, t0,    kk, lane);
        bf16x8 bH = fragSwz(Kh,  16*tu, kk, lane);
        bf16x8 bL = fragSwz(Kl_, 16*tu, kk, lane);
        accm = mfma16x16x32(aH, bH, accm);
        accm = mfma16x16x32(aH, bL, accm);
        accm = mfma16x16x32(aL, bH, accm);
      }
      #pragma unroll
      for (int r = 0; r < 4; ++r){
        int row = t0 + (lane>>4)*4 + r, col = 16*tu + (lane&15);
        float ev = (col < row) ? accm[r]*__expf(Ef[row] - Ef[col]) : 0.f;
        if (row > 0) Ef[row*64 + col] = ev;   // row 0 never read; keeps lg intact
      }
    }
  }
  // K_til^T[j][t] = (gamma_L/gamma_t) * k[t][j]  (single bf16, swizzled store)
  {
    const float lgL = Ef[63];
    for (int i = tid; i < 4096; i += 128){
      int t = i & 63, j = i >> 6;
      int ks = j ^ ((t&7)<<3);
      float kv = (float)Kh[t*64 + ks] + (float)Kl_[t*64 + ks];
      KtT[j*64 + (t ^ ((j&7)<<3))] = (bf16)(__expf(lgL - Ef[t]) * kv);
    }
  }
  __syncthreads();

  const float gL = __expf(Ef[63]);   // hoisted: Ef row 0 is clobbered by the WT/DT overlay below

  // blocked forward substitution: (I + diag(beta)E) X = diag(beta) R
  {
    float Xv[64], d[64];
    if (wid == 0){
      #pragma unroll
      for (int t = 0; t < 64; ++t)
        Xv[t] = vf[(tokbase + t)*1024 + h*64 + lane];
    } else {
      #pragma unroll
      for (int t = 0; t < 64; ++t){
        int ks = lane ^ ((t&7)<<3);
        Xv[t] = __expf(Ef[t]) * ((float)Kh[t*64 + ks] + (float)Kl_[t*64 + ks]);
      }
    }
    #pragma unroll
    for (int bi = 0; bi < 4; ++bi){
      float pre[16];
      #pragma unroll
      for (int tt = 0; tt < 16; ++tt){
        const int t = 16*bi + tt;
        float a0=0.f,a1=0.f,a2=0.f,a3=0.f;
        #pragma unroll
        for (int r4 = 0; r4 < 4*bi; ++r4){
          float4 e = *(const float4*)&Ef[t*64 + r4*4];
          a0 += e.x * d[r4*4+0];
          a1 += e.y * d[r4*4+1];
          a2 += e.z * d[r4*4+2];
          a3 += e.w * d[r4*4+3];
        }
        pre[tt] = (a0+a1)+(a2+a3);
      }
      #pragma unroll
      for (int tt = 0; tt < 16; ++tt){
        const int t = 16*bi + tt;
        float s = pre[tt];
        #pragma unroll
        for (int j = 0; j < 16; ++j)
          if (j < tt) s += Ef[t*64 + 16*bi + j] * d[16*bi + j];
        d[t] = __shfl(bet, t) * (Xv[t] - s);
      }
    }
    __syncthreads();    // all Ef reads done (both waves) -> safe to overlay WT/DT onto Ef
    bf16* myT = wid ? WT : DT;
    #pragma unroll
    for (int s4 = 0; s4 < 16; ++s4){
      bf16x4 v4;
      v4[0]=(bf16)d[s4*4+0]; v4[1]=(bf16)d[s4*4+1];
      v4[2]=(bf16)d[s4*4+2]; v4[3]=(bf16)d[s4*4+3];
      *(bf16x4*)&myT[lane*64 + ((s4*4) ^ ((lane&7)<<3))] = v4;
    }
    bf16* myG = wid ? Wg : Dg;
    #pragma unroll
    for (int t = 0; t < 64; ++t)
      myG[cbase + (size_t)t*64 + lane] = (bf16)d[t];
  }
  __syncthreads();

  // P^T[j][i] = gamma_L*I - sum_t K_til[t][j]*Wsol[t][i]  (wave0, MFMA, fp32 out)
  // B[i][j]   =              sum_t Dsol[t][i]*K_til[t][j]  (wave1, MFMA, bf16 out)
  if (wid == 0){
    #pragma unroll
    for (int tj = 0; tj < 4; ++tj)
      #pragma unroll
      for (int ti = 0; ti < 4; ++ti){
        f32x4 acc = f32x4_zero();
        #pragma unroll
        for (int kk = 0; kk < 2; ++kk)
          acc = mfma16x16x32(fragSwz(KtT, 16*tj, kk, lane), fragSwz(WT, 16*ti, kk, lane), acc);
        #pragma unroll
        for (int r = 0; r < 4; ++r){
          int row = 16*tj + (lane>>4)*4 + r, col = 16*ti + (lane&15);
          Pg[cbase + (size_t)row*64 + col] = ((row == col) ? gL : 0.f) - acc[r];
        }
      }
  } else {
    #pragma unroll
    for (int ti = 0; ti < 4; ++ti)
      #pragma unroll
      for (int tj = 0; tj < 4; ++tj){
        f32x4 acc = f32x4_zero();
        #pragma unroll
        for (int kk = 0; kk < 2; ++kk)
          acc = mfma16x16x32(fragSwz(DT, 16*ti, kk, lane), fragSwz(KtT, 16*tj, kk, lane), acc);
        #pragma unroll
        for (int r = 0; r < 4; ++r){
          int row = 16*ti + (lane>>4)*4 + r, col = 16*tj + (lane&15);
          Bg[cbase + (size_t)row*64 + col] = (bf16)acc[r];
        }
      }
  }
}

// ---------------------------------------------------------------- K4a: segment composition (256 blocks: 8 seg x 32 chains)
// (Pseg, Bseg) = (P_{c0},B_{c0}) ∘ ... ∘ (P_{c7},B_{c7});  Pacc/Bacc fp32 in registers.
__global__ __launch_bounds__(256) void k_phaseB1(const float* __restrict__ Pg, const bf16* __restrict__ Bg,
                                                 float* __restrict__ PsegT, float* __restrict__ BsegF){
  __shared__ bf16 PaccH[4096], PaccL[4096], BaccH[4096], BaccL[4096];
  __shared__ bf16 PcH[4096], PcL[4096];
  __shared__ bf16 BcS[4096];
  const int tid = threadIdx.x, lane = tid & 63, w = tid >> 6;
  const int seg = blockIdx.x;
  const size_t chain = blockIdx.y;
  f32x4 Pr[4], Br[4];
  #pragma unroll
  for (int it = 0; it < 4; ++it){
    #pragma unroll
    for (int r = 0; r < 4; ++r){
      int row = 16*w + (lane>>4)*4 + r, col = 16*it + (lane&15);
      Pr[it][r] = (row == col) ? 1.f : 0.f;   // Pacc = I
      Br[it][r] = 0.f;                        // Bacc = 0
    }
  }
  for (int i = 0; i < 8; ++i){
    const size_t cb = (chain*64 + (size_t)seg*8 + i)*4096;
    // write own-wave rows of Pacc/Bacc split planes
    #pragma unroll
    for (int it = 0; it < 4; ++it)
      #pragma unroll
      for (int r = 0; r < 4; ++r){
        int row = 16*w + (lane>>4)*4 + r, col = 16*it + (lane&15);
        bf2 sp = split2(Pr[it][r]); PaccH[row*64+col] = sp.h; PaccL[row*64+col] = sp.l;
        bf2 sb = split2(Br[it][r]); BaccH[row*64+col] = sb.h; BaccL[row*64+col] = sb.l;
      }
    __syncthreads();   // prev iter's MFMA done -> safe to overwrite PcH/L
    for (int j = tid; j < 1024; j += 256){
      float4 pv = ((const float4*)(Pg + cb))[j];
      bf16x4 ph, pl;
      bf2 u0 = split2(pv.x); ph[0]=u0.h; pl[0]=u0.l;
      bf2 u1 = split2(pv.y); ph[1]=u1.h; pl[1]=u1.l;
      bf2 u2 = split2(pv.z); ph[2]=u2.h; pl[2]=u2.l;
      bf2 u3 = split2(pv.w); ph[3]=u3.h; pl[3]=u3.l;
      ((bf16x4*)PcH)[j] = ph; ((bf16x4*)PcL)[j] = pl;
    }
    for (int j = tid; j < 512; j += 256)
      ((uint4*)BcS)[j] = ((const uint4*)(Bg + cb))[j];
    __syncthreads();
    f32x4 nP[4], nB[4];
    #pragma unroll
    for (int it = 0; it < 4; ++it){ nP[it] = f32x4_zero(); nB[it] = f32x4_zero(); }
    #pragma unroll
    for (int kk = 0; kk < 2; ++kk){
      bf16x8 aPH = frag64(PaccH, 16*w, kk, lane), aPL = frag64(PaccL, 16*w, kk, lane);
      bf16x8 aBH = frag64(BaccH, 16*w, kk, lane), aBL = frag64(BaccL, 16*w, kk, lane);
      #pragma unroll
      for (int it = 0; it < 4; ++it){
        bf16x8 bH = frag64(PcH, 16*it, kk, lane), bL = frag64(PcL, 16*it, kk, lane);
        nP[it] = mfma16x16x32(aPH, bH, nP[it]);
        nP[it] = mfma16x16x32(aPH, bL, nP[it]);
        nP[it] = mfma16x16x32(aPL, bH, nP[it]);
        nB[it] = mfma16x16x32(aBH, bH, nB[it]);
        nB[it] = mfma16x16x32(aBH, bL, nB[it]);
        nB[it] = mfma16x16x32(aBL, bH, nB[it]);
      }
    }
    #pragma unroll
    for (int it = 0; it < 4; ++it)
      #pragma unroll
      for (int r = 0; r < 4; ++r){
        int row = 16*w + (lane>>4)*4 + r, col = 16*it + (lane&15);
        Pr[it][r] = nP[it][r];
        Br[it][r] = nB[it][r] + (float)BcS[row*64 + col];
      }
  }
  const size_t sb = (chain*8 + seg)*4096;
  #pragma unroll
  for (int it = 0; it < 4; ++it)
    #pragma unroll
    for (int r = 0; r < 4; ++r){
      int row = 16*w + (lane>>4)*4 + r, col = 16*it + (lane&15);
      PsegT[sb + (size_t)col*64 + row] = Pr[it][r];   // transposed (B-operand layout)
      BsegF[sb + (size_t)row*64 + col] = Br[it][r];   // natural
    }
}

// ---------------------------------------------------------------- K4b: segment-level scan (32 blocks, 8 steps)
__global__ __launch_bounds__(256) void k_phaseB2(const float* __restrict__ PsegT, const float* __restrict__ BsegF,
                                                 float* __restrict__ S0g){
  __shared__ bf16 Sh[4096], Sl[4096], Ph[4096], Pl[4096];
  __shared__ float Bf[4096];
  const int tid = threadIdx.x, lane = tid & 63, w = tid >> 6;
  const size_t bid = blockIdx.x;
  f32x4 Sr[4];
  #pragma unroll
  for (int it = 0; it < 4; ++it) Sr[it] = f32x4_zero();
  for (int seg = 0; seg < 8; ++seg){
    const size_t sb  = (bid*8 + seg)*4096;
    const size_t s0b = (bid*64 + (size_t)seg*8)*4096;
    // store entry state (fp32) + write own-rows split planes
    #pragma unroll
    for (int it = 0; it < 4; ++it)
      #pragma unroll
      for (int r = 0; r < 4; ++r){
        int row = 16*w + (lane>>4)*4 + r, col = 16*it + (lane&15);
        S0g[s0b + (size_t)row*64 + col] = Sr[it][r];
        bf2 sp = split2(Sr[it][r]); Sh[row*64+col] = sp.h; Sl[row*64+col] = sp.l;
      }
    __syncthreads();
    for (int j = tid; j < 1024; j += 256){
      float4 pv = ((const float4*)(PsegT + sb))[j];
      bf16x4 ph, pl;
      bf2 u0 = split2(pv.x); ph[0]=u0.h; pl[0]=u0.l;
      bf2 u1 = split2(pv.y); ph[1]=u1.h; pl[1]=u1.l;
      bf2 u2 = split2(pv.z); ph[2]=u2.h; pl[2]=u2.l;
      bf2 u3 = split2(pv.w); ph[3]=u3.h; pl[3]=u3.l;
      ((bf16x4*)Ph)[j] = ph; ((bf16x4*)Pl)[j] = pl;
      ((float4*)Bf)[j] = ((const float4*)(BsegF + sb))[j];
    }
    __syncthreads();
    f32x4 nS[4];
    #pragma unroll
    for (int it = 0; it < 4; ++it) nS[it] = f32x4_zero();
    #pragma unroll
    for (int kk = 0; kk < 2; ++kk){
      bf16x8 aH = frag64(Sh, 16*w, kk, lane), aL = frag64(Sl, 16*w, kk, lane);
      #pragma unroll
      for (int it = 0; it < 4; ++it){
        bf16x8 bH = frag64(Ph, 16*it, kk, lane), bL = frag64(Pl, 16*it, kk, lane);
        nS[it] = mfma16x16x32(aH, bH, nS[it]);
        nS[it] = mfma16x16x32(aH, bL, nS[it]);
        nS[it] = mfma16x16x32(aL, bH, nS[it]);
      }
    }
    #pragma unroll
    for (int it = 0; it < 4; ++it)
      #pragma unroll
      for (int r = 0; r < 4; ++r){
        int row = 16*w + (lane>>4)*4 + r, col = 16*it + (lane&15);
        Sr[it][r] = nS[it][r] + Bf[row*64 + col];
      }
  }
}

// ---------------------------------------------------------------- K4c: within-segment replay (256 blocks, 7 steps)
__global__ __launch_bounds__(256) void k_phaseB3(const float* __restrict__ Pg, const bf16* __restrict__ Bg,
                                                 float* __restrict__ S0g){
  __shared__ bf16 Sh[4096], Sl[4096], Ph[4096], Pl[4096];
  __shared__ bf16 BcS[4096];
  const int tid = threadIdx.x, lane = tid & 63, w = tid >> 6;
  const int seg = blockIdx.x;
  const size_t chain = blockIdx.y;
  const size_t segbase = chain*64 + (size_t)seg*8;
  f32x4 Sr[4];
  // load segment entry state (written by B2)
  #pragma unroll
  for (int it = 0; it < 4; ++it)
    #pragma unroll
    for (int r = 0; r < 4; ++r){
      int row = 16*w + (lane>>4)*4 + r, col = 16*it + (lane&15);
      Sr[it][r] = S0g[segbase*4096 + (size_t)row*64 + col];
    }
  for (int i = 0; i < 7; ++i){
    const size_t cb = (segbase + i)*4096;
    #pragma unroll
    for (int it = 0; it < 4; ++it)
      #pragma unroll
      for (int r = 0; r < 4; ++r){
        int row = 16*w + (lane>>4)*4 + r, col = 16*it + (lane&15);
        bf2 sp = split2(Sr[it][r]); Sh[row*64+col] = sp.h; Sl[row*64+col] = sp.l;
      }
    __syncthreads();
    for (int j = tid; j < 1024; j += 256){
      float4 pv = ((const float4*)(Pg + cb))[j];
      bf16x4 ph, pl;
      bf2 u0 = split2(pv.x); ph[0]=u0.h; pl[0]=u0.l;
      bf2 u1 = split2(pv.y); ph[1]=u1.h; pl[1]=u1.l;
      bf2 u2 = split2(pv.z); ph[2]=u2.h; pl[2]=u2.l;
      bf2 u3 = split2(pv.w); ph[3]=u3.h; pl[3]=u3.l;
      ((bf16x4*)Ph)[j] = ph; ((bf16x4*)Pl)[j] = pl;
    }
    for (int j = tid; j < 512; j += 256)
      ((uint4*)BcS)[j] = ((const uint4*)(Bg + cb))[j];
    __syncthreads();
    f32x4 nS[4];
    #pragma unroll
    for (int it = 0; it < 4; ++it) nS[it] = f32x4_zero();
    #pragma unroll
    for (int kk = 0; kk < 2; ++kk){
      bf16x8 aH = frag64(Sh, 16*w, kk, lane), aL = frag64(Sl, 16*w, kk, lane);
      #pragma unroll
      for (int it = 0; it < 4; ++it){
        bf16x8 bH = frag64(Ph, 16*it, kk, lane), bL = frag64(Pl, 16*it, kk, lane);
        nS[it] = mfma16x16x32(aH, bH, nS[it]);
        nS[it] = mfma16x16x32(aH, bL, nS[it]);
        nS[it] = mfma16x16x32(aL, bH, nS[it]);
      }
    }
    const size_t outb = (segbase + i + 1)*4096;
    #pragma unroll
    for (int it = 0; it < 4; ++it)
      #pragma unroll
      for (int r = 0; r < 4; ++r){
        int row = 16*w + (lane>>4)*4 + r, col = 16*it + (lane&15);
        float v = nS[it][r] + (float)BcS[row*64 + col];
        Sr[it][r] = v;
        S0g[outb + (size_t)row*64 + col] = v;
      }
  }
}

// ---------------------------------------------------------------- K5: phase C, outputs + fused RMSNorm/gate (2048 blocks)
// LDS = 81920 B exactly -> 2 blocks/CU (2 waves/SIMD). All tiles XOR-swizzled; lg cumsum in registers.
__global__ __launch_bounds__(256, 2) void k_phaseC(
    const float* __restrict__ qf32, const bf16* __restrict__ qb16,
    const float* __restrict__ kf32, const bf16* __restrict__ kb16,
    const bf16* __restrict__ gf, const float* __restrict__ logA,
    const float* __restrict__ S0g, const bf16* __restrict__ Wg, const bf16* __restrict__ Dg,
    const float* __restrict__ rms_w, bf16* __restrict__ yh, bf16* __restrict__ yl){
  __shared__ bf16 Qh[4096], Ql[4096], Kh[4096], Klo[4096];
  __shared__ bf16 Wl_[4096], Dl_[4096];
  __shared__ bf16 S0h[4096], S0l[4096];
  __shared__ bf16 AAg[4096];
  __shared__ bf16 BDt[4096];
  const int tid = threadIdx.x, lane = tid & 63, w = tid >> 6;
  const int c = blockIdx.x, h = blockIdx.y, b = blockIdx.z;
  const size_t tokbase = (size_t)b*4096 + (size_t)c*64;
  const size_t cbase = ((size_t)((b*16 + h)*64 + c)) * 4096;

  load_split_tile(qf32, qb16, tokbase, h, Qh, Ql, tid, 256);
  load_split_tile(kf32, kb16, tokbase, h, Kh, Klo, tid, 256);
  for (int i = tid; i < 512; i += 256){
    int r = i >> 3, d = r*8 + ((i&7) ^ (r&7));   // 16B-granular swizzle on the 8-elem block index
    ((uint4*)Wl_)[d] = ((const uint4*)(Wg + cbase))[i];
    ((uint4*)Dl_)[d] = ((const uint4*)(Dg + cbase))[i];
  }
  for (int i = tid; i < 1024; i += 256){
    float4 v = ((const float4*)(S0g + cbase))[i];
    bf16x4 sh, sl;
    bf2 t0 = split2(v.x); sh[0]=t0.h; sl[0]=t0.l;
    bf2 t1 = split2(v.y); sh[1]=t1.h; sl[1]=t1.l;
    bf2 t2 = split2(v.z); sh[2]=t2.h; sl[2]=t2.l;
    bf2 t3 = split2(v.w); sh[3]=t3.h; sl[3]=t3.l;
    int t = i >> 4, off = ((i&15)*4) ^ ((t&7)<<3);
    *(bf16x4*)&S0h[t*64 + off] = sh;
    *(bf16x4*)&S0l[t*64 + off] = sl;
  }
  // per-wave redundant lg cumsum (replaces lg_s/gq_s LDS)
  float la = logA[(tokbase + lane)*16 + h];
  #pragma unroll
  for (int dlt = 1; dlt < 64; dlt <<= 1){
    float o = __shfl_up(la, dlt);
    if (lane >= dlt) la += o;
  }
  __syncthreads();

  { // AAg = mask_incl(Gamma .* QK^T), 3-product
    const int t0 = 16*w;
    #pragma unroll
    for (int tu = 0; tu < 4; ++tu){
      f32x4 accm = f32x4_zero();
      #pragma unroll
      for (int kk = 0; kk < 2; ++kk){
        bf16x8 aH = fragSwz(Qh,  t0,    kk, lane);
        bf16x8 aL = fragSwz(Ql,  t0,    kk, lane);
        bf16x8 bH = fragSwz(Kh,  16*tu, kk, lane);
        bf16x8 bL = fragSwz(Klo, 16*tu, kk, lane);
        accm = mfma16x16x32(aH, bH, accm);
        accm = mfma16x16x32(aH, bL, accm);
        accm = mfma16x16x32(aL, bH, accm);
      }
      #pragma unroll
      for (int r = 0; r < 4; ++r){
        int row = t0 + (lane>>4)*4 + r, col = 16*tu + (lane&15);
        float lgr = __shfl(la, row), lgc = __shfl(la, col);
        float v = (col <= row) ? accm[r]*__expf(lgr - lgc) : 0.f;
        AAg[row*64 + (col ^ ((row&7)<<3))] = (bf16)v;
      }
    }
  }
  { // BDt[i][tau] = Dloc[tau][i] - (S0 W_hat^T)[i][tau]
    const int i0 = 16*w;
    #pragma unroll
    for (int tu = 0; tu < 4; ++tu){
      f32x4 accm = f32x4_zero();
      #pragma unroll
      for (int kk = 0; kk < 2; ++kk){
        bf16x8 aH = fragSwz(S0h, i0,    kk, lane);
        bf16x8 aL = fragSwz(S0l, i0,    kk, lane);
        bf16x8 bb = fragSwz(Wl_, 16*tu, kk, lane);
        accm = mfma16x16x32(aH, bb, accm);
        accm = mfma16x16x32(aL, bb, accm);
      }
      #pragma unroll
      for (int r = 0; r < 4; ++r){
        int row = i0 + (lane>>4)*4 + r, col = 16*tu + (lane&15);
        float v = (float)Dl_[col*64 + (row ^ ((col&7)<<3))] - accm[r];
        BDt[row*64 + (col ^ ((row&7)<<3))] = (bf16)v;
      }
    }
  }
  __syncthreads();
  for (int i = tid; i < 4096; i += 256){
    int t = i >> 6;                              // uniform per wave per iteration
    float gq = __expf(__shfl(la, t));
    float v = gq * ((float)Qh[i] + (float)Ql[i]);  // swizzle is within-row: row scale is layout-agnostic
    bf2 sp = split2(v);
    Qh[i] = sp.h; Ql[i] = sp.l;
  }
  __syncthreads();
  {
    const int t0 = 16*w;
    f32x4 o_acc[4];
    #pragma unroll
    for (int it = 0; it < 4; ++it) o_acc[it] = f32x4_zero();
    #pragma unroll
    for (int kk = 0; kk < 2; ++kk){
      bf16x8 aQh = fragSwz(Qh, t0, kk, lane);
      bf16x8 aQl = fragSwz(Ql, t0, kk, lane);
      bf16x8 aA  = fragSwz(AAg, t0, kk, lane);
      #pragma unroll
      for (int it = 0; it < 4; ++it){
        bf16x8 bSh = fragSwz(S0h, 16*it, kk, lane);
        bf16x8 bSl = fragSwz(S0l, 16*it, kk, lane);
        bf16x8 bD  = fragSwz(BDt, 16*it, kk, lane);
        f32x4 t = o_acc[it];
        t = mfma16x16x32(aQh, bSh, t);
        t = mfma16x16x32(aQh, bSl, t);
        t = mfma16x16x32(aQl, bSh, t);
        t = mfma16x16x32(aA,  bD,  t);
        o_acc[it] = t;
      }
    }
    float rw[4];
    #pragma unroll
    for (int it = 0; it < 4; ++it) rw[it] = rms_w[16*it + (lane&15)];
    #pragma unroll
    for (int r = 0; r < 4; ++r){
      float ss = 0.f;
      #pragma unroll
      for (int it = 0; it < 4; ++it) ss += o_acc[it][r]*o_acc[it][r];
      ss += __shfl_xor(ss, 1); ss += __shfl_xor(ss, 2);
      ss += __shfl_xor(ss, 4); ss += __shfl_xor(ss, 8);
      const float scale = rsqrtf(ss*(1.f/64.f) + 1e-6f);
      const int row = t0 + (lane>>4)*4 + r;
      const size_t tok = tokbase + row;
      #pragma unroll
      for (int it = 0; it < 4; ++it){
        const int col = 16*it + (lane&15);
        float g = (float)gf[tok*1024 + h*64 + col];
        float sg = g / (1.f + __expf(-g));
        float v = o_acc[it][r]*scale*rw[it]*sg;
        bf2 sp = split2(v);
        yh[tok*1024 + h*64 + col] = sp.h;
        yl[tok*1024 + h*64 + col] = sp.l;
      }
    }
  }
}

// ---------------------------------------------------------------- launcher
extern "C" void kernel_launch(void* const* d_in, const int* in_sizes, int n_in,
                              void* d_out, int out_size, void* d_ws, size_t ws_size,
                              hipStream_t stream){
  const float* x     = (const float*)d_in[0];
  const float* Wq    = (const float*)d_in[1];
  const float* Wk    = (const float*)d_in[2];
  const float* Wv    = (const float*)d_in[3];
  const float* Wa    = (const float*)d_in[4];
  const float* Wb    = (const float*)d_in[5];
  const float* A_log = (const float*)d_in[6];
  const float* dt_b  = (const float*)d_in[7];
  const float* Wgt   = (const float*)d_in[8];
  const float* Wo    = (const float*)d_in[9];
  const float* rms_w = (const float*)d_in[10];

  const bool BIG = ws_size >= (size_t)215000000;

  char* ws = (char*)d_ws;
  size_t off = 0;
  auto alloc = [&](size_t bytes)->char*{
    char* p = ws + off;
    off += (bytes + 255) & ~(size_t)255;
    return p;
  };
  const size_t PLANE = (size_t)8192*1024*2;   // bf16 activation plane (16 MiB)
  const size_t WPL   = (size_t)1024*1024*2;   // bf16 weight plane (2 MiB)
  bf16* xh  = (bf16*)alloc(PLANE);            // region also hosts Pg (A->B3), then yh
  bf16* xl  = (bf16*)alloc(PLANE);
  bf16* wqh = (bf16*)alloc(WPL); bf16* wql = (bf16*)alloc(WPL);   // wqh..wgl also hosts Bg
  bf16* wkh = (bf16*)alloc(WPL); bf16* wkl = (bf16*)alloc(WPL);
  bf16* wvh = (bf16*)alloc(WPL); bf16* wvl = (bf16*)alloc(WPL);
  bf16* wgh = (bf16*)alloc(WPL); bf16* wgl = (bf16*)alloc(WPL);
  bf16* woh = (bf16*)alloc(WPL); bf16* wol = (bf16*)alloc(WPL);
  bf16* WabTh = (bf16*)alloc((size_t)32*1024*2);
  bf16* WabTl = (bf16*)alloc((size_t)32*1024*2);
  float* qf = nullptr; bf16* qb = nullptr;
  float* kf = nullptr; bf16* kb = nullptr;
  if (BIG){ qf = (float*)alloc((size_t)8192*1024*4); kf = (float*)alloc((size_t)8192*1024*4); }
  else    { qb = (bf16*) alloc(PLANE);               kb = (bf16*) alloc(PLANE); }
  float* vf  = (float*)alloc((size_t)8192*1024*4);  // dead after phase A -> hosts S0g
  bf16* gfb  = (bf16*)alloc(PLANE);
  float* logA  = (float*)alloc((size_t)8192*16*4);
  float* betap = (float*)alloc((size_t)8192*16*4);
  bf16* Wg  = (bf16*)alloc((size_t)2048*4096*2);
  bf16* Dg  = (bf16*)alloc((size_t)2048*4096*2);
  float* Pg  = (float*)xh;            // 33.5 MiB fp32 in xh+xl (dead between GEMMs and phase C)
  float* S0g = vf;                    // 33.5 MiB fp32 (vf dead after phase A)
  bf16* Bg   = wqh;                   // 16 MiB bf16 (projection weights dead)
  float* PsegT = (float*)d_out;       // 4 MiB scratch in d_out (overwritten by final GEMM)
  float* BsegF = (float*)d_out + 1048576;  // next 4 MiB
  bf16* yh = xh;                      // phase C outputs (Pg dead after B3)
  bf16* yl = xl;

  k_cvt_x<<<8192, 256, 0, stream>>>(x, xh, xl, 2097152);
  k_transpose_w<<<dim3(32,32), 256, 0, stream>>>(Wq,  wqh, wql);
  k_transpose_w<<<dim3(32,32), 256, 0, stream>>>(Wk,  wkh, wkl);
  k_transpose_w<<<dim3(32,32), 256, 0, stream>>>(Wv,  wvh, wvl);
  k_transpose_w<<<dim3(32,32), 256, 0, stream>>>(Wgt, wgh, wgl);
  k_transpose_w<<<dim3(32,32), 256, 0, stream>>>(Wo,  woh, wol);
  k_transpose_ab<<<128, 256, 0, stream>>>(Wa, Wb, WabTh, WabTl);

  if (BIG){
    k_gemm1<<<dim3(64,8), 256, 0, stream>>>(xh, wqh, nullptr, qf);
    k_gemm1<<<dim3(64,8), 256, 0, stream>>>(xh, wkh, nullptr, kf);
  } else {
    k_gemm1<<<dim3(64,8), 256, 0, stream>>>(xh, wqh, qb, nullptr);
    k_gemm1<<<dim3(64,8), 256, 0, stream>>>(xh, wkh, kb, nullptr);
  }
  k_gemm1<<<dim3(64,8), 256, 0, stream>>>(xh, wvh, nullptr, vf);
  k_gemm1<<<dim3(64,8), 256, 0, stream>>>(xh, wgh, gfb, nullptr);

  k_ab_gemm<<<256, 256, 0, stream>>>(xh, xl, WabTh, WabTl, A_log, dt_b, logA, betap);
  if (BIG) k_norm_f32<<<512, 256, 0, stream>>>(qf, kf);
  else     k_norm_b16<<<512, 256, 0, stream>>>(qb, kb);

  k_phaseA<<<dim3(64,16,2), 128, 0, stream>>>(kf, kb, vf, logA, betap, Wg, Dg, Pg, Bg);
  k_phaseB1<<<dim3(8,32), 256, 0, stream>>>(Pg, Bg, PsegT, BsegF);
  k_phaseB2<<<32, 256, 0, stream>>>(PsegT, BsegF, S0g);
  k_phaseB3<<<dim3(8,32), 256, 0, stream>>>(Pg, Bg, S0g);
  k_phaseC<<<dim3(64,16,2), 256, 0, stream>>>(qf, qb, kf, kb, gfb, logA, S0g, Wg, Dg, rms_w, yh, yl);

  k_gemm3<<<dim3(64,8), 256, 0, stream>>>(yh, yl, woh, wol, nullptr, (float*)d_out);
}

// Round 4
// 513.898 us; speedup vs baseline: 1.4996x; 1.1562x over previous
//
#include <hip/hip_runtime.h>
#include <cstdint>
#include <cstddef>

typedef __bf16 bf16;
typedef __bf16 bf16x4 __attribute__((ext_vector_type(4)));
typedef __bf16 bf16x8 __attribute__((ext_vector_type(8)));
typedef float  f32x4  __attribute__((ext_vector_type(4)));

#define GLD_LDS16(gp, lp) \
  __builtin_amdgcn_global_load_lds((__attribute__((address_space(1))) void*)(gp), \
                                   (__attribute__((address_space(3))) void*)(lp), 16, 0, 0)

__device__ __forceinline__ f32x4 f32x4_zero(){ f32x4 v; v[0]=0.f; v[1]=0.f; v[2]=0.f; v[3]=0.f; return v; }

__device__ __forceinline__ f32x4 mfma16x16x32(bf16x8 a, bf16x8 b, f32x4 c){
  return __builtin_amdgcn_mfma_f32_16x16x32_bf16(a, b, c, 0, 0, 0);
}
// fragment of a 64-col bf16 LDS array (stride 64), LINEAR layout (phaseB kernels)
__device__ __forceinline__ bf16x8 frag64(const bf16* base, int row0, int kk, int lane){
  return *(const bf16x8*)&base[(row0 + (lane&15))*64 + kk*32 + (lane>>4)*8];
}
// fragment of a 64-col bf16 LDS array with XOR bank-swizzle: elem ^= (row&7)<<3
// (16B-granular swizzle; keeps ds_read_b128 16B-aligned; 16-way conflict -> 2-way)
__device__ __forceinline__ bf16x8 fragSwz(const bf16* base, int row0, int kk, int lane){
  const int row = row0 + (lane&15);
  const int off = (kk*32 + (lane>>4)*8) ^ ((row&7)<<3);
  return *(const bf16x8*)&base[row*64 + off];
}
struct bf2 { bf16 h, l; };
__device__ __forceinline__ bf2 split2(float v){
  bf2 r; r.h = (bf16)v; r.l = (bf16)(v - (float)r.h); return r;
}

// ---------------------------------------------------------------- K0a: x -> hi/lo bf16 planes
__global__ __launch_bounds__(256) void k_cvt_x(const float* __restrict__ x,
                                               bf16* __restrict__ xh, bf16* __restrict__ xl, int n4){
  int i = blockIdx.x*256 + threadIdx.x;
  if (i < n4){
    float4 v = ((const float4*)x)[i];
    bf16x4 h, l;
    bf2 t0 = split2(v.x); h[0]=t0.h; l[0]=t0.l;
    bf2 t1 = split2(v.y); h[1]=t1.h; l[1]=t1.l;
    bf2 t2 = split2(v.z); h[2]=t2.h; l[2]=t2.l;
    bf2 t3 = split2(v.w); h[3]=t3.h; l[3]=t3.l;
    ((bf16x4*)xh)[i] = h;
    ((bf16x4*)xl)[i] = l;
  }
}

// ---------------------------------------------------------------- K0b: W[k][n] -> Wt hi/lo [n][k]
__global__ __launch_bounds__(256) void k_transpose_w(const float* __restrict__ W,
                                                     bf16* __restrict__ Wth, bf16* __restrict__ Wtl){
  __shared__ float tile[32][33];
  const int k0 = blockIdx.x*32, n0 = blockIdx.y*32;
  const int r = threadIdx.x >> 3, c4 = (threadIdx.x & 7)*4;
  float4 v = *(const float4*)&W[(size_t)(k0+r)*1024 + n0 + c4];
  tile[r][c4+0]=v.x; tile[r][c4+1]=v.y; tile[r][c4+2]=v.z; tile[r][c4+3]=v.w;
  __syncthreads();
  bf16x4 h, l;
  bf2 t0 = split2(tile[c4+0][r]); h[0]=t0.h; l[0]=t0.l;
  bf2 t1 = split2(tile[c4+1][r]); h[1]=t1.h; l[1]=t1.l;
  bf2 t2 = split2(tile[c4+2][r]); h[2]=t2.h; l[2]=t2.l;
  bf2 t3 = split2(tile[c4+3][r]); h[3]=t3.h; l[3]=t3.l;
  *(bf16x4*)&Wth[(size_t)(n0+r)*1024 + k0 + c4] = h;
  *(bf16x4*)&Wtl[(size_t)(n0+r)*1024 + k0 + c4] = l;
}

// ---------------------------------------------------------------- K0c: Walpha/Wbeta [1024][16] -> WabT hi/lo bf16 [32][1024]
__global__ __launch_bounds__(256) void k_transpose_ab(const float* __restrict__ Wa, const float* __restrict__ Wb,
                                                      bf16* __restrict__ WabTh, bf16* __restrict__ WabTl){
  int p = blockIdx.x*256 + threadIdx.x;
  if (p < 32768){
    int o = p >> 10, k = p & 1023;
    float v = (o < 16) ? Wa[k*16 + o] : Wb[k*16 + (o-16)];
    bf2 s = split2(v);
    WabTh[p] = s.h;
    WabTl[p] = s.l;
  }
}

// ---------------------------------------------------------------- K1: split-bf16 MFMA GEMM (3-product), K=1024
__global__ __launch_bounds__(256) void k_gemm3(const bf16* __restrict__ Ah, const bf16* __restrict__ Al,
                                               const bf16* __restrict__ Bth, const bf16* __restrict__ Btl,
                                               bf16* __restrict__ Cb, float* __restrict__ Cf){
  __shared__ bf16 Ash[128*32], Asl[128*32];
  __shared__ bf16 Bsh[128*32], Bsl[128*32];
  const int tid = threadIdx.x, lane = tid & 63, w = tid >> 6;
  const int wm = w >> 1, wn = w & 1;
  const size_t m0 = (size_t)blockIdx.x * 128;
  const size_t n0 = (size_t)blockIdx.y * 128;
  f32x4 acc[4][4];
  #pragma unroll
  for (int i=0;i<4;++i)
    #pragma unroll
    for (int j=0;j<4;++j) acc[i][j] = f32x4_zero();

  for (int k0 = 0; k0 < 1024; k0 += 32){
    __syncthreads();
    #pragma unroll
    for (int j = 0; j < 2; ++j){
      const int rbase = 32*w + 16*j;
      const int r = rbase + (lane >> 2);
      const int kk = k0 + (lane & 3)*8;
      GLD_LDS16(&Ah [(m0 + r)*1024 + kk], &Ash[rbase*32]);
      GLD_LDS16(&Al [(m0 + r)*1024 + kk], &Asl[rbase*32]);
      GLD_LDS16(&Bth[(n0 + r)*1024 + kk], &Bsh[rbase*32]);
      GLD_LDS16(&Btl[(n0 + r)*1024 + kk], &Bsl[rbase*32]);
    }
    __syncthreads();
    bf16x8 ah[4], al[4], bh[4], bl[4];
    #pragma unroll
    for (int t=0;t<4;++t){
      ah[t] = *(const bf16x8*)&Ash[(64*wm + 16*t + (lane&15))*32 + (lane>>4)*8];
      al[t] = *(const bf16x8*)&Asl[(64*wm + 16*t + (lane&15))*32 + (lane>>4)*8];
      bh[t] = *(const bf16x8*)&Bsh[(64*wn + 16*t + (lane&15))*32 + (lane>>4)*8];
      bl[t] = *(const bf16x8*)&Bsl[(64*wn + 16*t + (lane&15))*32 + (lane>>4)*8];
    }
    #pragma unroll
    for (int i=0;i<4;++i)
      #pragma unroll
      for (int j=0;j<4;++j){
        f32x4 t = acc[i][j];
        t = mfma16x16x32(ah[i], bh[j], t);
        t = mfma16x16x32(ah[i], bl[j], t);
        t = mfma16x16x32(al[i], bh[j], t);
        acc[i][j] = t;
      }
  }
  #pragma unroll
  for (int i=0;i<4;++i)
    #pragma unroll
    for (int j=0;j<4;++j)
      #pragma unroll
      for (int r=0;r<4;++r){
        size_t row = m0 + 64*wm + 16*i + (lane>>4)*4 + r;
        size_t col = n0 + 64*wn + 16*j + (lane&15);
        float v = acc[i][j][r];
        if (Cf) Cf[row*1024 + col] = v;
        else    Cb[row*1024 + col] = (bf16)v;
      }
}

// ---------------------------------------------------------------- K1b: single-bf16 MFMA GEMM, K=1024
// NRM: 0 = plain, 1 = fused q l2norm (scale 0.125/||.||), 2 = fused k l2norm (1/||.||).
// Each wave's 4 j-tiles span exactly one 64-wide head (N-tile 128 = 2 heads, 64-aligned),
// so the head row-norm is a 16-lane shfl_xor reduce over the wave's own acc -- identical
// math to the deleted standalone k_norm kernels (134 MB HBM round-trip saved).
template<int NRM>
__global__ __launch_bounds__(256) void k_gemm1(const bf16* __restrict__ Ah, const bf16* __restrict__ Bth,
                                               bf16* __restrict__ Cb, float* __restrict__ Cf){
  __shared__ bf16 Ash[128*32];
  __shared__ bf16 Bsh[128*32];
  const int tid = threadIdx.x, lane = tid & 63, w = tid >> 6;
  const int wm = w >> 1, wn = w & 1;
  const size_t m0 = (size_t)blockIdx.x * 128;
  const size_t n0 = (size_t)blockIdx.y * 128;
  f32x4 acc[4][4];
  #pragma unroll
  for (int i=0;i<4;++i)
    #pragma unroll
    for (int j=0;j<4;++j) acc[i][j] = f32x4_zero();

  for (int k0 = 0; k0 < 1024; k0 += 32){
    __syncthreads();
    #pragma unroll
    for (int j = 0; j < 2; ++j){
      const int rbase = 32*w + 16*j;
      const int r = rbase + (lane >> 2);
      const int kk = k0 + (lane & 3)*8;
      GLD_LDS16(&Ah [(m0 + r)*1024 + kk], &Ash[rbase*32]);
      GLD_LDS16(&Bth[(n0 + r)*1024 + kk], &Bsh[rbase*32]);
    }
    __syncthreads();
    bf16x8 ah[4], bh[4];
    #pragma unroll
    for (int t=0;t<4;++t){
      ah[t] = *(const bf16x8*)&Ash[(64*wm + 16*t + (lane&15))*32 + (lane>>4)*8];
      bh[t] = *(const bf16x8*)&Bsh[(64*wn + 16*t + (lane&15))*32 + (lane>>4)*8];
    }
    #pragma unroll
    for (int i=0;i<4;++i)
      #pragma unroll
      for (int j=0;j<4;++j)
        acc[i][j] = mfma16x16x32(ah[i], bh[j], acc[i][j]);
  }
  #pragma unroll
  for (int i=0;i<4;++i)
    #pragma unroll
    for (int r=0;r<4;++r){
      float sc = 1.f;
      if (NRM){
        float ss = 0.f;
        #pragma unroll
        for (int j=0;j<4;++j) ss += acc[i][j][r]*acc[i][j][r];
        ss += __shfl_xor(ss, 1); ss += __shfl_xor(ss, 2);
        ss += __shfl_xor(ss, 4); ss += __shfl_xor(ss, 8);
        sc = (NRM==1 ? 0.125f : 1.0f) / fmaxf(sqrtf(ss), 1e-12f);
      }
      #pragma unroll
      for (int j=0;j<4;++j){
        size_t row = m0 + 64*wm + 16*i + (lane>>4)*4 + r;
        size_t col = n0 + 64*wn + 16*j + (lane&15);
        float v = acc[i][j][r]*sc;
        if (Cf) Cf[row*1024 + col] = v;
        else    Cb[row*1024 + col] = (bf16)v;
      }
    }
}

// ---------------------------------------------------------------- K2: alpha/beta projections as split-bf16 MFMA GEMM
__global__ __launch_bounds__(256) void k_ab_gemm(const bf16* __restrict__ xh, const bf16* __restrict__ xl,
    const bf16* __restrict__ WabTh, const bf16* __restrict__ WabTl,
    const float* __restrict__ A_log, const float* __restrict__ dt_bias,
    float* __restrict__ logA, float* __restrict__ betap){
  __shared__ bf16 Ash[2][2048], Asl[2][2048];   // 32 rows x 64 k per buffer
  const int tid = threadIdx.x, lane = tid & 63, w = tid >> 6;
  const int mt = w >> 1, nt = w & 1;
  const size_t m0 = (size_t)blockIdx.x * 32;
  const int srow = tid >> 3;
  const int scol = 8*((tid & 7) ^ (srow & 7));
  const size_t sg = (m0 + srow)*1024 + scol;

  f32x4 acc = f32x4_zero();
  GLD_LDS16(&xh[sg], &Ash[0][w*512]);
  GLD_LDS16(&xl[sg], &Asl[0][w*512]);
  for (int s = 0; s < 16; ++s){
    const int cur = s & 1;
    __syncthreads();                    // implicit vmcnt(0): buf[cur] staged
    if (s + 1 < 16){
      const size_t g = sg + (size_t)(s+1)*64;
      GLD_LDS16(&xh[g], &Ash[cur^1][w*512]);
      GLD_LDS16(&xl[g], &Asl[cur^1][w*512]);
    }
    const int k0 = s*64;
    #pragma unroll
    for (int kk = 0; kk < 2; ++kk){
      bf16x8 aH = fragSwz(Ash[cur], 16*mt, kk, lane);
      bf16x8 aL = fragSwz(Asl[cur], 16*mt, kk, lane);
      const size_t bo = (size_t)(16*nt + (lane&15))*1024 + k0 + kk*32 + (lane>>4)*8;
      bf16x8 bH = *(const bf16x8*)&WabTh[bo];
      bf16x8 bL = *(const bf16x8*)&WabTl[bo];
      acc = mfma16x16x32(aH, bH, acc);
      acc = mfma16x16x32(aH, bL, acc);
      acc = mfma16x16x32(aL, bH, acc);
    }
  }
  const int col = lane & 15;
  #pragma unroll
  for (int r = 0; r < 4; ++r){
    const size_t row = m0 + 16*mt + (lane>>4)*4 + r;
    float v = acc[r];
    if (nt == 0){
      float z = v + dt_bias[col];
      float dt = (z > 20.f) ? z : log1pf(expf(z));
      logA[row*16 + col] = -expf(A_log[col]) * dt;   // log(alpha_t)
    } else {
      betap[row*16 + col] = 1.f/(1.f + expf(-v));    // beta_t
    }
  }
}

// helper: load a 64x64 head-tile (fp32 or bf16 source) and split into hi/lo bf16 LDS planes,
// stride 64, XOR-swizzled: elem_off ^= (row&7)<<3  (matches fragSwz)
__device__ __forceinline__ void load_split_tile(const float* f32, const bf16* b16,
                                                size_t tokbase, int h,
                                                bf16* Lh, bf16* Ll, int tid, int nthr){
  for (int i = tid; i < 1024; i += nthr){
    int t = i >> 4, c4 = (i & 15)*4;
    const size_t g = (tokbase + t)*1024 + (size_t)h*64 + c4;
    float4 v;
    if (f32) v = *(const float4*)&f32[g];
    else { bf16x4 b = *(const bf16x4*)&b16[g]; v.x=(float)b[0]; v.y=(float)b[1]; v.z=(float)b[2]; v.w=(float)b[3]; }
    bf16x4 hh, ll;
    bf2 s0 = split2(v.x); hh[0]=s0.h; ll[0]=s0.l;
    bf2 s1 = split2(v.y); hh[1]=s1.h; ll[1]=s1.l;
    bf2 s2 = split2(v.z); hh[2]=s2.h; ll[2]=s2.l;
    bf2 s3 = split2(v.w); hh[3]=s3.h; ll[3]=s3.l;
    const int off = c4 ^ ((t&7)<<3);
    *(bf16x4*)&Lh[t*64 + off] = hh;
    *(bf16x4*)&Ll[t*64 + off] = ll;
  }
}

// ---------------------------------------------------------------- K3: phase A (2048 blocks, 128 thr)
// LDS = 32768 B -> 5 blocks/CU; __launch_bounds__(128,4) caps VGPR at 128 -> 4 waves/SIMD.
// Right-looking forward substitution (diag solve + rank-16 trailing update) keeps live state
// at d[64]+temps (~100 VGPR, no Xv[64]) -- round 1 showed 128-cap with 128 live floats spills.
// Overlays: KtT -> Ef rows 32..63 (dead after solve); DT -> Kh, WT -> Kl_ (dead after KtT build).
// lg cumsum lives in Ef row 0 (never read by solve, never overlaid).
__global__ __launch_bounds__(128, 4) void k_phaseA(const float* __restrict__ kf32, const bf16* __restrict__ kb16,
    const float* __restrict__ vf, const float* __restrict__ logA, const float* __restrict__ betap,
    bf16* __restrict__ Wg, bf16* __restrict__ Dg, float* __restrict__ Pg, bf16* __restrict__ Bg){
  __shared__ bf16  Kh[4096], Kl_[4096];   // 8 KiB + 8 KiB
  __shared__ float Ef[4096];              // 16 KiB; row 0 = lg cumsum
  bf16* DT  = Kh;                         // overlay: Dsol^T (after KtT build)
  bf16* WT  = Kl_;                        // overlay: Wsol^T
  bf16* KtT = (bf16*)&Ef[2048];           // overlay: K_til^T (Ef rows 32..63, after solve)
  const int tid = threadIdx.x, lane = tid & 63, wid = tid >> 6;
  const int c = blockIdx.x, h = blockIdx.y, b = blockIdx.z;
  const size_t tokbase = (size_t)b*4096 + (size_t)c*64;
  const size_t cbase = ((size_t)((b*16 + h)*64 + c)) * 4096;

  load_split_tile(kf32, kb16, tokbase, h, Kh, Kl_, tid, 128);
  const float bet = betap[(tokbase + lane)*16 + h];   // per-lane beta_t, t = lane
  if (tid < 64){
    float la = logA[(tokbase + tid)*16 + h];
    #pragma unroll
    for (int dlt = 1; dlt < 64; dlt <<= 1){
      float o = __shfl_up(la, dlt);
      if (lane >= dlt) la += o;
    }
    Ef[tid] = la;                // lg cumsum in E row 0 (row 0 never read by solve)
  }
  __syncthreads();

  // E[t][tau] = (gamma_t/gamma_tau)*(k_t . k_tau), strictly lower; else 0  (3-product MFMA)
  #pragma unroll
  for (int tt = 0; tt < 2; ++tt){
    const int t0 = 32*wid + 16*tt;
    #pragma unroll
    for (int tu = 0; tu < 4; ++tu){
      f32x4 accm = f32x4_zero();
      #pragma unroll
      for (int kk = 0; kk < 2; ++kk){
        bf16x8 aH = fragSwz(Kh,  t0,    kk, lane);
        bf16x8 aL = fragSwz(Kl_, t0,    kk, lane);
        bf16x8 bH = fragSwz(Kh,  16*tu, kk, lane);
        bf16x8 bL = fragSwz(Kl_, 16*tu, kk, lane);
        accm = mfma16x16x32(aH, bH, accm);
        accm = mfma16x16x32(aH, bL, accm);
        accm = mfma16x16x32(aL, bH, accm);
      }
      #pragma unroll
      for (int r = 0; r < 4; ++r){
        int row = t0 + (lane>>4)*4 + r, col = 16*tu + (lane&15);
        float ev = (col < row) ? accm[r]*__expf(Ef[row] - Ef[col]) : 0.f;
        if (row > 0) Ef[row*64 + col] = ev;   // row 0 never read; keeps lg intact
      }
    }
  }
  __syncthreads();   // E complete (both waves) before solve reads

  // right-looking blocked forward substitution: (I + diag(beta)E) X = diag(beta) R
  float d[64];
  {
    if (wid == 0){
      #pragma unroll
      for (int t = 0; t < 64; ++t)
        d[t] = vf[(tokbase + t)*1024 + h*64 + lane];
    } else {
      #pragma unroll
      for (int t = 0; t < 64; ++t){
        int ks = lane ^ ((t&7)<<3);
        d[t] = __expf(Ef[t]) * ((float)Kh[t*64 + ks] + (float)Kl_[t*64 + ks]);
      }
    }
    #pragma unroll
    for (int bi = 0; bi < 4; ++bi){
      // diagonal 16x16 unit-lower solve
      #pragma unroll
      for (int tt = 0; tt < 16; ++tt){
        const int t = 16*bi + tt;
        float s = 0.f;
        #pragma unroll
        for (int j = 0; j < 16; ++j)
          if (j < tt) s += Ef[t*64 + 16*bi + j] * d[16*bi + j];
        d[t] = __shfl(bet, t) * (d[t] - s);
      }
      // trailing rank-16 update of all later blocks
      #pragma unroll
      for (int b2 = bi + 1; b2 < 4; ++b2)
        #pragma unroll
        for (int tt = 0; tt < 16; ++tt){
          const int t = 16*b2 + tt;
          float a0=0.f,a1=0.f,a2=0.f,a3=0.f;
          #pragma unroll
          for (int q = 0; q < 4; ++q){
            float4 e = *(const float4*)&Ef[t*64 + 16*bi + q*4];
            a0 += e.x * d[16*bi + q*4 + 0];
            a1 += e.y * d[16*bi + q*4 + 1];
            a2 += e.z * d[16*bi + q*4 + 2];
            a3 += e.w * d[16*bi + q*4 + 3];
          }
          d[t] -= (a0+a1)+(a2+a3);
        }
    }
  }
  __syncthreads();   // all Ef/Kh/Kl solve reads done

  // K_til^T[j][t] = (gamma_L/gamma_t) * k[t][j]  (built AFTER solve, into Ef rows 32..63)
  {
    const float gsc = __expf(Ef[63] - Ef[lane]);   // t = i&63 == lane for stride-128 loop
    for (int i = tid; i < 4096; i += 128){
      int t = lane, j = i >> 6;
      int ks = j ^ ((t&7)<<3);
      float kv = (float)Kh[t*64 + ks] + (float)Kl_[t*64 + ks];
      KtT[j*64 + (t ^ ((j&7)<<3))] = (bf16)(gsc * kv);
    }
  }
  __syncthreads();   // KtT built; Kh/Kl_ now dead -> DT/WT overlay safe

  const float gL = __expf(Ef[63]);   // Ef row 0 intact (KtT occupies rows 32..63 only)
  {
    bf16* myT = wid ? WT : DT;
    #pragma unroll
    for (int s4 = 0; s4 < 16; ++s4){
      bf16x4 v4;
      v4[0]=(bf16)d[s4*4+0]; v4[1]=(bf16)d[s4*4+1];
      v4[2]=(bf16)d[s4*4+2]; v4[3]=(bf16)d[s4*4+3];
      *(bf16x4*)&myT[lane*64 + ((s4*4) ^ ((lane&7)<<3))] = v4;
    }
    bf16* myG = wid ? Wg : Dg;
    #pragma unroll
    for (int t = 0; t < 64; ++t)
      myG[cbase + (size_t)t*64 + lane] = (bf16)d[t];
  }
  __syncthreads();

  // P^T[j][i] = gamma_L*I - sum_t K_til[t][j]*Wsol[t][i]  (wave0, MFMA, fp32 out)
  // B[i][j]   =              sum_t Dsol[t][i]*K_til[t][j]  (wave1, MFMA, bf16 out)
  if (wid == 0){
    #pragma unroll
    for (int tj = 0; tj < 4; ++tj)
      #pragma unroll
      for (int ti = 0; ti < 4; ++ti){
        f32x4 acc = f32x4_zero();
        #pragma unroll
        for (int kk = 0; kk < 2; ++kk)
          acc = mfma16x16x32(fragSwz(KtT, 16*tj, kk, lane), fragSwz(WT, 16*ti, kk, lane), acc);
        #pragma unroll
        for (int r = 0; r < 4; ++r){
          int row = 16*tj + (lane>>4)*4 + r, col = 16*ti + (lane&15);
          Pg[cbase + (size_t)row*64 + col] = ((row == col) ? gL : 0.f) - acc[r];
        }
      }
  } else {
    #pragma unroll
    for (int ti = 0; ti < 4; ++ti)
      #pragma unroll
      for (int tj = 0; tj < 4; ++tj){
        f32x4 acc = f32x4_zero();
        #pragma unroll
        for (int kk = 0; kk < 2; ++kk)
          acc = mfma16x16x32(fragSwz(DT, 16*ti, kk, lane), fragSwz(KtT, 16*tj, kk, lane), acc);
        #pragma unroll
        for (int r = 0; r < 4; ++r){
          int row = 16*ti + (lane>>4)*4 + r, col = 16*tj + (lane&15);
          Bg[cbase + (size_t)row*64 + col] = (bf16)acc[r];
        }
      }
  }
}

// ---------------------------------------------------------------- K4a: segment composition (256 blocks: 8 seg x 32 chains)
__global__ __launch_bounds__(256) void k_phaseB1(const float* __restrict__ Pg, const bf16* __restrict__ Bg,
                                                 float* __restrict__ PsegT, float* __restrict__ BsegF){
  __shared__ bf16 PaccH[4096], PaccL[4096], BaccH[4096], BaccL[4096];
  __shared__ bf16 PcH[4096], PcL[4096];
  __shared__ bf16 BcS[4096];
  const int tid = threadIdx.x, lane = tid & 63, w = tid >> 6;
  const int seg = blockIdx.x;
  const size_t chain = blockIdx.y;
  f32x4 Pr[4], Br[4];
  #pragma unroll
  for (int it = 0; it < 4; ++it){
    #pragma unroll
    for (int r = 0; r < 4; ++r){
      int row = 16*w + (lane>>4)*4 + r, col = 16*it + (lane&15);
      Pr[it][r] = (row == col) ? 1.f : 0.f;   // Pacc = I
      Br[it][r] = 0.f;                        // Bacc = 0
    }
  }
  for (int i = 0; i < 8; ++i){
    const size_t cb = (chain*64 + (size_t)seg*8 + i)*4096;
    #pragma unroll
    for (int it = 0; it < 4; ++it)
      #pragma unroll
      for (int r = 0; r < 4; ++r){
        int row = 16*w + (lane>>4)*4 + r, col = 16*it + (lane&15);
        bf2 sp = split2(Pr[it][r]); PaccH[row*64+col] = sp.h; PaccL[row*64+col] = sp.l;
        bf2 sb = split2(Br[it][r]); BaccH[row*64+col] = sb.h; BaccL[row*64+col] = sb.l;
      }
    __syncthreads();   // prev iter's MFMA done -> safe to overwrite PcH/L
    for (int j = tid; j < 1024; j += 256){
      float4 pv = ((const float4*)(Pg + cb))[j];
      bf16x4 ph, pl;
      bf2 u0 = split2(pv.x); ph[0]=u0.h; pl[0]=u0.l;
      bf2 u1 = split2(pv.y); ph[1]=u1.h; pl[1]=u1.l;
      bf2 u2 = split2(pv.z); ph[2]=u2.h; pl[2]=u2.l;
      bf2 u3 = split2(pv.w); ph[3]=u3.h; pl[3]=u3.l;
      ((bf16x4*)PcH)[j] = ph; ((bf16x4*)PcL)[j] = pl;
    }
    for (int j = tid; j < 512; j += 256)
      ((uint4*)BcS)[j] = ((const uint4*)(Bg + cb))[j];
    __syncthreads();
    f32x4 nP[4], nB[4];
    #pragma unroll
    for (int it = 0; it < 4; ++it){ nP[it] = f32x4_zero(); nB[it] = f32x4_zero(); }
    #pragma unroll
    for (int kk = 0; kk < 2; ++kk){
      bf16x8 aPH = frag64(PaccH, 16*w, kk, lane), aPL = frag64(PaccL, 16*w, kk, lane);
      bf16x8 aBH = frag64(BaccH, 16*w, kk, lane), aBL = frag64(BaccL, 16*w, kk, lane);
      #pragma unroll
      for (int it = 0; it < 4; ++it){
        bf16x8 bH = frag64(PcH, 16*it, kk, lane), bL = frag64(PcL, 16*it, kk, lane);
        nP[it] = mfma16x16x32(aPH, bH, nP[it]);
        nP[it] = mfma16x16x32(aPH, bL, nP[it]);
        nP[it] = mfma16x16x32(aPL, bH, nP[it]);
        nB[it] = mfma16x16x32(aBH, bH, nB[it]);
        nB[it] = mfma16x16x32(aBH, bL, nB[it]);
        nB[it] = mfma16x16x32(aBL, bH, nB[it]);
      }
    }
    #pragma unroll
    for (int it = 0; it < 4; ++it)
      #pragma unroll
      for (int r = 0; r < 4; ++r){
        int row = 16*w + (lane>>4)*4 + r, col = 16*it + (lane&15);
        Pr[it][r] = nP[it][r];
        Br[it][r] = nB[it][r] + (float)BcS[row*64 + col];
      }
  }
  const size_t sb = (chain*8 + seg)*4096;
  #pragma unroll
  for (int it = 0; it < 4; ++it)
    #pragma unroll
    for (int r = 0; r < 4; ++r){
      int row = 16*w + (lane>>4)*4 + r, col = 16*it + (lane&15);
      PsegT[sb + (size_t)col*64 + row] = Pr[it][r];   // transposed (B-operand layout)
      BsegF[sb + (size_t)row*64 + col] = Br[it][r];   // natural
    }
}

// ---------------------------------------------------------------- K4b: segment-level scan (32 blocks, 8 steps)
__global__ __launch_bounds__(256) void k_phaseB2(const float* __restrict__ PsegT, const float* __restrict__ BsegF,
                                                 float* __restrict__ S0g){
  __shared__ bf16 Sh[4096], Sl[4096], Ph[4096], Pl[4096];
  __shared__ float Bf[4096];
  const int tid = threadIdx.x, lane = tid & 63, w = tid >> 6;
  const size_t bid = blockIdx.x;
  f32x4 Sr[4];
  #pragma unroll
  for (int it = 0; it < 4; ++it) Sr[it] = f32x4_zero();
  for (int seg = 0; seg < 8; ++seg){
    const size_t sb  = (bid*8 + seg)*4096;
    const size_t s0b = (bid*64 + (size_t)seg*8)*4096;
    #pragma unroll
    for (int it = 0; it < 4; ++it)
      #pragma unroll
      for (int r = 0; r < 4; ++r){
        int row = 16*w + (lane>>4)*4 + r, col = 16*it + (lane&15);
        S0g[s0b + (size_t)row*64 + col] = Sr[it][r];
        bf2 sp = split2(Sr[it][r]); Sh[row*64+col] = sp.h; Sl[row*64+col] = sp.l;
      }
    __syncthreads();
    for (int j = tid; j < 1024; j += 256){
      float4 pv = ((const float4*)(PsegT + sb))[j];
      bf16x4 ph, pl;
      bf2 u0 = split2(pv.x); ph[0]=u0.h; pl[0]=u0.l;
      bf2 u1 = split2(pv.y); ph[1]=u1.h; pl[1]=u1.l;
      bf2 u2 = split2(pv.z); ph[2]=u2.h; pl[2]=u2.l;
      bf2 u3 = split2(pv.w); ph[3]=u3.h; pl[3]=u3.l;
      ((bf16x4*)Ph)[j] = ph; ((bf16x4*)Pl)[j] = pl;
      ((float4*)Bf)[j] = ((const float4*)(BsegF + sb))[j];
    }
    __syncthreads();
    f32x4 nS[4];
    #pragma unroll
    for (int it = 0; it < 4; ++it) nS[it] = f32x4_zero();
    #pragma unroll
    for (int kk = 0; kk < 2; ++kk){
      bf16x8 aH = frag64(Sh, 16*w, kk, lane), aL = frag64(Sl, 16*w, kk, lane);
      #pragma unroll
      for (int it = 0; it < 4; ++it){
        bf16x8 bH = frag64(Ph, 16*it, kk, lane), bL = frag64(Pl, 16*it, kk, lane);
        nS[it] = mfma16x16x32(aH, bH, nS[it]);
        nS[it] = mfma16x16x32(aH, bL, nS[it]);
        nS[it] = mfma16x16x32(aL, bH, nS[it]);
      }
    }
    #pragma unroll
    for (int it = 0; it < 4; ++it)
      #pragma unroll
      for (int r = 0; r < 4; ++r){
        int row = 16*w + (lane>>4)*4 + r, col = 16*it + (lane&15);
        Sr[it][r] = nS[it][r] + Bf[row*64 + col];
      }
  }
}

// ---------------------------------------------------------------- K4c: within-segment replay (256 blocks, 7 steps)
__global__ __launch_bounds__(256) void k_phaseB3(const float* __restrict__ Pg, const bf16* __restrict__ Bg,
                                                 float* __restrict__ S0g){
  __shared__ bf16 Sh[4096], Sl[4096], Ph[4096], Pl[4096];
  __shared__ bf16 BcS[4096];
  const int tid = threadIdx.x, lane = tid & 63, w = tid >> 6;
  const int seg = blockIdx.x;
  const size_t chain = blockIdx.y;
  const size_t segbase = chain*64 + (size_t)seg*8;
  f32x4 Sr[4];
  #pragma unroll
  for (int it = 0; it < 4; ++it)
    #pragma unroll
    for (int r = 0; r < 4; ++r){
      int row = 16*w + (lane>>4)*4 + r, col = 16*it + (lane&15);
      Sr[it][r] = S0g[segbase*4096 + (size_t)row*64 + col];
    }
  for (int i = 0; i < 7; ++i){
    const size_t cb = (segbase + i)*4096;
    #pragma unroll
    for (int it = 0; it < 4; ++it)
      #pragma unroll
      for (int r = 0; r < 4; ++r){
        int row = 16*w + (lane>>4)*4 + r, col = 16*it + (lane&15);
        bf2 sp = split2(Sr[it][r]); Sh[row*64+col] = sp.h; Sl[row*64+col] = sp.l;
      }
    __syncthreads();
    for (int j = tid; j < 1024; j += 256){
      float4 pv = ((const float4*)(Pg + cb))[j];
      bf16x4 ph, pl;
      bf2 u0 = split2(pv.x); ph[0]=u0.h; pl[0]=u0.l;
      bf2 u1 = split2(pv.y); ph[1]=u1.h; pl[1]=u1.l;
      bf2 u2 = split2(pv.z); ph[2]=u2.h; pl[2]=u2.l;
      bf2 u3 = split2(pv.w); ph[3]=u3.h; pl[3]=u3.l;
      ((bf16x4*)Ph)[j] = ph; ((bf16x4*)Pl)[j] = pl;
    }
    for (int j = tid; j < 512; j += 256)
      ((uint4*)BcS)[j] = ((const uint4*)(Bg + cb))[j];
    __syncthreads();
    f32x4 nS[4];
    #pragma unroll
    for (int it = 0; it < 4; ++it) nS[it] = f32x4_zero();
    #pragma unroll
    for (int kk = 0; kk < 2; ++kk){
      bf16x8 aH = frag64(Sh, 16*w, kk, lane), aL = frag64(Sl, 16*w, kk, lane);
      #pragma unroll
      for (int it = 0; it < 4; ++it){
        bf16x8 bH = frag64(Ph, 16*it, kk, lane), bL = frag64(Pl, 16*it, kk, lane);
        nS[it] = mfma16x16x32(aH, bH, nS[it]);
        nS[it] = mfma16x16x32(aH, bL, nS[it]);
        nS[it] = mfma16x16x32(aL, bH, nS[it]);
      }
    }
    const size_t outb = (segbase + i + 1)*4096;
    #pragma unroll
    for (int it = 0; it < 4; ++it)
      #pragma unroll
      for (int r = 0; r < 4; ++r){
        int row = 16*w + (lane>>4)*4 + r, col = 16*it + (lane&15);
        float v = nS[it][r] + (float)BcS[row*64 + col];
        Sr[it][r] = v;
        S0g[outb + (size_t)row*64 + col] = v;
      }
  }
}

// ---------------------------------------------------------------- K5: phase C, outputs + fused RMSNorm/gate (2048 blocks)
__global__ __launch_bounds__(256, 2) void k_phaseC(
    const float* __restrict__ qf32, const bf16* __restrict__ qb16,
    const float* __restrict__ kf32, const bf16* __restrict__ kb16,
    const bf16* __restrict__ gf, const float* __restrict__ logA,
    const float* __restrict__ S0g, const bf16* __restrict__ Wg, const bf16* __restrict__ Dg,
    const float* __restrict__ rms_w, bf16* __restrict__ yh, bf16* __restrict__ yl){
  __shared__ bf16 Qh[4096], Ql[4096], Kh[4096], Klo[4096];
  __shared__ bf16 Wl_[4096], Dl_[4096];
  __shared__ bf16 S0h[4096], S0l[4096];
  __shared__ bf16 AAg[4096];
  __shared__ bf16 BDt[4096];
  const int tid = threadIdx.x, lane = tid & 63, w = tid >> 6;
  const int c = blockIdx.x, h = blockIdx.y, b = blockIdx.z;
  const size_t tokbase = (size_t)b*4096 + (size_t)c*64;
  const size_t cbase = ((size_t)((b*16 + h)*64 + c)) * 4096;

  load_split_tile(qf32, qb16, tokbase, h, Qh, Ql, tid, 256);
  load_split_tile(kf32, kb16, tokbase, h, Kh, Klo, tid, 256);
  for (int i = tid; i < 512; i += 256){
    int r = i >> 3, d = r*8 + ((i&7) ^ (r&7));   // 16B-granular swizzle on the 8-elem block index
    ((uint4*)Wl_)[d] = ((const uint4*)(Wg + cbase))[i];
    ((uint4*)Dl_)[d] = ((const uint4*)(Dg + cbase))[i];
  }
  for (int i = tid; i < 1024; i += 256){
    float4 v = ((const float4*)(S0g + cbase))[i];
    bf16x4 sh, sl;
    bf2 t0 = split2(v.x); sh[0]=t0.h; sl[0]=t0.l;
    bf2 t1 = split2(v.y); sh[1]=t1.h; sl[1]=t1.l;
    bf2 t2 = split2(v.z); sh[2]=t2.h; sl[2]=t2.l;
    bf2 t3 = split2(v.w); sh[3]=t3.h; sl[3]=t3.l;
    int t = i >> 4, off = ((i&15)*4) ^ ((t&7)<<3);
    *(bf16x4*)&S0h[t*64 + off] = sh;
    *(bf16x4*)&S0l[t*64 + off] = sl;
  }
  // per-wave redundant lg cumsum (replaces lg_s/gq_s LDS)
  float la = logA[(tokbase + lane)*16 + h];
  #pragma unroll
  for (int dlt = 1; dlt < 64; dlt <<= 1){
    float o = __shfl_up(la, dlt);
    if (lane >= dlt) la += o;
  }
  __syncthreads();

  { // AAg = mask_incl(Gamma .* QK^T), 3-product
    const int t0 = 16*w;
    #pragma unroll
    for (int tu = 0; tu < 4; ++tu){
      f32x4 accm = f32x4_zero();
      #pragma unroll
      for (int kk = 0; kk < 2; ++kk){
        bf16x8 aH = fragSwz(Qh,  t0,    kk, lane);
        bf16x8 aL = fragSwz(Ql,  t0,    kk, lane);
        bf16x8 bH = fragSwz(Kh,  16*tu, kk, lane);
        bf16x8 bL = fragSwz(Klo, 16*tu, kk, lane);
        accm = mfma16x16x32(aH, bH, accm);
        accm = mfma16x16x32(aH, bL, accm);
        accm = mfma16x16x32(aL, bH, accm);
      }
      #pragma unroll
      for (int r = 0; r < 4; ++r){
        int row = t0 + (lane>>4)*4 + r, col = 16*tu + (lane&15);
        float lgr = __shfl(la, row), lgc = __shfl(la, col);
        float v = (col <= row) ? accm[r]*__expf(lgr - lgc) : 0.f;
        AAg[row*64 + (col ^ ((row&7)<<3))] = (bf16)v;
      }
    }
  }
  { // BDt[i][tau] = Dloc[tau][i] - (S0 W_hat^T)[i][tau]
    const int i0 = 16*w;
    #pragma unroll
    for (int tu = 0; tu < 4; ++tu){
      f32x4 accm = f32x4_zero();
      #pragma unroll
      for (int kk = 0; kk < 2; ++kk){
        bf16x8 aH = fragSwz(S0h, i0,    kk, lane);
        bf16x8 aL = fragSwz(S0l, i0,    kk, lane);
        bf16x8 bb = fragSwz(Wl_, 16*tu, kk, lane);
        accm = mfma16x16x32(aH, bb, accm);
        accm = mfma16x16x32(aL, bb, accm);
      }
      #pragma unroll
      for (int r = 0; r < 4; ++r){
        int row = i0 + (lane>>4)*4 + r, col = 16*tu + (lane&15);
        float v = (float)Dl_[col*64 + (row ^ ((col&7)<<3))] - accm[r];
        BDt[row*64 + (col ^ ((row&7)<<3))] = (bf16)v;
      }
    }
  }
  __syncthreads();
  for (int i = tid; i < 4096; i += 256){
    int t = i >> 6;                              // uniform per wave per iteration
    float gq = __expf(__shfl(la, t));
    float v = gq * ((float)Qh[i] + (float)Ql[i]);  // swizzle is within-row: row scale is layout-agnostic
    bf2 sp = split2(v);
    Qh[i] = sp.h; Ql[i] = sp.l;
  }
  __syncthreads();
  {
    const int t0 = 16*w;
    f32x4 o_acc[4];
    #pragma unroll
    for (int it = 0; it < 4; ++it) o_acc[it] = f32x4_zero();
    #pragma unroll
    for (int kk = 0; kk < 2; ++kk){
      bf16x8 aQh = fragSwz(Qh, t0, kk, lane);
      bf16x8 aQl = fragSwz(Ql, t0, kk, lane);
      bf16x8 aA  = fragSwz(AAg, t0, kk, lane);
      #pragma unroll
      for (int it = 0; it < 4; ++it){
        bf16x8 bSh = fragSwz(S0h, 16*it, kk, lane);
        bf16x8 bSl = fragSwz(S0l, 16*it, kk, lane);
        bf16x8 bD  = fragSwz(BDt, 16*it, kk, lane);
        f32x4 t = o_acc[it];
        t = mfma16x16x32(aQh, bSh, t);
        t = mfma16x16x32(aQh, bSl, t);
        t = mfma16x16x32(aQl, bSh, t);
        t = mfma16x16x32(aA,  bD,  t);
        o_acc[it] = t;
      }
    }
    float rw[4];
    #pragma unroll
    for (int it = 0; it < 4; ++it) rw[it] = rms_w[16*it + (lane&15)];
    #pragma unroll
    for (int r = 0; r < 4; ++r){
      float ss = 0.f;
      #pragma unroll
      for (int it = 0; it < 4; ++it) ss += o_acc[it][r]*o_acc[it][r];
      ss += __shfl_xor(ss, 1); ss += __shfl_xor(ss, 2);
      ss += __shfl_xor(ss, 4); ss += __shfl_xor(ss, 8);
      const float scale = rsqrtf(ss*(1.f/64.f) + 1e-6f);
      const int row = t0 + (lane>>4)*4 + r;
      const size_t tok = tokbase + row;
      #pragma unroll
      for (int it = 0; it < 4; ++it){
        const int col = 16*it + (lane&15);
        float g = (float)gf[tok*1024 + h*64 + col];
        float sg = g / (1.f + __expf(-g));
        float v = o_acc[it][r]*scale*rw[it]*sg;
        bf2 sp = split2(v);
        yh[tok*1024 + h*64 + col] = sp.h;
        yl[tok*1024 + h*64 + col] = sp.l;
      }
    }
  }
}

// ---------------------------------------------------------------- launcher
extern "C" void kernel_launch(void* const* d_in, const int* in_sizes, int n_in,
                              void* d_out, int out_size, void* d_ws, size_t ws_size,
                              hipStream_t stream){
  const float* x     = (const float*)d_in[0];
  const float* Wq    = (const float*)d_in[1];
  const float* Wk    = (const float*)d_in[2];
  const float* Wv    = (const float*)d_in[3];
  const float* Wa    = (const float*)d_in[4];
  const float* Wb    = (const float*)d_in[5];
  const float* A_log = (const float*)d_in[6];
  const float* dt_b  = (const float*)d_in[7];
  const float* Wgt   = (const float*)d_in[8];
  const float* Wo    = (const float*)d_in[9];
  const float* rms_w = (const float*)d_in[10];

  const bool BIG = ws_size >= (size_t)215000000;

  char* ws = (char*)d_ws;
  size_t off = 0;
  auto alloc = [&](size_t bytes)->char*{
    char* p = ws + off;
    off += (bytes + 255) & ~(size_t)255;
    return p;
  };
  const size_t PLANE = (size_t)8192*1024*2;   // bf16 activation plane (16 MiB)
  const size_t WPL   = (size_t)1024*1024*2;   // bf16 weight plane (2 MiB)
  bf16* xh  = (bf16*)alloc(PLANE);            // region also hosts Pg (A->B3), then yh
  bf16* xl  = (bf16*)alloc(PLANE);
  bf16* wqh = (bf16*)alloc(WPL); bf16* wql = (bf16*)alloc(WPL);   // wqh..wgl also hosts Bg
  bf16* wkh = (bf16*)alloc(WPL); bf16* wkl = (bf16*)alloc(WPL);
  bf16* wvh = (bf16*)alloc(WPL); bf16* wvl = (bf16*)alloc(WPL);
  bf16* wgh = (bf16*)alloc(WPL); bf16* wgl = (bf16*)alloc(WPL);
  bf16* woh = (bf16*)alloc(WPL); bf16* wol = (bf16*)alloc(WPL);
  bf16* WabTh = (bf16*)alloc((size_t)32*1024*2);
  bf16* WabTl = (bf16*)alloc((size_t)32*1024*2);
  float* qf = nullptr; bf16* qb = nullptr;
  float* kf = nullptr; bf16* kb = nullptr;
  if (BIG){ qf = (float*)alloc((size_t)8192*1024*4); kf = (float*)alloc((size_t)8192*1024*4); }
  else    { qb = (bf16*) alloc(PLANE);               kb = (bf16*) alloc(PLANE); }
  float* vf  = (float*)alloc((size_t)8192*1024*4);  // dead after phase A -> hosts S0g
  bf16* gfb  = (bf16*)alloc(PLANE);
  float* logA  = (float*)alloc((size_t)8192*16*4);
  float* betap = (float*)alloc((size_t)8192*16*4);
  bf16* Wg  = (bf16*)alloc((size_t)2048*4096*2);
  bf16* Dg  = (bf16*)alloc((size_t)2048*4096*2);
  float* Pg  = (float*)xh;            // 33.5 MiB fp32 in xh+xl (dead between GEMMs and phase C)
  float* S0g = vf;                    // 33.5 MiB fp32 (vf dead after phase A)
  bf16* Bg   = wqh;                   // 16 MiB bf16 (projection weights dead)
  float* PsegT = (float*)d_out;       // 4 MiB scratch in d_out (overwritten by final GEMM)
  float* BsegF = (float*)d_out + 1048576;  // next 4 MiB
  bf16* yh = xh;                      // phase C outputs (Pg dead after B3)
  bf16* yl = xl;

  k_cvt_x<<<8192, 256, 0, stream>>>(x, xh, xl, 2097152);
  k_transpose_w<<<dim3(32,32), 256, 0, stream>>>(Wq,  wqh, wql);
  k_transpose_w<<<dim3(32,32), 256, 0, stream>>>(Wk,  wkh, wkl);
  k_transpose_w<<<dim3(32,32), 256, 0, stream>>>(Wv,  wvh, wvl);
  k_transpose_w<<<dim3(32,32), 256, 0, stream>>>(Wgt, wgh, wgl);
  k_transpose_w<<<dim3(32,32), 256, 0, stream>>>(Wo,  woh, wol);
  k_transpose_ab<<<128, 256, 0, stream>>>(Wa, Wb, WabTh, WabTl);

  if (BIG){
    k_gemm1<1><<<dim3(64,8), 256, 0, stream>>>(xh, wqh, nullptr, qf);
    k_gemm1<2><<<dim3(64,8), 256, 0, stream>>>(xh, wkh, nullptr, kf);
  } else {
    k_gemm1<1><<<dim3(64,8), 256, 0, stream>>>(xh, wqh, qb, nullptr);
    k_gemm1<2><<<dim3(64,8), 256, 0, stream>>>(xh, wkh, kb, nullptr);
  }
  k_gemm1<0><<<dim3(64,8), 256, 0, stream>>>(xh, wvh, nullptr, vf);
  k_gemm1<0><<<dim3(64,8), 256, 0, stream>>>(xh, wgh, gfb, nullptr);

  k_ab_gemm<<<256, 256, 0, stream>>>(xh, xl, WabTh, WabTl, A_log, dt_b, logA, betap);

  k_phaseA<<<dim3(64,16,2), 128, 0, stream>>>(kf, kb, vf, logA, betap, Wg, Dg, Pg, Bg);
  k_phaseB1<<<dim3(8,32), 256, 0, stream>>>(Pg, Bg, PsegT, BsegF);
  k_phaseB2<<<32, 256, 0, stream>>>(PsegT, BsegF, S0g);
  k_phaseB3<<<dim3(8,32), 256, 0, stream>>>(Pg, Bg, S0g);
  k_phaseC<<<dim3(64,16,2), 256, 0, stream>>>(qf, qb, kf, kb, gfb, logA, S0g, Wg, Dg, rms_w, yh, yl);

  k_gemm3<<<dim3(64,8), 256, 0, stream>>>(yh, yl, woh, wol, nullptr, (float*)d_out);
}

// Round 5
// 513.134 us; speedup vs baseline: 1.5019x; 1.0015x over previous
//
#include <hip/hip_runtime.h>
#include <cstdint>
#include <cstddef>

typedef __bf16 bf16;
typedef __bf16 bf16x4 __attribute__((ext_vector_type(4)));
typedef __bf16 bf16x8 __attribute__((ext_vector_type(8)));
typedef float  f32x4  __attribute__((ext_vector_type(4)));

#define GLD_LDS16(gp, lp) \
  __builtin_amdgcn_global_load_lds((__attribute__((address_space(1))) void*)(gp), \
                                   (__attribute__((address_space(3))) void*)(lp), 16, 0, 0)

__device__ __forceinline__ f32x4 f32x4_zero(){ f32x4 v; v[0]=0.f; v[1]=0.f; v[2]=0.f; v[3]=0.f; return v; }

__device__ __forceinline__ f32x4 mfma16x16x32(bf16x8 a, bf16x8 b, f32x4 c){
  return __builtin_amdgcn_mfma_f32_16x16x32_bf16(a, b, c, 0, 0, 0);
}
// fragment of a 64-col bf16 LDS array (stride 64), LINEAR layout (phaseB kernels)
__device__ __forceinline__ bf16x8 frag64(const bf16* base, int row0, int kk, int lane){
  return *(const bf16x8*)&base[(row0 + (lane&15))*64 + kk*32 + (lane>>4)*8];
}
// fragment of a 64-col bf16 LDS array with XOR bank-swizzle: elem ^= (row&7)<<3
__device__ __forceinline__ bf16x8 fragSwz(const bf16* base, int row0, int kk, int lane){
  const int row = row0 + (lane&15);
  const int off = (kk*32 + (lane>>4)*8) ^ ((row&7)<<3);
  return *(const bf16x8*)&base[row*64 + off];
}
struct bf2 { bf16 h, l; };
__device__ __forceinline__ bf2 split2(float v){
  bf2 r; r.h = (bf16)v; r.l = (bf16)(v - (float)r.h); return r;
}

// ---------------------------------------------------------------- K0a: x -> hi/lo bf16 planes
__global__ __launch_bounds__(256) void k_cvt_x(const float* __restrict__ x,
                                               bf16* __restrict__ xh, bf16* __restrict__ xl, int n4){
  int i = blockIdx.x*256 + threadIdx.x;
  if (i < n4){
    float4 v = ((const float4*)x)[i];
    bf16x4 h, l;
    bf2 t0 = split2(v.x); h[0]=t0.h; l[0]=t0.l;
    bf2 t1 = split2(v.y); h[1]=t1.h; l[1]=t1.l;
    bf2 t2 = split2(v.z); h[2]=t2.h; l[2]=t2.l;
    bf2 t3 = split2(v.w); h[3]=t3.h; l[3]=t3.l;
    ((bf16x4*)xh)[i] = h;
    ((bf16x4*)xl)[i] = l;
  }
}

// ---------------------------------------------------------------- K0b: W[k][n] -> Wt hi/lo [n][k]
__global__ __launch_bounds__(256) void k_transpose_w(const float* __restrict__ W,
                                                     bf16* __restrict__ Wth, bf16* __restrict__ Wtl){
  __shared__ float tile[32][33];
  const int k0 = blockIdx.x*32, n0 = blockIdx.y*32;
  const int r = threadIdx.x >> 3, c4 = (threadIdx.x & 7)*4;
  float4 v = *(const float4*)&W[(size_t)(k0+r)*1024 + n0 + c4];
  tile[r][c4+0]=v.x; tile[r][c4+1]=v.y; tile[r][c4+2]=v.z; tile[r][c4+3]=v.w;
  __syncthreads();
  bf16x4 h, l;
  bf2 t0 = split2(tile[c4+0][r]); h[0]=t0.h; l[0]=t0.l;
  bf2 t1 = split2(tile[c4+1][r]); h[1]=t1.h; l[1]=t1.l;
  bf2 t2 = split2(tile[c4+2][r]); h[2]=t2.h; l[2]=t2.l;
  bf2 t3 = split2(tile[c4+3][r]); h[3]=t3.h; l[3]=t3.l;
  *(bf16x4*)&Wth[(size_t)(n0+r)*1024 + k0 + c4] = h;
  *(bf16x4*)&Wtl[(size_t)(n0+r)*1024 + k0 + c4] = l;
}

// ---------------------------------------------------------------- K0c: Walpha/Wbeta [1024][16] -> WabT hi/lo bf16 [32][1024]
__global__ __launch_bounds__(256) void k_transpose_ab(const float* __restrict__ Wa, const float* __restrict__ Wb,
                                                      bf16* __restrict__ WabTh, bf16* __restrict__ WabTl){
  int p = blockIdx.x*256 + threadIdx.x;
  if (p < 32768){
    int o = p >> 10, k = p & 1023;
    float v = (o < 16) ? Wa[k*16 + o] : Wb[k*16 + (o-16)];
    bf2 s = split2(v);
    WabTh[p] = s.h;
    WabTl[p] = s.l;
  }
}

// ---------------------------------------------------------------- K1: split-bf16 MFMA GEMM (3-product), K=1024
__global__ __launch_bounds__(256) void k_gemm3(const bf16* __restrict__ Ah, const bf16* __restrict__ Al,
                                               const bf16* __restrict__ Bth, const bf16* __restrict__ Btl,
                                               bf16* __restrict__ Cb, float* __restrict__ Cf){
  __shared__ bf16 Ash[128*32], Asl[128*32];
  __shared__ bf16 Bsh[128*32], Bsl[128*32];
  const int tid = threadIdx.x, lane = tid & 63, w = tid >> 6;
  const int wm = w >> 1, wn = w & 1;
  const size_t m0 = (size_t)blockIdx.x * 128;
  const size_t n0 = (size_t)blockIdx.y * 128;
  f32x4 acc[4][4];
  #pragma unroll
  for (int i=0;i<4;++i)
    #pragma unroll
    for (int j=0;j<4;++j) acc[i][j] = f32x4_zero();

  for (int k0 = 0; k0 < 1024; k0 += 32){
    __syncthreads();
    #pragma unroll
    for (int j = 0; j < 2; ++j){
      const int rbase = 32*w + 16*j;
      const int r = rbase + (lane >> 2);
      const int kk = k0 + (lane & 3)*8;
      GLD_LDS16(&Ah [(m0 + r)*1024 + kk], &Ash[rbase*32]);
      GLD_LDS16(&Al [(m0 + r)*1024 + kk], &Asl[rbase*32]);
      GLD_LDS16(&Bth[(n0 + r)*1024 + kk], &Bsh[rbase*32]);
      GLD_LDS16(&Btl[(n0 + r)*1024 + kk], &Bsl[rbase*32]);
    }
    __syncthreads();
    bf16x8 ah[4], al[4], bh[4], bl[4];
    #pragma unroll
    for (int t=0;t<4;++t){
      ah[t] = *(const bf16x8*)&Ash[(64*wm + 16*t + (lane&15))*32 + (lane>>4)*8];
      al[t] = *(const bf16x8*)&Asl[(64*wm + 16*t + (lane&15))*32 + (lane>>4)*8];
      bh[t] = *(const bf16x8*)&Bsh[(64*wn + 16*t + (lane&15))*32 + (lane>>4)*8];
      bl[t] = *(const bf16x8*)&Bsl[(64*wn + 16*t + (lane&15))*32 + (lane>>4)*8];
    }
    #pragma unroll
    for (int i=0;i<4;++i)
      #pragma unroll
      for (int j=0;j<4;++j){
        f32x4 t = acc[i][j];
        t = mfma16x16x32(ah[i], bh[j], t);
        t = mfma16x16x32(ah[i], bl[j], t);
        t = mfma16x16x32(al[i], bh[j], t);
        acc[i][j] = t;
      }
  }
  #pragma unroll
  for (int i=0;i<4;++i)
    #pragma unroll
    for (int j=0;j<4;++j)
      #pragma unroll
      for (int r=0;r<4;++r){
        size_t row = m0 + 64*wm + 16*i + (lane>>4)*4 + r;
        size_t col = n0 + 64*wn + 16*j + (lane&15);
        float v = acc[i][j][r];
        if (Cf) Cf[row*1024 + col] = v;
        else    Cb[row*1024 + col] = (bf16)v;
      }
}

// ---------------------------------------------------------------- K1b: single-bf16 MFMA GEMM, K=1024
// NRM: 0 = plain, 1 = fused q l2norm (0.125/||.||), 2 = fused k l2norm (1/||.||).
// Cl != nullptr -> write hi/lo bf16 split planes (Cb=hi, Cl=lo) so consumers can
// global_load_lds-stage directly (no fp32->split VALU work downstream).
template<int NRM>
__global__ __launch_bounds__(256) void k_gemm1(const bf16* __restrict__ Ah, const bf16* __restrict__ Bth,
                                               bf16* __restrict__ Cb, float* __restrict__ Cf,
                                               bf16* __restrict__ Cl){
  __shared__ bf16 Ash[128*32];
  __shared__ bf16 Bsh[128*32];
  const int tid = threadIdx.x, lane = tid & 63, w = tid >> 6;
  const int wm = w >> 1, wn = w & 1;
  const size_t m0 = (size_t)blockIdx.x * 128;
  const size_t n0 = (size_t)blockIdx.y * 128;
  f32x4 acc[4][4];
  #pragma unroll
  for (int i=0;i<4;++i)
    #pragma unroll
    for (int j=0;j<4;++j) acc[i][j] = f32x4_zero();

  for (int k0 = 0; k0 < 1024; k0 += 32){
    __syncthreads();
    #pragma unroll
    for (int j = 0; j < 2; ++j){
      const int rbase = 32*w + 16*j;
      const int r = rbase + (lane >> 2);
      const int kk = k0 + (lane & 3)*8;
      GLD_LDS16(&Ah [(m0 + r)*1024 + kk], &Ash[rbase*32]);
      GLD_LDS16(&Bth[(n0 + r)*1024 + kk], &Bsh[rbase*32]);
    }
    __syncthreads();
    bf16x8 ah[4], bh[4];
    #pragma unroll
    for (int t=0;t<4;++t){
      ah[t] = *(const bf16x8*)&Ash[(64*wm + 16*t + (lane&15))*32 + (lane>>4)*8];
      bh[t] = *(const bf16x8*)&Bsh[(64*wn + 16*t + (lane&15))*32 + (lane>>4)*8];
    }
    #pragma unroll
    for (int i=0;i<4;++i)
      #pragma unroll
      for (int j=0;j<4;++j)
        acc[i][j] = mfma16x16x32(ah[i], bh[j], acc[i][j]);
  }
  #pragma unroll
  for (int i=0;i<4;++i)
    #pragma unroll
    for (int r=0;r<4;++r){
      float sc = 1.f;
      if (NRM){
        float ss = 0.f;
        #pragma unroll
        for (int j=0;j<4;++j) ss += acc[i][j][r]*acc[i][j][r];
        ss += __shfl_xor(ss, 1); ss += __shfl_xor(ss, 2);
        ss += __shfl_xor(ss, 4); ss += __shfl_xor(ss, 8);
        sc = (NRM==1 ? 0.125f : 1.0f) / fmaxf(sqrtf(ss), 1e-12f);
      }
      #pragma unroll
      for (int j=0;j<4;++j){
        size_t row = m0 + 64*wm + 16*i + (lane>>4)*4 + r;
        size_t col = n0 + 64*wn + 16*j + (lane&15);
        float v = acc[i][j][r]*sc;
        if (Cl){ bf2 sp = split2(v); Cb[row*1024 + col] = sp.h; Cl[row*1024 + col] = sp.l; }
        else if (Cf) Cf[row*1024 + col] = v;
        else         Cb[row*1024 + col] = (bf16)v;
      }
    }
}

// ---------------------------------------------------------------- K2: alpha/beta projections as split-bf16 MFMA GEMM
__global__ __launch_bounds__(256) void k_ab_gemm(const bf16* __restrict__ xh, const bf16* __restrict__ xl,
    const bf16* __restrict__ WabTh, const bf16* __restrict__ WabTl,
    const float* __restrict__ A_log, const float* __restrict__ dt_bias,
    float* __restrict__ logA, float* __restrict__ betap){
  __shared__ bf16 Ash[2][2048], Asl[2][2048];   // 32 rows x 64 k per buffer
  const int tid = threadIdx.x, lane = tid & 63, w = tid >> 6;
  const int mt = w >> 1, nt = w & 1;
  const size_t m0 = (size_t)blockIdx.x * 32;
  const int srow = tid >> 3;
  const int scol = 8*((tid & 7) ^ (srow & 7));
  const size_t sg = (m0 + srow)*1024 + scol;

  f32x4 acc = f32x4_zero();
  GLD_LDS16(&xh[sg], &Ash[0][w*512]);
  GLD_LDS16(&xl[sg], &Asl[0][w*512]);
  for (int s = 0; s < 16; ++s){
    const int cur = s & 1;
    __syncthreads();                    // implicit vmcnt(0): buf[cur] staged
    if (s + 1 < 16){
      const size_t g = sg + (size_t)(s+1)*64;
      GLD_LDS16(&xh[g], &Ash[cur^1][w*512]);
      GLD_LDS16(&xl[g], &Asl[cur^1][w*512]);
    }
    const int k0 = s*64;
    #pragma unroll
    for (int kk = 0; kk < 2; ++kk){
      bf16x8 aH = fragSwz(Ash[cur], 16*mt, kk, lane);
      bf16x8 aL = fragSwz(Asl[cur], 16*mt, kk, lane);
      const size_t bo = (size_t)(16*nt + (lane&15))*1024 + k0 + kk*32 + (lane>>4)*8;
      bf16x8 bH = *(const bf16x8*)&WabTh[bo];
      bf16x8 bL = *(const bf16x8*)&WabTl[bo];
      acc = mfma16x16x32(aH, bH, acc);
      acc = mfma16x16x32(aH, bL, acc);
      acc = mfma16x16x32(aL, bH, acc);
    }
  }
  const int col = lane & 15;
  #pragma unroll
  for (int r = 0; r < 4; ++r){
    const size_t row = m0 + 16*mt + (lane>>4)*4 + r;
    float v = acc[r];
    if (nt == 0){
      float z = v + dt_bias[col];
      float dt = (z > 20.f) ? z : log1pf(expf(z));
      logA[row*16 + col] = -expf(A_log[col]) * dt;   // log(alpha_t)
    } else {
      betap[row*16 + col] = 1.f/(1.f + expf(-v));    // beta_t
    }
  }
}

// ---------------------------------------------------------------- K3: phase A (2048 blocks, 128 thr)
// LDS = 32768 B -> 5 blocks/CU; __launch_bounds__(128,4) caps VGPR at 128 (VGPR 84, no spill r4).
// K tile staged via global_load_lds from pre-split kh/kl planes (pre-swizzled global source,
// linear LDS dest, swizzled read -- rule both-sides). beta is FOLDED into E rows and the RHS
// at init, removing 64 serial ds_bpermute (shfl(bet,t)) from the solve's dependency chain.
__global__ __launch_bounds__(128, 4) void k_phaseA(const bf16* __restrict__ khp, const bf16* __restrict__ klp,
    const float* __restrict__ vf, const float* __restrict__ logA, const float* __restrict__ betap,
    bf16* __restrict__ Wg, bf16* __restrict__ Dg, float* __restrict__ Pg, bf16* __restrict__ Bg){
  __shared__ bf16  Kh[4096], Kl_[4096];   // 8 KiB + 8 KiB
  __shared__ float Ef[4096];              // 16 KiB; row 0 = lg cumsum
  bf16* DT  = Kh;                         // overlay: Dsol^T (after KtT build)
  bf16* WT  = Kl_;                        // overlay: Wsol^T
  bf16* KtT = (bf16*)&Ef[2048];           // overlay: K_til^T (Ef rows 32..63, after solve)
  const int tid = threadIdx.x, lane = tid & 63, wid = tid >> 6;
  const int c = blockIdx.x, h = blockIdx.y, b = blockIdx.z;
  const size_t tokbase = (size_t)b*4096 + (size_t)c*64;
  const size_t cbase = ((size_t)((b*16 + h)*64 + c)) * 4096;

  { // async stage K tile (hi/lo) with pre-swizzled source
    const int chunk = tid & 7, r0 = tid >> 3;       // r0: wave0 0..7, wave1 8..15
    #pragma unroll
    for (int rr = 0; rr < 4; ++rr){
      const int row = 16*rr + r0;
      const size_t g = (tokbase + row)*1024 + (size_t)h*64 + 8*(chunk ^ (row & 7));
      GLD_LDS16(&khp[g], &Kh[(16*rr + 8*wid)*64]);
      if (klp) GLD_LDS16(&klp[g], &Kl_[(16*rr + 8*wid)*64]);
    }
    if (!klp){
      uint4 z4; z4.x=0; z4.y=0; z4.z=0; z4.w=0;
      for (int z = tid; z < 512; z += 128) ((uint4*)Kl_)[z] = z4;
    }
  }
  const float bet = betap[(tokbase + lane)*16 + h];   // per-lane beta_t, t = lane
  if (tid < 64){
    float la = logA[(tokbase + tid)*16 + h];
    #pragma unroll
    for (int dlt = 1; dlt < 64; dlt <<= 1){
      float o = __shfl_up(la, dlt);
      if (lane >= dlt) la += o;
    }
    Ef[tid] = la;                // lg cumsum in E row 0 (row 0 never read by solve)
  }
  __syncthreads();               // GLD staged (vmcnt drain at barrier) + lg ready

  // E~[t][tau] = beta_t * (gamma_t/gamma_tau)*(k_t . k_tau), strictly lower; else 0
  #pragma unroll
  for (int tt = 0; tt < 2; ++tt){
    const int t0 = 32*wid + 16*tt;
    #pragma unroll
    for (int tu = 0; tu < 4; ++tu){
      f32x4 accm = f32x4_zero();
      #pragma unroll
      for (int kk = 0; kk < 2; ++kk){
        bf16x8 aH = fragSwz(Kh,  t0,    kk, lane);
        bf16x8 aL = fragSwz(Kl_, t0,    kk, lane);
        bf16x8 bH = fragSwz(Kh,  16*tu, kk, lane);
        bf16x8 bL = fragSwz(Kl_, 16*tu, kk, lane);
        accm = mfma16x16x32(aH, bH, accm);
        accm = mfma16x16x32(aH, bL, accm);
        accm = mfma16x16x32(aL, bH, accm);
      }
      #pragma unroll
      for (int r = 0; r < 4; ++r){
        int row = t0 + (lane>>4)*4 + r, col = 16*tu + (lane&15);
        float bR = __shfl(bet, row);   // beta folded into E row (independent bpermutes)
        float ev = (col < row) ? accm[r]*__expf(Ef[row] - Ef[col])*bR : 0.f;
        if (row > 0) Ef[row*64 + col] = ev;   // row 0 never read; keeps lg intact
      }
    }
  }
  __syncthreads();   // E complete (both waves) before solve reads

  // right-looking blocked forward substitution with beta pre-folded:
  // d[t] = beta_t*X[t];  d[t] -= sum_j E~[t][j] d[j]   (pure FMA chain, no shfl in chain)
  float d[64];
  {
    if (wid == 0){
      #pragma unroll
      for (int t = 0; t < 64; ++t)
        d[t] = __shfl(bet, t) * vf[(tokbase + t)*1024 + h*64 + lane];
    } else {
      #pragma unroll
      for (int t = 0; t < 64; ++t){
        int ks = lane ^ ((t&7)<<3);
        d[t] = __shfl(bet, t) * __expf(Ef[t]) * ((float)Kh[t*64 + ks] + (float)Kl_[t*64 + ks]);
      }
    }
    #pragma unroll
    for (int bi = 0; bi < 4; ++bi){
      // diagonal 16x16 unit-lower solve
      #pragma unroll
      for (int tt = 0; tt < 16; ++tt){
        const int t = 16*bi + tt;
        float s = 0.f;
        #pragma unroll
        for (int j = 0; j < 16; ++j)
          if (j < tt) s += Ef[t*64 + 16*bi + j] * d[16*bi + j];
        d[t] = d[t] - s;
      }
      // trailing rank-16 update of all later blocks
      #pragma unroll
      for (int b2 = bi + 1; b2 < 4; ++b2)
        #pragma unroll
        for (int tt = 0; tt < 16; ++tt){
          const int t = 16*b2 + tt;
          float a0=0.f,a1=0.f,a2=0.f,a3=0.f;
          #pragma unroll
          for (int q = 0; q < 4; ++q){
            float4 e = *(const float4*)&Ef[t*64 + 16*bi + q*4];
            a0 += e.x * d[16*bi + q*4 + 0];
            a1 += e.y * d[16*bi + q*4 + 1];
            a2 += e.z * d[16*bi + q*4 + 2];
            a3 += e.w * d[16*bi + q*4 + 3];
          }
          d[t] -= (a0+a1)+(a2+a3);
        }
    }
  }
  __syncthreads();   // all Ef/Kh/Kl solve reads done

  // K_til^T[j][t] = (gamma_L/gamma_t) * k[t][j]  (built AFTER solve, into Ef rows 32..63)
  {
    const float gsc = __expf(Ef[63] - Ef[lane]);   // t == lane for the stride-128 loop
    for (int i = tid; i < 4096; i += 128){
      int t = lane, j = i >> 6;
      int ks = j ^ ((t&7)<<3);
      float kv = (float)Kh[t*64 + ks] + (float)Kl_[t*64 + ks];
      KtT[j*64 + (t ^ ((j&7)<<3))] = (bf16)(gsc * kv);
    }
  }
  __syncthreads();   // KtT built; Kh/Kl_ now dead -> DT/WT overlay safe

  const float gL = __expf(Ef[63]);   // Ef row 0 intact (KtT occupies rows 32..63 only)
  {
    bf16* myT = wid ? WT : DT;
    #pragma unroll
    for (int s4 = 0; s4 < 16; ++s4){
      bf16x4 v4;
      v4[0]=(bf16)d[s4*4+0]; v4[1]=(bf16)d[s4*4+1];
      v4[2]=(bf16)d[s4*4+2]; v4[3]=(bf16)d[s4*4+3];
      *(bf16x4*)&myT[lane*64 + ((s4*4) ^ ((lane&7)<<3))] = v4;
    }
    bf16* myG = wid ? Wg : Dg;
    #pragma unroll
    for (int t = 0; t < 64; ++t)
      myG[cbase + (size_t)t*64 + lane] = (bf16)d[t];
  }
  __syncthreads();

  // P^T[j][i] = gamma_L*I - sum_t K_til[t][j]*Wsol[t][i]  (wave0, MFMA, fp32 out)
  // B[i][j]   =              sum_t Dsol[t][i]*K_til[t][j]  (wave1, MFMA, bf16 out)
  if (wid == 0){
    #pragma unroll
    for (int tj = 0; tj < 4; ++tj)
      #pragma unroll
      for (int ti = 0; ti < 4; ++ti){
        f32x4 acc = f32x4_zero();
        #pragma unroll
        for (int kk = 0; kk < 2; ++kk)
          acc = mfma16x16x32(fragSwz(KtT, 16*tj, kk, lane), fragSwz(WT, 16*ti, kk, lane), acc);
        #pragma unroll
        for (int r = 0; r < 4; ++r){
          int row = 16*tj + (lane>>4)*4 + r, col = 16*ti + (lane&15);
          Pg[cbase + (size_t)row*64 + col] = ((row == col) ? gL : 0.f) - acc[r];
        }
      }
  } else {
    #pragma unroll
    for (int ti = 0; ti < 4; ++ti)
      #pragma unroll
      for (int tj = 0; tj < 4; ++tj){
        f32x4 acc = f32x4_zero();
        #pragma unroll
        for (int kk = 0; kk < 2; ++kk)
          acc = mfma16x16x32(fragSwz(DT, 16*ti, kk, lane), fragSwz(KtT, 16*tj, kk, lane), acc);
        #pragma unroll
        for (int r = 0; r < 4; ++r){
          int row = 16*ti + (lane>>4)*4 + r, col = 16*tj + (lane&15);
          Bg[cbase + (size_t)row*64 + col] = (bf16)acc[r];
        }
      }
  }
}

// ---------------------------------------------------------------- K4a: segment composition (256 blocks: 8 seg x 32 chains)
__global__ __launch_bounds__(256) void k_phaseB1(const float* __restrict__ Pg, const bf16* __restrict__ Bg,
                                                 float* __restrict__ PsegT, float* __restrict__ BsegF){
  __shared__ bf16 PaccH[4096], PaccL[4096], BaccH[4096], BaccL[4096];
  __shared__ bf16 PcH[4096], PcL[4096];
  __shared__ bf16 BcS[4096];
  const int tid = threadIdx.x, lane = tid & 63, w = tid >> 6;
  const int seg = blockIdx.x;
  const size_t chain = blockIdx.y;
  f32x4 Pr[4], Br[4];
  #pragma unroll
  for (int it = 0; it < 4; ++it){
    #pragma unroll
    for (int r = 0; r < 4; ++r){
      int row = 16*w + (lane>>4)*4 + r, col = 16*it + (lane&15);
      Pr[it][r] = (row == col) ? 1.f : 0.f;   // Pacc = I
      Br[it][r] = 0.f;                        // Bacc = 0
    }
  }
  for (int i = 0; i < 8; ++i){
    const size_t cb = (chain*64 + (size_t)seg*8 + i)*4096;
    #pragma unroll
    for (int it = 0; it < 4; ++it)
      #pragma unroll
      for (int r = 0; r < 4; ++r){
        int row = 16*w + (lane>>4)*4 + r, col = 16*it + (lane&15);
        bf2 sp = split2(Pr[it][r]); PaccH[row*64+col] = sp.h; PaccL[row*64+col] = sp.l;
        bf2 sb = split2(Br[it][r]); BaccH[row*64+col] = sb.h; BaccL[row*64+col] = sb.l;
      }
    __syncthreads();   // prev iter's MFMA done -> safe to overwrite PcH/L
    for (int j = tid; j < 1024; j += 256){
      float4 pv = ((const float4*)(Pg + cb))[j];
      bf16x4 ph, pl;
      bf2 u0 = split2(pv.x); ph[0]=u0.h; pl[0]=u0.l;
      bf2 u1 = split2(pv.y); ph[1]=u1.h; pl[1]=u1.l;
      bf2 u2 = split2(pv.z); ph[2]=u2.h; pl[2]=u2.l;
      bf2 u3 = split2(pv.w); ph[3]=u3.h; pl[3]=u3.l;
      ((bf16x4*)PcH)[j] = ph; ((bf16x4*)PcL)[j] = pl;
    }
    for (int j = tid; j < 512; j += 256)
      ((uint4*)BcS)[j] = ((const uint4*)(Bg + cb))[j];
    __syncthreads();
    f32x4 nP[4], nB[4];
    #pragma unroll
    for (int it = 0; it < 4; ++it){ nP[it] = f32x4_zero(); nB[it] = f32x4_zero(); }
    #pragma unroll
    for (int kk = 0; kk < 2; ++kk){
      bf16x8 aPH = frag64(PaccH, 16*w, kk, lane), aPL = frag64(PaccL, 16*w, kk, lane);
      bf16x8 aBH = frag64(BaccH, 16*w, kk, lane), aBL = frag64(BaccL, 16*w, kk, lane);
      #pragma unroll
      for (int it = 0; it < 4; ++it){
        bf16x8 bH = frag64(PcH, 16*it, kk, lane), bL = frag64(PcL, 16*it, kk, lane);
        nP[it] = mfma16x16x32(aPH, bH, nP[it]);
        nP[it] = mfma16x16x32(aPH, bL, nP[it]);
        nP[it] = mfma16x16x32(aPL, bH, nP[it]);
        nB[it] = mfma16x16x32(aBH, bH, nB[it]);
        nB[it] = mfma16x16x32(aBH, bL, nB[it]);
        nB[it] = mfma16x16x32(aBL, bH, nB[it]);
      }
    }
    #pragma unroll
    for (int it = 0; it < 4; ++it)
      #pragma unroll
      for (int r = 0; r < 4; ++r){
        int row = 16*w + (lane>>4)*4 + r, col = 16*it + (lane&15);
        Pr[it][r] = nP[it][r];
        Br[it][r] = nB[it][r] + (float)BcS[row*64 + col];
      }
  }
  const size_t sb = (chain*8 + seg)*4096;
  #pragma unroll
  for (int it = 0; it < 4; ++it)
    #pragma unroll
    for (int r = 0; r < 4; ++r){
      int row = 16*w + (lane>>4)*4 + r, col = 16*it + (lane&15);
      PsegT[sb + (size_t)col*64 + row] = Pr[it][r];   // transposed (B-operand layout)
      BsegF[sb + (size_t)row*64 + col] = Br[it][r];   // natural
    }
}

// ---------------------------------------------------------------- K4b: segment-level scan (32 blocks, 8 steps)
__global__ __launch_bounds__(256) void k_phaseB2(const float* __restrict__ PsegT, const float* __restrict__ BsegF,
                                                 float* __restrict__ S0g){
  __shared__ bf16 Sh[4096], Sl[4096], Ph[4096], Pl[4096];
  __shared__ float Bf[4096];
  const int tid = threadIdx.x, lane = tid & 63, w = tid >> 6;
  const size_t bid = blockIdx.x;
  f32x4 Sr[4];
  #pragma unroll
  for (int it = 0; it < 4; ++it) Sr[it] = f32x4_zero();
  for (int seg = 0; seg < 8; ++seg){
    const size_t sb  = (bid*8 + seg)*4096;
    const size_t s0b = (bid*64 + (size_t)seg*8)*4096;
    #pragma unroll
    for (int it = 0; it < 4; ++it)
      #pragma unroll
      for (int r = 0; r < 4; ++r){
        int row = 16*w + (lane>>4)*4 + r, col = 16*it + (lane&15);
        S0g[s0b + (size_t)row*64 + col] = Sr[it][r];
        bf2 sp = split2(Sr[it][r]); Sh[row*64+col] = sp.h; Sl[row*64+col] = sp.l;
      }
    __syncthreads();
    for (int j = tid; j < 1024; j += 256){
      float4 pv = ((const float4*)(PsegT + sb))[j];
      bf16x4 ph, pl;
      bf2 u0 = split2(pv.x); ph[0]=u0.h; pl[0]=u0.l;
      bf2 u1 = split2(pv.y); ph[1]=u1.h; pl[1]=u1.l;
      bf2 u2 = split2(pv.z); ph[2]=u2.h; pl[2]=u2.l;
      bf2 u3 = split2(pv.w); ph[3]=u3.h; pl[3]=u3.l;
      ((bf16x4*)Ph)[j] = ph; ((bf16x4*)Pl)[j] = pl;
      ((float4*)Bf)[j] = ((const float4*)(BsegF + sb))[j];
    }
    __syncthreads();
    f32x4 nS[4];
    #pragma unroll
    for (int it = 0; it < 4; ++it) nS[it] = f32x4_zero();
    #pragma unroll
    for (int kk = 0; kk < 2; ++kk){
      bf16x8 aH = frag64(Sh, 16*w, kk, lane), aL = frag64(Sl, 16*w, kk, lane);
      #pragma unroll
      for (int it = 0; it < 4; ++it){
        bf16x8 bH = frag64(Ph, 16*it, kk, lane), bL = frag64(Pl, 16*it, kk, lane);
        nS[it] = mfma16x16x32(aH, bH, nS[it]);
        nS[it] = mfma16x16x32(aH, bL, nS[it]);
        nS[it] = mfma16x16x32(aL, bH, nS[it]);
      }
    }
    #pragma unroll
    for (int it = 0; it < 4; ++it)
      #pragma unroll
      for (int r = 0; r < 4; ++r){
        int row = 16*w + (lane>>4)*4 + r, col = 16*it + (lane&15);
        Sr[it][r] = nS[it][r] + Bf[row*64 + col];
      }
  }
}

// ---------------------------------------------------------------- K4c: within-segment replay (256 blocks, 7 steps)
__global__ __launch_bounds__(256) void k_phaseB3(const float* __restrict__ Pg, const bf16* __restrict__ Bg,
                                                 float* __restrict__ S0g){
  __shared__ bf16 Sh[4096], Sl[4096], Ph[4096], Pl[4096];
  __shared__ bf16 BcS[4096];
  const int tid = threadIdx.x, lane = tid & 63, w = tid >> 6;
  const int seg = blockIdx.x;
  const size_t chain = blockIdx.y;
  const size_t segbase = chain*64 + (size_t)seg*8;
  f32x4 Sr[4];
  #pragma unroll
  for (int it = 0; it < 4; ++it)
    #pragma unroll
    for (int r = 0; r < 4; ++r){
      int row = 16*w + (lane>>4)*4 + r, col = 16*it + (lane&15);
      Sr[it][r] = S0g[segbase*4096 + (size_t)row*64 + col];
    }
  for (int i = 0; i < 7; ++i){
    const size_t cb = (segbase + i)*4096;
    #pragma unroll
    for (int it = 0; it < 4; ++it)
      #pragma unroll
      for (int r = 0; r < 4; ++r){
        int row = 16*w + (lane>>4)*4 + r, col = 16*it + (lane&15);
        bf2 sp = split2(Sr[it][r]); Sh[row*64+col] = sp.h; Sl[row*64+col] = sp.l;
      }
    __syncthreads();
    for (int j = tid; j < 1024; j += 256){
      float4 pv = ((const float4*)(Pg + cb))[j];
      bf16x4 ph, pl;
      bf2 u0 = split2(pv.x); ph[0]=u0.h; pl[0]=u0.l;
      bf2 u1 = split2(pv.y); ph[1]=u1.h; pl[1]=u1.l;
      bf2 u2 = split2(pv.z); ph[2]=u2.h; pl[2]=u2.l;
      bf2 u3 = split2(pv.w); ph[3]=u3.h; pl[3]=u3.l;
      ((bf16x4*)Ph)[j] = ph; ((bf16x4*)Pl)[j] = pl;
    }
    for (int j = tid; j < 512; j += 256)
      ((uint4*)BcS)[j] = ((const uint4*)(Bg + cb))[j];
    __syncthreads();
    f32x4 nS[4];
    #pragma unroll
    for (int it = 0; it < 4; ++it) nS[it] = f32x4_zero();
    #pragma unroll
    for (int kk = 0; kk < 2; ++kk){
      bf16x8 aH = frag64(Sh, 16*w, kk, lane), aL = frag64(Sl, 16*w, kk, lane);
      #pragma unroll
      for (int it = 0; it < 4; ++it){
        bf16x8 bH = frag64(Ph, 16*it, kk, lane), bL = frag64(Pl, 16*it, kk, lane);
        nS[it] = mfma16x16x32(aH, bH, nS[it]);
        nS[it] = mfma16x16x32(aH, bL, nS[it]);
        nS[it] = mfma16x16x32(aL, bH, nS[it]);
      }
    }
    const size_t outb = (segbase + i + 1)*4096;
    #pragma unroll
    for (int it = 0; it < 4; ++it)
      #pragma unroll
      for (int r = 0; r < 4; ++r){
        int row = 16*w + (lane>>4)*4 + r, col = 16*it + (lane&15);
        float v = nS[it][r] + (float)BcS[row*64 + col];
        Sr[it][r] = v;
        S0g[outb + (size_t)row*64 + col] = v;
      }
  }
}

// ---------------------------------------------------------------- K5: phase C, outputs + fused RMSNorm/gate (2048 blocks)
// Q/K/W/D tiles staged via global_load_lds (pre-swizzled source); S0 stays fp32->split VALU.
__global__ __launch_bounds__(256, 2) void k_phaseC(
    const bf16* __restrict__ qhp, const bf16* __restrict__ qlp,
    const bf16* __restrict__ khp, const bf16* __restrict__ klp,
    const bf16* __restrict__ gf, const float* __restrict__ logA,
    const float* __restrict__ S0g, const bf16* __restrict__ Wg, const bf16* __restrict__ Dg,
    const float* __restrict__ rms_w, bf16* __restrict__ yh, bf16* __restrict__ yl){
  __shared__ bf16 Qh[4096], Ql[4096], Kh[4096], Klo[4096];
  __shared__ bf16 Wl_[4096], Dl_[4096];
  __shared__ bf16 S0h[4096], S0l[4096];
  __shared__ bf16 AAg[4096];
  __shared__ bf16 BDt[4096];
  const int tid = threadIdx.x, lane = tid & 63, w = tid >> 6;
  const int c = blockIdx.x, h = blockIdx.y, b = blockIdx.z;
  const size_t tokbase = (size_t)b*4096 + (size_t)c*64;
  const size_t cbase = ((size_t)((b*16 + h)*64 + c)) * 4096;

  { // async stage Q/K (hi/lo) + Wg/Dg with pre-swizzled source
    const int chunk = tid & 7, r0 = tid >> 3;   // r0 0..31; wave w rows 8w..8w+7 per round
    #pragma unroll
    for (int rr = 0; rr < 2; ++rr){
      const int row = 32*rr + r0;
      const int dbase = (32*rr + 8*w)*64;
      const size_t g = (tokbase + row)*1024 + (size_t)h*64 + 8*(chunk ^ (row & 7));
      GLD_LDS16(&qhp[g], &Qh[dbase]);
      if (qlp) GLD_LDS16(&qlp[g], &Ql[dbase]);
      GLD_LDS16(&khp[g], &Kh[dbase]);
      if (klp) GLD_LDS16(&klp[g], &Klo[dbase]);
      const size_t gg = cbase + (size_t)row*64 + 8*(chunk ^ (row & 7));
      GLD_LDS16(&Wg[gg], &Wl_[dbase]);
      GLD_LDS16(&Dg[gg], &Dl_[dbase]);
    }
    if (!qlp){
      uint4 z4; z4.x=0; z4.y=0; z4.z=0; z4.w=0;
      for (int z = tid; z < 512; z += 256){ ((uint4*)Ql)[z] = z4; ((uint4*)Klo)[z] = z4; }
    }
  }
  for (int i = tid; i < 1024; i += 256){
    float4 v = ((const float4*)(S0g + cbase))[i];
    bf16x4 sh, sl;
    bf2 t0 = split2(v.x); sh[0]=t0.h; sl[0]=t0.l;
    bf2 t1 = split2(v.y); sh[1]=t1.h; sl[1]=t1.l;
    bf2 t2 = split2(v.z); sh[2]=t2.h; sl[2]=t2.l;
    bf2 t3 = split2(v.w); sh[3]=t3.h; sl[3]=t3.l;
    int t = i >> 4, off = ((i&15)*4) ^ ((t&7)<<3);
    *(bf16x4*)&S0h[t*64 + off] = sh;
    *(bf16x4*)&S0l[t*64 + off] = sl;
  }
  // per-wave redundant lg cumsum
  float la = logA[(tokbase + lane)*16 + h];
  #pragma unroll
  for (int dlt = 1; dlt < 64; dlt <<= 1){
    float o = __shfl_up(la, dlt);
    if (lane >= dlt) la += o;
  }
  __syncthreads();

  { // AAg = mask_incl(Gamma .* QK^T), 3-product
    const int t0 = 16*w;
    #pragma unroll
    for (int tu = 0; tu < 4; ++tu){
      f32x4 accm = f32x4_zero();
      #pragma unroll
      for (int kk = 0; kk < 2; ++kk){
        bf16x8 aH = fragSwz(Qh,  t0,    kk, lane);
        bf16x8 aL = fragSwz(Ql,  t0,    kk, lane);
        bf16x8 bH = fragSwz(Kh,  16*tu, kk, lane);
        bf16x8 bL = fragSwz(Klo, 16*tu, kk, lane);
        accm = mfma16x16x32(aH, bH, accm);
        accm = mfma16x16x32(aH, bL, accm);
        accm = mfma16x16x32(aL, bH, accm);
      }
      #pragma unroll
      for (int r = 0; r < 4; ++r){
        int row = t0 + (lane>>4)*4 + r, col = 16*tu + (lane&15);
        float lgr = __shfl(la, row), lgc = __shfl(la, col);
        float v = (col <= row) ? accm[r]*__expf(lgr - lgc) : 0.f;
        AAg[row*64 + (col ^ ((row&7)<<3))] = (bf16)v;
      }
    }
  }
  { // BDt[i][tau] = Dloc[tau][i] - (S0 W_hat^T)[i][tau]
    const int i0 = 16*w;
    #pragma unroll
    for (int tu = 0; tu < 4; ++tu){
      f32x4 accm = f32x4_zero();
      #pragma unroll
      for (int kk = 0; kk < 2; ++kk){
        bf16x8 aH = fragSwz(S0h, i0,    kk, lane);
        bf16x8 aL = fragSwz(S0l, i0,    kk, lane);
        bf16x8 bb = fragSwz(Wl_, 16*tu, kk, lane);
        accm = mfma16x16x32(aH, bb, accm);
        accm = mfma16x16x32(aL, bb, accm);
      }
      #pragma unroll
      for (int r = 0; r < 4; ++r){
        int row = i0 + (lane>>4)*4 + r, col = 16*tu + (lane&15);
        float v = (float)Dl_[col*64 + (row ^ ((col&7)<<3))] - accm[r];
        BDt[row*64 + (col ^ ((row&7)<<3))] = (bf16)v;
      }
    }
  }
  __syncthreads();
  for (int i = tid; i < 4096; i += 256){
    int t = i >> 6;                              // uniform per wave per iteration
    float gq = __expf(__shfl(la, t));
    float v = gq * ((float)Qh[i] + (float)Ql[i]);  // swizzle is within-row: row scale layout-agnostic
    bf2 sp = split2(v);
    Qh[i] = sp.h; Ql[i] = sp.l;
  }
  __syncthreads();
  {
    const int t0 = 16*w;
    f32x4 o_acc[4];
    #pragma unroll
    for (int it = 0; it < 4; ++it) o_acc[it] = f32x4_zero();
    #pragma unroll
    for (int kk = 0; kk < 2; ++kk){
      bf16x8 aQh = fragSwz(Qh, t0, kk, lane);
      bf16x8 aQl = fragSwz(Ql, t0, kk, lane);
      bf16x8 aA  = fragSwz(AAg, t0, kk, lane);
      #pragma unroll
      for (int it = 0; it < 4; ++it){
        bf16x8 bSh = fragSwz(S0h, 16*it, kk, lane);
        bf16x8 bSl = fragSwz(S0l, 16*it, kk, lane);
        bf16x8 bD  = fragSwz(BDt, 16*it, kk, lane);
        f32x4 t = o_acc[it];
        t = mfma16x16x32(aQh, bSh, t);
        t = mfma16x16x32(aQh, bSl, t);
        t = mfma16x16x32(aQl, bSh, t);
        t = mfma16x16x32(aA,  bD,  t);
        o_acc[it] = t;
      }
    }
    float rw[4];
    #pragma unroll
    for (int it = 0; it < 4; ++it) rw[it] = rms_w[16*it + (lane&15)];
    #pragma unroll
    for (int r = 0; r < 4; ++r){
      float ss = 0.f;
      #pragma unroll
      for (int it = 0; it < 4; ++it) ss += o_acc[it][r]*o_acc[it][r];
      ss += __shfl_xor(ss, 1); ss += __shfl_xor(ss, 2);
      ss += __shfl_xor(ss, 4); ss += __shfl_xor(ss, 8);
      const float scale = rsqrtf(ss*(1.f/64.f) + 1e-6f);
      const int row = t0 + (lane>>4)*4 + r;
      const size_t tok = tokbase + row;
      #pragma unroll
      for (int it = 0; it < 4; ++it){
        const int col = 16*it + (lane&15);
        float g = (float)gf[tok*1024 + h*64 + col];
        float sg = g / (1.f + __expf(-g));
        float v = o_acc[it][r]*scale*rw[it]*sg;
        bf2 sp = split2(v);
        yh[tok*1024 + h*64 + col] = sp.h;
        yl[tok*1024 + h*64 + col] = sp.l;
      }
    }
  }
}

// ---------------------------------------------------------------- launcher
extern "C" void kernel_launch(void* const* d_in, const int* in_sizes, int n_in,
                              void* d_out, int out_size, void* d_ws, size_t ws_size,
                              hipStream_t stream){
  const float* x     = (const float*)d_in[0];
  const float* Wq    = (const float*)d_in[1];
  const float* Wk    = (const float*)d_in[2];
  const float* Wv    = (const float*)d_in[3];
  const float* Wa    = (const float*)d_in[4];
  const float* Wb    = (const float*)d_in[5];
  const float* A_log = (const float*)d_in[6];
  const float* dt_b  = (const float*)d_in[7];
  const float* Wgt   = (const float*)d_in[8];
  const float* Wo    = (const float*)d_in[9];
  const float* rms_w = (const float*)d_in[10];

  const bool BIG = ws_size >= (size_t)215000000;

  char* ws = (char*)d_ws;
  size_t off = 0;
  auto alloc = [&](size_t bytes)->char*{
    char* p = ws + off;
    off += (bytes + 255) & ~(size_t)255;
    return p;
  };
  const size_t PLANE = (size_t)8192*1024*2;   // bf16 activation plane (16 MiB)
  const size_t WPL   = (size_t)1024*1024*2;   // bf16 weight plane (2 MiB)
  bf16* xh  = (bf16*)alloc(PLANE);            // region also hosts Pg (A->B3), then yh
  bf16* xl  = (bf16*)alloc(PLANE);
  bf16* wqh = (bf16*)alloc(WPL); bf16* wql = (bf16*)alloc(WPL);   // wqh..wgl also hosts Bg
  bf16* wkh = (bf16*)alloc(WPL); bf16* wkl = (bf16*)alloc(WPL);
  bf16* wvh = (bf16*)alloc(WPL); bf16* wvl = (bf16*)alloc(WPL);
  bf16* wgh = (bf16*)alloc(WPL); bf16* wgl = (bf16*)alloc(WPL);
  bf16* woh = (bf16*)alloc(WPL); bf16* wol = (bf16*)alloc(WPL);
  bf16* WabTh = (bf16*)alloc((size_t)32*1024*2);
  bf16* WabTl = (bf16*)alloc((size_t)32*1024*2);
  // q/k as hi/lo bf16 split planes (same bytes as fp32 in BIG mode; hi-only in SMALL)
  bf16* qh = nullptr; bf16* ql = nullptr;
  bf16* kh = nullptr; bf16* kl = nullptr;
  if (BIG){
    qh = (bf16*)alloc(PLANE); ql = (bf16*)alloc(PLANE);
    kh = (bf16*)alloc(PLANE); kl = (bf16*)alloc(PLANE);
  } else {
    qh = (bf16*)alloc(PLANE);
    kh = (bf16*)alloc(PLANE);
  }
  float* vf  = (float*)alloc((size_t)8192*1024*4);  // dead after phase A -> hosts S0g
  bf16* gfb  = (bf16*)alloc(PLANE);
  float* logA  = (float*)alloc((size_t)8192*16*4);
  float* betap = (float*)alloc((size_t)8192*16*4);
  bf16* Wg  = (bf16*)alloc((size_t)2048*4096*2);
  bf16* Dg  = (bf16*)alloc((size_t)2048*4096*2);
  float* Pg  = (float*)xh;            // 33.5 MiB fp32 in xh+xl (dead between GEMMs and phase C)
  float* S0g = vf;                    // 33.5 MiB fp32 (vf dead after phase A)
  bf16* Bg   = wqh;                   // 16 MiB bf16 (projection weights dead)
  float* PsegT = (float*)d_out;       // 4 MiB scratch in d_out (overwritten by final GEMM)
  float* BsegF = (float*)d_out + 1048576;  // next 4 MiB
  bf16* yh = xh;                      // phase C outputs (Pg dead after B3)
  bf16* yl = xl;

  k_cvt_x<<<8192, 256, 0, stream>>>(x, xh, xl, 2097152);
  k_transpose_w<<<dim3(32,32), 256, 0, stream>>>(Wq,  wqh, wql);
  k_transpose_w<<<dim3(32,32), 256, 0, stream>>>(Wk,  wkh, wkl);
  k_transpose_w<<<dim3(32,32), 256, 0, stream>>>(Wv,  wvh, wvl);
  k_transpose_w<<<dim3(32,32), 256, 0, stream>>>(Wgt, wgh, wgl);
  k_transpose_w<<<dim3(32,32), 256, 0, stream>>>(Wo,  woh, wol);
  k_transpose_ab<<<128, 256, 0, stream>>>(Wa, Wb, WabTh, WabTl);

  k_gemm1<1><<<dim3(64,8), 256, 0, stream>>>(xh, wqh, qh, nullptr, ql);  // ql may be null (hi-only)
  k_gemm1<2><<<dim3(64,8), 256, 0, stream>>>(xh, wkh, kh, nullptr, kl);
  k_gemm1<0><<<dim3(64,8), 256, 0, stream>>>(xh, wvh, nullptr, vf, nullptr);
  k_gemm1<0><<<dim3(64,8), 256, 0, stream>>>(xh, wgh, gfb, nullptr, nullptr);

  k_ab_gemm<<<256, 256, 0, stream>>>(xh, xl, WabTh, WabTl, A_log, dt_b, logA, betap);

  k_phaseA<<<dim3(64,16,2), 128, 0, stream>>>(kh, kl, vf, logA, betap, Wg, Dg, Pg, Bg);
  k_phaseB1<<<dim3(8,32), 256, 0, stream>>>(Pg, Bg, PsegT, BsegF);
  k_phaseB2<<<32, 256, 0, stream>>>(PsegT, BsegF, S0g);
  k_phaseB3<<<dim3(8,32), 256, 0, stream>>>(Pg, Bg, S0g);
  k_phaseC<<<dim3(64,16,2), 256, 0, stream>>>(qh, ql, kh, kl, gfb, logA, S0g, Wg, Dg, rms_w, yh, yl);

  k_gemm3<<<dim3(64,8), 256, 0, stream>>>(yh, yl, woh, wol, nullptr, (float*)d_out);
}

// Round 6
// 507.361 us; speedup vs baseline: 1.5189x; 1.0114x over previous
//
#include <hip/hip_runtime.h>
#include <cstdint>
#include <cstddef>

typedef __bf16 bf16;
typedef __bf16 bf16x4 __attribute__((ext_vector_type(4)));
typedef __bf16 bf16x8 __attribute__((ext_vector_type(8)));
typedef float  f32x4  __attribute__((ext_vector_type(4)));

#define GLD_LDS16(gp, lp) \
  __builtin_amdgcn_global_load_lds((__attribute__((address_space(1))) void*)(gp), \
                                   (__attribute__((address_space(3))) void*)(lp), 16, 0, 0)

__device__ __forceinline__ f32x4 f32x4_zero(){ f32x4 v; v[0]=0.f; v[1]=0.f; v[2]=0.f; v[3]=0.f; return v; }

__device__ __forceinline__ f32x4 mfma16x16x32(bf16x8 a, bf16x8 b, f32x4 c){
  return __builtin_amdgcn_mfma_f32_16x16x32_bf16(a, b, c, 0, 0, 0);
}
// fragment of a 64-col bf16 LDS array (stride 64), LINEAR layout (phaseB kernels)
__device__ __forceinline__ bf16x8 frag64(const bf16* base, int row0, int kk, int lane){
  return *(const bf16x8*)&base[(row0 + (lane&15))*64 + kk*32 + (lane>>4)*8];
}
// fragment of a 64-col bf16 LDS array with XOR bank-swizzle: elem ^= (row&7)<<3
__device__ __forceinline__ bf16x8 fragSwz(const bf16* base, int row0, int kk, int lane){
  const int row = row0 + (lane&15);
  const int off = (kk*32 + (lane>>4)*8) ^ ((row&7)<<3);
  return *(const bf16x8*)&base[row*64 + off];
}
struct bf2 { bf16 h, l; };
__device__ __forceinline__ bf2 split2(float v){
  bf2 r; r.h = (bf16)v; r.l = (bf16)(v - (float)r.h); return r;
}

// ---------------------------------------------------------------- K0a: x -> hi/lo bf16 planes
__global__ __launch_bounds__(256) void k_cvt_x(const float* __restrict__ x,
                                               bf16* __restrict__ xh, bf16* __restrict__ xl, int n4){
  int i = blockIdx.x*256 + threadIdx.x;
  if (i < n4){
    float4 v = ((const float4*)x)[i];
    bf16x4 h, l;
    bf2 t0 = split2(v.x); h[0]=t0.h; l[0]=t0.l;
    bf2 t1 = split2(v.y); h[1]=t1.h; l[1]=t1.l;
    bf2 t2 = split2(v.z); h[2]=t2.h; l[2]=t2.l;
    bf2 t3 = split2(v.w); h[3]=t3.h; l[3]=t3.l;
    ((bf16x4*)xh)[i] = h;
    ((bf16x4*)xl)[i] = l;
  }
}

// ---------------------------------------------------------------- K0b: W[k][n] -> Wt hi/lo [n][k]
__global__ __launch_bounds__(256) void k_transpose_w(const float* __restrict__ W,
                                                     bf16* __restrict__ Wth, bf16* __restrict__ Wtl){
  __shared__ float tile[32][33];
  const int k0 = blockIdx.x*32, n0 = blockIdx.y*32;
  const int r = threadIdx.x >> 3, c4 = (threadIdx.x & 7)*4;
  float4 v = *(const float4*)&W[(size_t)(k0+r)*1024 + n0 + c4];
  tile[r][c4+0]=v.x; tile[r][c4+1]=v.y; tile[r][c4+2]=v.z; tile[r][c4+3]=v.w;
  __syncthreads();
  bf16x4 h, l;
  bf2 t0 = split2(tile[c4+0][r]); h[0]=t0.h; l[0]=t0.l;
  bf2 t1 = split2(tile[c4+1][r]); h[1]=t1.h; l[1]=t1.l;
  bf2 t2 = split2(tile[c4+2][r]); h[2]=t2.h; l[2]=t2.l;
  bf2 t3 = split2(tile[c4+3][r]); h[3]=t3.h; l[3]=t3.l;
  *(bf16x4*)&Wth[(size_t)(n0+r)*1024 + k0 + c4] = h;
  *(bf16x4*)&Wtl[(size_t)(n0+r)*1024 + k0 + c4] = l;
}

// ---------------------------------------------------------------- K0c: Walpha/Wbeta [1024][16] -> WabT hi/lo bf16 [32][1024]
__global__ __launch_bounds__(256) void k_transpose_ab(const float* __restrict__ Wa, const float* __restrict__ Wb,
                                                      bf16* __restrict__ WabTh, bf16* __restrict__ WabTl){
  int p = blockIdx.x*256 + threadIdx.x;
  if (p < 32768){
    int o = p >> 10, k = p & 1023;
    float v = (o < 16) ? Wa[k*16 + o] : Wb[k*16 + (o-16)];
    bf2 s = split2(v);
    WabTh[p] = s.h;
    WabTl[p] = s.l;
  }
}

// ---------------------------------------------------------------- K1: split-bf16 MFMA GEMM (3-product), K=1024
__global__ __launch_bounds__(256) void k_gemm3(const bf16* __restrict__ Ah, const bf16* __restrict__ Al,
                                               const bf16* __restrict__ Bth, const bf16* __restrict__ Btl,
                                               bf16* __restrict__ Cb, float* __restrict__ Cf){
  __shared__ bf16 Ash[128*32], Asl[128*32];
  __shared__ bf16 Bsh[128*32], Bsl[128*32];
  const int tid = threadIdx.x, lane = tid & 63, w = tid >> 6;
  const int wm = w >> 1, wn = w & 1;
  const size_t m0 = (size_t)blockIdx.x * 128;
  const size_t n0 = (size_t)blockIdx.y * 128;
  f32x4 acc[4][4];
  #pragma unroll
  for (int i=0;i<4;++i)
    #pragma unroll
    for (int j=0;j<4;++j) acc[i][j] = f32x4_zero();

  for (int k0 = 0; k0 < 1024; k0 += 32){
    __syncthreads();
    #pragma unroll
    for (int j = 0; j < 2; ++j){
      const int rbase = 32*w + 16*j;
      const int r = rbase + (lane >> 2);
      const int kk = k0 + (lane & 3)*8;
      GLD_LDS16(&Ah [(m0 + r)*1024 + kk], &Ash[rbase*32]);
      GLD_LDS16(&Al [(m0 + r)*1024 + kk], &Asl[rbase*32]);
      GLD_LDS16(&Bth[(n0 + r)*1024 + kk], &Bsh[rbase*32]);
      GLD_LDS16(&Btl[(n0 + r)*1024 + kk], &Bsl[rbase*32]);
    }
    __syncthreads();
    bf16x8 ah[4], al[4], bh[4], bl[4];
    #pragma unroll
    for (int t=0;t<4;++t){
      ah[t] = *(const bf16x8*)&Ash[(64*wm + 16*t + (lane&15))*32 + (lane>>4)*8];
      al[t] = *(const bf16x8*)&Asl[(64*wm + 16*t + (lane&15))*32 + (lane>>4)*8];
      bh[t] = *(const bf16x8*)&Bsh[(64*wn + 16*t + (lane&15))*32 + (lane>>4)*8];
      bl[t] = *(const bf16x8*)&Bsl[(64*wn + 16*t + (lane&15))*32 + (lane>>4)*8];
    }
    #pragma unroll
    for (int i=0;i<4;++i)
      #pragma unroll
      for (int j=0;j<4;++j){
        f32x4 t = acc[i][j];
        t = mfma16x16x32(ah[i], bh[j], t);
        t = mfma16x16x32(ah[i], bl[j], t);
        t = mfma16x16x32(al[i], bh[j], t);
        acc[i][j] = t;
      }
  }
  #pragma unroll
  for (int i=0;i<4;++i)
    #pragma unroll
    for (int j=0;j<4;++j)
      #pragma unroll
      for (int r=0;r<4;++r){
        size_t row = m0 + 64*wm + 16*i + (lane>>4)*4 + r;
        size_t col = n0 + 64*wn + 16*j + (lane&15);
        float v = acc[i][j][r];
        if (Cf) Cf[row*1024 + col] = v;
        else    Cb[row*1024 + col] = (bf16)v;
      }
}

// ---------------------------------------------------------------- K1b: single-bf16 MFMA GEMM, K=1024
// NRM: 0 = plain, 1 = fused q l2norm (0.125/||.||), 2 = fused k l2norm (1/||.||).
// Cl != nullptr -> write hi/lo bf16 split planes (Cb=hi, Cl=lo).
template<int NRM>
__global__ __launch_bounds__(256) void k_gemm1(const bf16* __restrict__ Ah, const bf16* __restrict__ Bth,
                                               bf16* __restrict__ Cb, float* __restrict__ Cf,
                                               bf16* __restrict__ Cl){
  __shared__ bf16 Ash[128*32];
  __shared__ bf16 Bsh[128*32];
  const int tid = threadIdx.x, lane = tid & 63, w = tid >> 6;
  const int wm = w >> 1, wn = w & 1;
  const size_t m0 = (size_t)blockIdx.x * 128;
  const size_t n0 = (size_t)blockIdx.y * 128;
  f32x4 acc[4][4];
  #pragma unroll
  for (int i=0;i<4;++i)
    #pragma unroll
    for (int j=0;j<4;++j) acc[i][j] = f32x4_zero();

  for (int k0 = 0; k0 < 1024; k0 += 32){
    __syncthreads();
    #pragma unroll
    for (int j = 0; j < 2; ++j){
      const int rbase = 32*w + 16*j;
      const int r = rbase + (lane >> 2);
      const int kk = k0 + (lane & 3)*8;
      GLD_LDS16(&Ah [(m0 + r)*1024 + kk], &Ash[rbase*32]);
      GLD_LDS16(&Bth[(n0 + r)*1024 + kk], &Bsh[rbase*32]);
    }
    __syncthreads();
    bf16x8 ah[4], bh[4];
    #pragma unroll
    for (int t=0;t<4;++t){
      ah[t] = *(const bf16x8*)&Ash[(64*wm + 16*t + (lane&15))*32 + (lane>>4)*8];
      bh[t] = *(const bf16x8*)&Bsh[(64*wn + 16*t + (lane&15))*32 + (lane>>4)*8];
    }
    #pragma unroll
    for (int i=0;i<4;++i)
      #pragma unroll
      for (int j=0;j<4;++j)
        acc[i][j] = mfma16x16x32(ah[i], bh[j], acc[i][j]);
  }
  #pragma unroll
  for (int i=0;i<4;++i)
    #pragma unroll
    for (int r=0;r<4;++r){
      float sc = 1.f;
      if (NRM){
        float ss = 0.f;
        #pragma unroll
        for (int j=0;j<4;++j) ss += acc[i][j][r]*acc[i][j][r];
        ss += __shfl_xor(ss, 1); ss += __shfl_xor(ss, 2);
        ss += __shfl_xor(ss, 4); ss += __shfl_xor(ss, 8);
        sc = (NRM==1 ? 0.125f : 1.0f) / fmaxf(sqrtf(ss), 1e-12f);
      }
      #pragma unroll
      for (int j=0;j<4;++j){
        size_t row = m0 + 64*wm + 16*i + (lane>>4)*4 + r;
        size_t col = n0 + 64*wn + 16*j + (lane&15);
        float v = acc[i][j][r]*sc;
        if (Cl){ bf2 sp = split2(v); Cb[row*1024 + col] = sp.h; Cl[row*1024 + col] = sp.l; }
        else if (Cf) Cf[row*1024 + col] = v;
        else         Cb[row*1024 + col] = (bf16)v;
      }
    }
}

// ---------------------------------------------------------------- K2: alpha/beta projections as split-bf16 MFMA GEMM
__global__ __launch_bounds__(256) void k_ab_gemm(const bf16* __restrict__ xh, const bf16* __restrict__ xl,
    const bf16* __restrict__ WabTh, const bf16* __restrict__ WabTl,
    const float* __restrict__ A_log, const float* __restrict__ dt_bias,
    float* __restrict__ logA, float* __restrict__ betap){
  __shared__ bf16 Ash[2][2048], Asl[2][2048];   // 32 rows x 64 k per buffer
  const int tid = threadIdx.x, lane = tid & 63, w = tid >> 6;
  const int mt = w >> 1, nt = w & 1;
  const size_t m0 = (size_t)blockIdx.x * 32;
  const int srow = tid >> 3;
  const int scol = 8*((tid & 7) ^ (srow & 7));
  const size_t sg = (m0 + srow)*1024 + scol;

  f32x4 acc = f32x4_zero();
  GLD_LDS16(&xh[sg], &Ash[0][w*512]);
  GLD_LDS16(&xl[sg], &Asl[0][w*512]);
  for (int s = 0; s < 16; ++s){
    const int cur = s & 1;
    __syncthreads();                    // implicit vmcnt(0): buf[cur] staged
    if (s + 1 < 16){
      const size_t g = sg + (size_t)(s+1)*64;
      GLD_LDS16(&xh[g], &Ash[cur^1][w*512]);
      GLD_LDS16(&xl[g], &Asl[cur^1][w*512]);
    }
    const int k0 = s*64;
    #pragma unroll
    for (int kk = 0; kk < 2; ++kk){
      bf16x8 aH = fragSwz(Ash[cur], 16*mt, kk, lane);
      bf16x8 aL = fragSwz(Asl[cur], 16*mt, kk, lane);
      const size_t bo = (size_t)(16*nt + (lane&15))*1024 + k0 + kk*32 + (lane>>4)*8;
      bf16x8 bH = *(const bf16x8*)&WabTh[bo];
      bf16x8 bL = *(const bf16x8*)&WabTl[bo];
      acc = mfma16x16x32(aH, bH, acc);
      acc = mfma16x16x32(aH, bL, acc);
      acc = mfma16x16x32(aL, bH, acc);
    }
  }
  const int col = lane & 15;
  #pragma unroll
  for (int r = 0; r < 4; ++r){
    const size_t row = m0 + 16*mt + (lane>>4)*4 + r;
    float v = acc[r];
    if (nt == 0){
      float z = v + dt_bias[col];
      float dt = (z > 20.f) ? z : log1pf(expf(z));
      logA[row*16 + col] = -expf(A_log[col]) * dt;   // log(alpha_t)
    } else {
      betap[row*16 + col] = 1.f/(1.f + expf(-v));    // beta_t
    }
  }
}

// ---------------------------------------------------------------- K3: phase A (2048 blocks, 128 thr)
// LDS 32768 -> 5 blocks/CU; (128,4) caps VGPR 128 (84 actual, no spill). K staged via GLD
// (pre-swizzled source). beta folded into E/RHS. Diag solve uses a 4-WAY ILP TREE: the serial
// s += E*d chain (~120 dep FMAs x 4cyc x 4 blocks) was the latency bottleneck (r5: VALUBusy 41%,
// 59% stall); 4 partial sums cut the chain ~4x. P output stored as SPLIT bf16 planes (PgH/PgL) --
// numerically identical to downstream's fp32->split, halves P write traffic.
__global__ __launch_bounds__(128, 4) void k_phaseA(const bf16* __restrict__ khp, const bf16* __restrict__ klp,
    const float* __restrict__ vf, const float* __restrict__ logA, const float* __restrict__ betap,
    bf16* __restrict__ Wg, bf16* __restrict__ Dg,
    bf16* __restrict__ PgH, bf16* __restrict__ PgL, bf16* __restrict__ Bg){
  __shared__ bf16  Kh[4096], Kl_[4096];   // 8 KiB + 8 KiB
  __shared__ float Ef[4096];              // 16 KiB; row 0 = lg cumsum
  bf16* DT  = Kh;                         // overlay: Dsol^T (after KtT build)
  bf16* WT  = Kl_;                        // overlay: Wsol^T
  bf16* KtT = (bf16*)&Ef[2048];           // overlay: K_til^T (Ef rows 32..63, after solve)
  const int tid = threadIdx.x, lane = tid & 63, wid = tid >> 6;
  const int c = blockIdx.x, h = blockIdx.y, b = blockIdx.z;
  const size_t tokbase = (size_t)b*4096 + (size_t)c*64;
  const size_t cbase = ((size_t)((b*16 + h)*64 + c)) * 4096;

  { // async stage K tile (hi/lo) with pre-swizzled source
    const int chunk = tid & 7, r0 = tid >> 3;       // r0: wave0 0..7, wave1 8..15
    #pragma unroll
    for (int rr = 0; rr < 4; ++rr){
      const int row = 16*rr + r0;
      const size_t g = (tokbase + row)*1024 + (size_t)h*64 + 8*(chunk ^ (row & 7));
      GLD_LDS16(&khp[g], &Kh[(16*rr + 8*wid)*64]);
      if (klp) GLD_LDS16(&klp[g], &Kl_[(16*rr + 8*wid)*64]);
    }
    if (!klp){
      uint4 z4; z4.x=0; z4.y=0; z4.z=0; z4.w=0;
      for (int z = tid; z < 512; z += 128) ((uint4*)Kl_)[z] = z4;
    }
  }
  const float bet = betap[(tokbase + lane)*16 + h];   // per-lane beta_t, t = lane
  if (tid < 64){
    float la = logA[(tokbase + tid)*16 + h];
    #pragma unroll
    for (int dlt = 1; dlt < 64; dlt <<= 1){
      float o = __shfl_up(la, dlt);
      if (lane >= dlt) la += o;
    }
    Ef[tid] = la;                // lg cumsum in E row 0 (row 0 never read by solve)
  }
  __syncthreads();               // GLD staged + lg ready

  // E~[t][tau] = beta_t * (gamma_t/gamma_tau)*(k_t . k_tau), strictly lower; else 0
  #pragma unroll
  for (int tt = 0; tt < 2; ++tt){
    const int t0 = 32*wid + 16*tt;
    #pragma unroll
    for (int tu = 0; tu < 4; ++tu){
      f32x4 accm = f32x4_zero();
      #pragma unroll
      for (int kk = 0; kk < 2; ++kk){
        bf16x8 aH = fragSwz(Kh,  t0,    kk, lane);
        bf16x8 aL = fragSwz(Kl_, t0,    kk, lane);
        bf16x8 bH = fragSwz(Kh,  16*tu, kk, lane);
        bf16x8 bL = fragSwz(Kl_, 16*tu, kk, lane);
        accm = mfma16x16x32(aH, bH, accm);
        accm = mfma16x16x32(aH, bL, accm);
        accm = mfma16x16x32(aL, bH, accm);
      }
      #pragma unroll
      for (int r = 0; r < 4; ++r){
        int row = t0 + (lane>>4)*4 + r, col = 16*tu + (lane&15);
        float bR = __shfl(bet, row);   // beta folded into E row
        float ev = (col < row) ? accm[r]*__expf(Ef[row] - Ef[col])*bR : 0.f;
        if (row > 0) Ef[row*64 + col] = ev;   // row 0 never read; keeps lg intact
      }
    }
  }
  __syncthreads();   // E complete (both waves) before solve reads

  // right-looking blocked forward substitution, beta pre-folded, 4-way ILP tree in diag
  float d[64];
  {
    if (wid == 0){
      #pragma unroll
      for (int t = 0; t < 64; ++t)
        d[t] = __shfl(bet, t) * vf[(tokbase + t)*1024 + h*64 + lane];
    } else {
      #pragma unroll
      for (int t = 0; t < 64; ++t){
        int ks = lane ^ ((t&7)<<3);
        d[t] = __shfl(bet, t) * __expf(Ef[t]) * ((float)Kh[t*64 + ks] + (float)Kl_[t*64 + ks]);
      }
    }
    #pragma unroll
    for (int bi = 0; bi < 4; ++bi){
      // diagonal 16x16 unit-lower solve: 4 independent partial sums (chain ~tt/4 not tt)
      #pragma unroll
      for (int tt = 0; tt < 16; ++tt){
        const int t = 16*bi + tt;
        float p0=0.f, p1=0.f, p2=0.f, p3=0.f;
        #pragma unroll
        for (int j = 0; j < 16; ++j){
          if (j < tt){
            float e = Ef[t*64 + 16*bi + j];
            float dj = d[16*bi + j];
            if      ((j&3)==0) p0 += e*dj;
            else if ((j&3)==1) p1 += e*dj;
            else if ((j&3)==2) p2 += e*dj;
            else               p3 += e*dj;
          }
        }
        d[t] = d[t] - ((p0+p1)+(p2+p3));
      }
      // trailing rank-16 update of all later blocks (independent per t)
      #pragma unroll
      for (int b2 = bi + 1; b2 < 4; ++b2)
        #pragma unroll
        for (int tt = 0; tt < 16; ++tt){
          const int t = 16*b2 + tt;
          float a0=0.f,a1=0.f,a2=0.f,a3=0.f;
          #pragma unroll
          for (int q = 0; q < 4; ++q){
            float4 e = *(const float4*)&Ef[t*64 + 16*bi + q*4];
            a0 += e.x * d[16*bi + q*4 + 0];
            a1 += e.y * d[16*bi + q*4 + 1];
            a2 += e.z * d[16*bi + q*4 + 2];
            a3 += e.w * d[16*bi + q*4 + 3];
          }
          d[t] -= (a0+a1)+(a2+a3);
        }
    }
  }
  __syncthreads();   // all Ef/Kh/Kl solve reads done

  // K_til^T[j][t] = (gamma_L/gamma_t) * k[t][j]  (built AFTER solve, into Ef rows 32..63)
  {
    const float gsc = __expf(Ef[63] - Ef[lane]);   // t == lane for the stride-128 loop
    for (int i = tid; i < 4096; i += 128){
      int t = lane, j = i >> 6;
      int ks = j ^ ((t&7)<<3);
      float kv = (float)Kh[t*64 + ks] + (float)Kl_[t*64 + ks];
      KtT[j*64 + (t ^ ((j&7)<<3))] = (bf16)(gsc * kv);
    }
  }
  __syncthreads();   // KtT built; Kh/Kl_ now dead -> DT/WT overlay safe

  const float gL = __expf(Ef[63]);   // Ef row 0 intact (KtT occupies rows 32..63 only)
  {
    bf16* myT = wid ? WT : DT;
    #pragma unroll
    for (int s4 = 0; s4 < 16; ++s4){
      bf16x4 v4;
      v4[0]=(bf16)d[s4*4+0]; v4[1]=(bf16)d[s4*4+1];
      v4[2]=(bf16)d[s4*4+2]; v4[3]=(bf16)d[s4*4+3];
      *(bf16x4*)&myT[lane*64 + ((s4*4) ^ ((lane&7)<<3))] = v4;
    }
    bf16* myG = wid ? Wg : Dg;
    #pragma unroll
    for (int t = 0; t < 64; ++t)
      myG[cbase + (size_t)t*64 + lane] = (bf16)d[t];
  }
  __syncthreads();

  // P^T[j][i] = gamma_L*I - sum_t K_til[t][j]*Wsol[t][i]  (wave0, MFMA, SPLIT bf16 out)
  // B[i][j]   =              sum_t Dsol[t][i]*K_til[t][j]  (wave1, MFMA, bf16 out)
  if (wid == 0){
    #pragma unroll
    for (int tj = 0; tj < 4; ++tj)
      #pragma unroll
      for (int ti = 0; ti < 4; ++ti){
        f32x4 acc = f32x4_zero();
        #pragma unroll
        for (int kk = 0; kk < 2; ++kk)
          acc = mfma16x16x32(fragSwz(KtT, 16*tj, kk, lane), fragSwz(WT, 16*ti, kk, lane), acc);
        #pragma unroll
        for (int r = 0; r < 4; ++r){
          int row = 16*tj + (lane>>4)*4 + r, col = 16*ti + (lane&15);
          float v = ((row == col) ? gL : 0.f) - acc[r];
          bf2 sp = split2(v);
          PgH[cbase + (size_t)row*64 + col] = sp.h;
          PgL[cbase + (size_t)row*64 + col] = sp.l;
        }
      }
  } else {
    #pragma unroll
    for (int ti = 0; ti < 4; ++ti)
      #pragma unroll
      for (int tj = 0; tj < 4; ++tj){
        f32x4 acc = f32x4_zero();
        #pragma unroll
        for (int kk = 0; kk < 2; ++kk)
          acc = mfma16x16x32(fragSwz(DT, 16*ti, kk, lane), fragSwz(KtT, 16*tj, kk, lane), acc);
        #pragma unroll
        for (int r = 0; r < 4; ++r){
          int row = 16*ti + (lane>>4)*4 + r, col = 16*tj + (lane&15);
          Bg[cbase + (size_t)row*64 + col] = (bf16)acc[r];
        }
      }
  }
}

// ---------------------------------------------------------------- K4a: segment composition (256 blocks: 8 seg x 32 chains)
// P now arrives as split bf16 planes -> plain uint4 copies (no fp32 load + split2 per step)
__global__ __launch_bounds__(256) void k_phaseB1(const bf16* __restrict__ PgH, const bf16* __restrict__ PgL,
                                                 const bf16* __restrict__ Bg,
                                                 float* __restrict__ PsegT, float* __restrict__ BsegF){
  __shared__ bf16 PaccH[4096], PaccL[4096], BaccH[4096], BaccL[4096];
  __shared__ bf16 PcH[4096], PcL[4096];
  __shared__ bf16 BcS[4096];
  const int tid = threadIdx.x, lane = tid & 63, w = tid >> 6;
  const int seg = blockIdx.x;
  const size_t chain = blockIdx.y;
  f32x4 Pr[4], Br[4];
  #pragma unroll
  for (int it = 0; it < 4; ++it){
    #pragma unroll
    for (int r = 0; r < 4; ++r){
      int row = 16*w + (lane>>4)*4 + r, col = 16*it + (lane&15);
      Pr[it][r] = (row == col) ? 1.f : 0.f;   // Pacc = I
      Br[it][r] = 0.f;                        // Bacc = 0
    }
  }
  for (int i = 0; i < 8; ++i){
    const size_t cb = (chain*64 + (size_t)seg*8 + i)*4096;
    #pragma unroll
    for (int it = 0; it < 4; ++it)
      #pragma unroll
      for (int r = 0; r < 4; ++r){
        int row = 16*w + (lane>>4)*4 + r, col = 16*it + (lane&15);
        bf2 sp = split2(Pr[it][r]); PaccH[row*64+col] = sp.h; PaccL[row*64+col] = sp.l;
        bf2 sb = split2(Br[it][r]); BaccH[row*64+col] = sb.h; BaccL[row*64+col] = sb.l;
      }
    __syncthreads();   // prev iter's MFMA done -> safe to overwrite PcH/L
    for (int j = tid; j < 512; j += 256){
      ((uint4*)PcH)[j] = ((const uint4*)(PgH + cb))[j];
      ((uint4*)PcL)[j] = ((const uint4*)(PgL + cb))[j];
      ((uint4*)BcS)[j] = ((const uint4*)(Bg  + cb))[j];
    }
    __syncthreads();
    f32x4 nP[4], nB[4];
    #pragma unroll
    for (int it = 0; it < 4; ++it){ nP[it] = f32x4_zero(); nB[it] = f32x4_zero(); }
    #pragma unroll
    for (int kk = 0; kk < 2; ++kk){
      bf16x8 aPH = frag64(PaccH, 16*w, kk, lane), aPL = frag64(PaccL, 16*w, kk, lane);
      bf16x8 aBH = frag64(BaccH, 16*w, kk, lane), aBL = frag64(BaccL, 16*w, kk, lane);
      #pragma unroll
      for (int it = 0; it < 4; ++it){
        bf16x8 bH = frag64(PcH, 16*it, kk, lane), bL = frag64(PcL, 16*it, kk, lane);
        nP[it] = mfma16x16x32(aPH, bH, nP[it]);
        nP[it] = mfma16x16x32(aPH, bL, nP[it]);
        nP[it] = mfma16x16x32(aPL, bH, nP[it]);
        nB[it] = mfma16x16x32(aBH, bH, nB[it]);
        nB[it] = mfma16x16x32(aBH, bL, nB[it]);
        nB[it] = mfma16x16x32(aBL, bH, nB[it]);
      }
    }
    #pragma unroll
    for (int it = 0; it < 4; ++it)
      #pragma unroll
      for (int r = 0; r < 4; ++r){
        int row = 16*w + (lane>>4)*4 + r, col = 16*it + (lane&15);
        Pr[it][r] = nP[it][r];
        Br[it][r] = nB[it][r] + (float)BcS[row*64 + col];
      }
  }
  const size_t sb = (chain*8 + seg)*4096;
  #pragma unroll
  for (int it = 0; it < 4; ++it)
    #pragma unroll
    for (int r = 0; r < 4; ++r){
      int row = 16*w + (lane>>4)*4 + r, col = 16*it + (lane&15);
      PsegT[sb + (size_t)col*64 + row] = Pr[it][r];   // transposed (B-operand layout)
      BsegF[sb + (size_t)row*64 + col] = Br[it][r];   // natural
    }
}

// ---------------------------------------------------------------- K4b: segment-level scan (32 blocks, 8 steps)
__global__ __launch_bounds__(256) void k_phaseB2(const float* __restrict__ PsegT, const float* __restrict__ BsegF,
                                                 float* __restrict__ S0g){
  __shared__ bf16 Sh[4096], Sl[4096], Ph[4096], Pl[4096];
  __shared__ float Bf[4096];
  const int tid = threadIdx.x, lane = tid & 63, w = tid >> 6;
  const size_t bid = blockIdx.x;
  f32x4 Sr[4];
  #pragma unroll
  for (int it = 0; it < 4; ++it) Sr[it] = f32x4_zero();
  for (int seg = 0; seg < 8; ++seg){
    const size_t sb  = (bid*8 + seg)*4096;
    const size_t s0b = (bid*64 + (size_t)seg*8)*4096;
    #pragma unroll
    for (int it = 0; it < 4; ++it)
      #pragma unroll
      for (int r = 0; r < 4; ++r){
        int row = 16*w + (lane>>4)*4 + r, col = 16*it + (lane&15);
        S0g[s0b + (size_t)row*64 + col] = Sr[it][r];
        bf2 sp = split2(Sr[it][r]); Sh[row*64+col] = sp.h; Sl[row*64+col] = sp.l;
      }
    __syncthreads();
    for (int j = tid; j < 1024; j += 256){
      float4 pv = ((const float4*)(PsegT + sb))[j];
      bf16x4 ph, pl;
      bf2 u0 = split2(pv.x); ph[0]=u0.h; pl[0]=u0.l;
      bf2 u1 = split2(pv.y); ph[1]=u1.h; pl[1]=u1.l;
      bf2 u2 = split2(pv.z); ph[2]=u2.h; pl[2]=u2.l;
      bf2 u3 = split2(pv.w); ph[3]=u3.h; pl[3]=u3.l;
      ((bf16x4*)Ph)[j] = ph; ((bf16x4*)Pl)[j] = pl;
      ((float4*)Bf)[j] = ((const float4*)(BsegF + sb))[j];
    }
    __syncthreads();
    f32x4 nS[4];
    #pragma unroll
    for (int it = 0; it < 4; ++it) nS[it] = f32x4_zero();
    #pragma unroll
    for (int kk = 0; kk < 2; ++kk){
      bf16x8 aH = frag64(Sh, 16*w, kk, lane), aL = frag64(Sl, 16*w, kk, lane);
      #pragma unroll
      for (int it = 0; it < 4; ++it){
        bf16x8 bH = frag64(Ph, 16*it, kk, lane), bL = frag64(Pl, 16*it, kk, lane);
        nS[it] = mfma16x16x32(aH, bH, nS[it]);
        nS[it] = mfma16x16x32(aH, bL, nS[it]);
        nS[it] = mfma16x16x32(aL, bH, nS[it]);
      }
    }
    #pragma unroll
    for (int it = 0; it < 4; ++it)
      #pragma unroll
      for (int r = 0; r < 4; ++r){
        int row = 16*w + (lane>>4)*4 + r, col = 16*it + (lane&15);
        Sr[it][r] = nS[it][r] + Bf[row*64 + col];
      }
  }
}

// ---------------------------------------------------------------- K4c: within-segment replay (256 blocks, 7 steps)
__global__ __launch_bounds__(256) void k_phaseB3(const bf16* __restrict__ PgH, const bf16* __restrict__ PgL,
                                                 const bf16* __restrict__ Bg,
                                                 float* __restrict__ S0g){
  __shared__ bf16 Sh[4096], Sl[4096], Ph[4096], Pl[4096];
  __shared__ bf16 BcS[4096];
  const int tid = threadIdx.x, lane = tid & 63, w = tid >> 6;
  const int seg = blockIdx.x;
  const size_t chain = blockIdx.y;
  const size_t segbase = chain*64 + (size_t)seg*8;
  f32x4 Sr[4];
  #pragma unroll
  for (int it = 0; it < 4; ++it)
    #pragma unroll
    for (int r = 0; r < 4; ++r){
      int row = 16*w + (lane>>4)*4 + r, col = 16*it + (lane&15);
      Sr[it][r] = S0g[segbase*4096 + (size_t)row*64 + col];
    }
  for (int i = 0; i < 7; ++i){
    const size_t cb = (segbase + i)*4096;
    #pragma unroll
    for (int it = 0; it < 4; ++it)
      #pragma unroll
      for (int r = 0; r < 4; ++r){
        int row = 16*w + (lane>>4)*4 + r, col = 16*it + (lane&15);
        bf2 sp = split2(Sr[it][r]); Sh[row*64+col] = sp.h; Sl[row*64+col] = sp.l;
      }
    __syncthreads();
    for (int j = tid; j < 512; j += 256){
      ((uint4*)Ph)[j]  = ((const uint4*)(PgH + cb))[j];
      ((uint4*)Pl)[j]  = ((const uint4*)(PgL + cb))[j];
      ((uint4*)BcS)[j] = ((const uint4*)(Bg  + cb))[j];
    }
    __syncthreads();
    f32x4 nS[4];
    #pragma unroll
    for (int it = 0; it < 4; ++it) nS[it] = f32x4_zero();
    #pragma unroll
    for (int kk = 0; kk < 2; ++kk){
      bf16x8 aH = frag64(Sh, 16*w, kk, lane), aL = frag64(Sl, 16*w, kk, lane);
      #pragma unroll
      for (int it = 0; it < 4; ++it){
        bf16x8 bH = frag64(Ph, 16*it, kk, lane), bL = frag64(Pl, 16*it, kk, lane);
        nS[it] = mfma16x16x32(aH, bH, nS[it]);
        nS[it] = mfma16x16x32(aH, bL, nS[it]);
        nS[it] = mfma16x16x32(aL, bH, nS[it]);
      }
    }
    const size_t outb = (segbase + i + 1)*4096;
    #pragma unroll
    for (int it = 0; it < 4; ++it)
      #pragma unroll
      for (int r = 0; r < 4; ++r){
        int row = 16*w + (lane>>4)*4 + r, col = 16*it + (lane&15);
        float v = nS[it][r] + (float)BcS[row*64 + col];
        Sr[it][r] = v;
        S0g[outb + (size_t)row*64 + col] = v;
      }
  }
}

// ---------------------------------------------------------------- K5: phase C, outputs + fused RMSNorm/gate (2048 blocks)
__global__ __launch_bounds__(256, 2) void k_phaseC(
    const bf16* __restrict__ qhp, const bf16* __restrict__ qlp,
    const bf16* __restrict__ khp, const bf16* __restrict__ klp,
    const bf16* __restrict__ gf, const float* __restrict__ logA,
    const float* __restrict__ S0g, const bf16* __restrict__ Wg, const bf16* __restrict__ Dg,
    const float* __restrict__ rms_w, bf16* __restrict__ yh, bf16* __restrict__ yl){
  __shared__ bf16 Qh[4096], Ql[4096], Kh[4096], Klo[4096];
  __shared__ bf16 Wl_[4096], Dl_[4096];
  __shared__ bf16 S0h[4096], S0l[4096];
  __shared__ bf16 AAg[4096];
  __shared__ bf16 BDt[4096];
  const int tid = threadIdx.x, lane = tid & 63, w = tid >> 6;
  const int c = blockIdx.x, h = blockIdx.y, b = blockIdx.z;
  const size_t tokbase = (size_t)b*4096 + (size_t)c*64;
  const size_t cbase = ((size_t)((b*16 + h)*64 + c)) * 4096;

  { // async stage Q/K (hi/lo) + Wg/Dg with pre-swizzled source
    const int chunk = tid & 7, r0 = tid >> 3;   // r0 0..31; wave w rows 8w..8w+7 per round
    #pragma unroll
    for (int rr = 0; rr < 2; ++rr){
      const int row = 32*rr + r0;
      const int dbase = (32*rr + 8*w)*64;
      const size_t g = (tokbase + row)*1024 + (size_t)h*64 + 8*(chunk ^ (row & 7));
      GLD_LDS16(&qhp[g], &Qh[dbase]);
      if (qlp) GLD_LDS16(&qlp[g], &Ql[dbase]);
      GLD_LDS16(&khp[g], &Kh[dbase]);
      if (klp) GLD_LDS16(&klp[g], &Klo[dbase]);
      const size_t gg = cbase + (size_t)row*64 + 8*(chunk ^ (row & 7));
      GLD_LDS16(&Wg[gg], &Wl_[dbase]);
      GLD_LDS16(&Dg[gg], &Dl_[dbase]);
    }
    if (!qlp){
      uint4 z4; z4.x=0; z4.y=0; z4.z=0; z4.w=0;
      for (int z = tid; z < 512; z += 256){ ((uint4*)Ql)[z] = z4; ((uint4*)Klo)[z] = z4; }
    }
  }
  for (int i = tid; i < 1024; i += 256){
    float4 v = ((const float4*)(S0g + cbase))[i];
    bf16x4 sh, sl;
    bf2 t0 = split2(v.x); sh[0]=t0.h; sl[0]=t0.l;
    bf2 t1 = split2(v.y); sh[1]=t1.h; sl[1]=t1.l;
    bf2 t2 = split2(v.z); sh[2]=t2.h; sl[2]=t2.l;
    bf2 t3 = split2(v.w); sh[3]=t3.h; sl[3]=t3.l;
    int t = i >> 4, off = ((i&15)*4) ^ ((t&7)<<3);
    *(bf16x4*)&S0h[t*64 + off] = sh;
    *(bf16x4*)&S0l[t*64 + off] = sl;
  }
  // per-wave redundant lg cumsum
  float la = logA[(tokbase + lane)*16 + h];
  #pragma unroll
  for (int dlt = 1; dlt < 64; dlt <<= 1){
    float o = __shfl_up(la, dlt);
    if (lane >= dlt) la += o;
  }
  __syncthreads();

  { // AAg = mask_incl(Gamma .* QK^T), 3-product
    const int t0 = 16*w;
    #pragma unroll
    for (int tu = 0; tu < 4; ++tu){
      f32x4 accm = f32x4_zero();
      #pragma unroll
      for (int kk = 0; kk < 2; ++kk){
        bf16x8 aH = fragSwz(Qh,  t0,    kk, lane);
        bf16x8 aL = fragSwz(Ql,  t0,    kk, lane);
        bf16x8 bH = fragSwz(Kh,  16*tu, kk, lane);
        bf16x8 bL = fragSwz(Klo, 16*tu, kk, lane);
        accm = mfma16x16x32(aH, bH, accm);
        accm = mfma16x16x32(aH, bL, accm);
        accm = mfma16x16x32(aL, bH, accm);
      }
      #pragma unroll
      for (int r = 0; r < 4; ++r){
        int row = t0 + (lane>>4)*4 + r, col = 16*tu + (lane&15);
        float lgr = __shfl(la, row), lgc = __shfl(la, col);
        float v = (col <= row) ? accm[r]*__expf(lgr - lgc) : 0.f;
        AAg[row*64 + (col ^ ((row&7)<<3))] = (bf16)v;
      }
    }
  }
  { // BDt[i][tau] = Dloc[tau][i] - (S0 W_hat^T)[i][tau]
    const int i0 = 16*w;
    #pragma unroll
    for (int tu = 0; tu < 4; ++tu){
      f32x4 accm = f32x4_zero();
      #pragma unroll
      for (int kk = 0; kk < 2; ++kk){
        bf16x8 aH = fragSwz(S0h, i0,    kk, lane);
        bf16x8 aL = fragSwz(S0l, i0,    kk, lane);
        bf16x8 bb = fragSwz(Wl_, 16*tu, kk, lane);
        accm = mfma16x16x32(aH, bb, accm);
        accm = mfma16x16x32(aL, bb, accm);
      }
      #pragma unroll
      for (int r = 0; r < 4; ++r){
        int row = i0 + (lane>>4)*4 + r, col = 16*tu + (lane&15);
        float v = (float)Dl_[col*64 + (row ^ ((col&7)<<3))] - accm[r];
        BDt[row*64 + (col ^ ((row&7)<<3))] = (bf16)v;
      }
    }
  }
  __syncthreads();
  for (int i = tid; i < 4096; i += 256){
    int t = i >> 6;                              // uniform per wave per iteration
    float gq = __expf(__shfl(la, t));
    float v = gq * ((float)Qh[i] + (float)Ql[i]);  // swizzle is within-row: row scale layout-agnostic
    bf2 sp = split2(v);
    Qh[i] = sp.h; Ql[i] = sp.l;
  }
  __syncthreads();
  {
    const int t0 = 16*w;
    f32x4 o_acc[4];
    #pragma unroll
    for (int it = 0; it < 4; ++it) o_acc[it] = f32x4_zero();
    #pragma unroll
    for (int kk = 0; kk < 2; ++kk){
      bf16x8 aQh = fragSwz(Qh, t0, kk, lane);
      bf16x8 aQl = fragSwz(Ql, t0, kk, lane);
      bf16x8 aA  = fragSwz(AAg, t0, kk, lane);
      #pragma unroll
      for (int it = 0; it < 4; ++it){
        bf16x8 bSh = fragSwz(S0h, 16*it, kk, lane);
        bf16x8 bSl = fragSwz(S0l, 16*it, kk, lane);
        bf16x8 bD  = fragSwz(BDt, 16*it, kk, lane);
        f32x4 t = o_acc[it];
        t = mfma16x16x32(aQh, bSh, t);
        t = mfma16x16x32(aQh, bSl, t);
        t = mfma16x16x32(aQl, bSh, t);
        t = mfma16x16x32(aA,  bD,  t);
        o_acc[it] = t;
      }
    }
    float rw[4];
    #pragma unroll
    for (int it = 0; it < 4; ++it) rw[it] = rms_w[16*it + (lane&15)];
    #pragma unroll
    for (int r = 0; r < 4; ++r){
      float ss = 0.f;
      #pragma unroll
      for (int it = 0; it < 4; ++it) ss += o_acc[it][r]*o_acc[it][r];
      ss += __shfl_xor(ss, 1); ss += __shfl_xor(ss, 2);
      ss += __shfl_xor(ss, 4); ss += __shfl_xor(ss, 8);
      const float scale = rsqrtf(ss*(1.f/64.f) + 1e-6f);
      const int row = t0 + (lane>>4)*4 + r;
      const size_t tok = tokbase + row;
      #pragma unroll
      for (int it = 0; it < 4; ++it){
        const int col = 16*it + (lane&15);
        float g = (float)gf[tok*1024 + h*64 + col];
        float sg = g / (1.f + __expf(-g));
        float v = o_acc[it][r]*scale*rw[it]*sg;
        bf2 sp = split2(v);
        yh[tok*1024 + h*64 + col] = sp.h;
        yl[tok*1024 + h*64 + col] = sp.l;
      }
    }
  }
}

// ---------------------------------------------------------------- launcher
extern "C" void kernel_launch(void* const* d_in, const int* in_sizes, int n_in,
                              void* d_out, int out_size, void* d_ws, size_t ws_size,
                              hipStream_t stream){
  const float* x     = (const float*)d_in[0];
  const float* Wq    = (const float*)d_in[1];
  const float* Wk    = (const float*)d_in[2];
  const float* Wv    = (const float*)d_in[3];
  const float* Wa    = (const float*)d_in[4];
  const float* Wb    = (const float*)d_in[5];
  const float* A_log = (const float*)d_in[6];
  const float* dt_b  = (const float*)d_in[7];
  const float* Wgt   = (const float*)d_in[8];
  const float* Wo    = (const float*)d_in[9];
  const float* rms_w = (const float*)d_in[10];

  const bool BIG = ws_size >= (size_t)215000000;

  char* ws = (char*)d_ws;
  size_t off = 0;
  auto alloc = [&](size_t bytes)->char*{
    char* p = ws + off;
    off += (bytes + 255) & ~(size_t)255;
    return p;
  };
  const size_t PLANE = (size_t)8192*1024*2;   // bf16 activation plane (16 MiB)
  const size_t WPL   = (size_t)1024*1024*2;   // bf16 weight plane (2 MiB)
  bf16* xh  = (bf16*)alloc(PLANE);            // region also hosts PgH (A->B3), then yh
  bf16* xl  = (bf16*)alloc(PLANE);            // region also hosts PgL (A->B3), then yl
  bf16* wqh = (bf16*)alloc(WPL); bf16* wql = (bf16*)alloc(WPL);   // wqh..wgl also hosts Bg
  bf16* wkh = (bf16*)alloc(WPL); bf16* wkl = (bf16*)alloc(WPL);
  bf16* wvh = (bf16*)alloc(WPL); bf16* wvl = (bf16*)alloc(WPL);
  bf16* wgh = (bf16*)alloc(WPL); bf16* wgl = (bf16*)alloc(WPL);
  bf16* woh = (bf16*)alloc(WPL); bf16* wol = (bf16*)alloc(WPL);
  bf16* WabTh = (bf16*)alloc((size_t)32*1024*2);
  bf16* WabTl = (bf16*)alloc((size_t)32*1024*2);
  // q/k as hi/lo bf16 split planes (hi-only in SMALL)
  bf16* qh = nullptr; bf16* ql = nullptr;
  bf16* kh = nullptr; bf16* kl = nullptr;
  if (BIG){
    qh = (bf16*)alloc(PLANE); ql = (bf16*)alloc(PLANE);
    kh = (bf16*)alloc(PLANE); kl = (bf16*)alloc(PLANE);
  } else {
    qh = (bf16*)alloc(PLANE);
    kh = (bf16*)alloc(PLANE);
  }
  float* vf  = (float*)alloc((size_t)8192*1024*4);  // dead after phase A -> hosts S0g
  bf16* gfb  = (bf16*)alloc(PLANE);
  float* logA  = (float*)alloc((size_t)8192*16*4);
  float* betap = (float*)alloc((size_t)8192*16*4);
  bf16* Wg  = (bf16*)alloc((size_t)2048*4096*2);
  bf16* Dg  = (bf16*)alloc((size_t)2048*4096*2);
  bf16* PgH = xh;                     // P hi plane (xh dead after GEMMs)
  bf16* PgL = xl;                     // P lo plane
  float* S0g = vf;                    // 33.5 MiB fp32 (vf dead after phase A)
  bf16* Bg   = wqh;                   // 16 MiB bf16 (projection weights dead)
  float* PsegT = (float*)d_out;       // 4 MiB scratch in d_out (overwritten by final GEMM)
  float* BsegF = (float*)d_out + 1048576;  // next 4 MiB
  bf16* yh = xh;                      // phase C outputs (PgH/PgL dead after B3)
  bf16* yl = xl;

  k_cvt_x<<<8192, 256, 0, stream>>>(x, xh, xl, 2097152);
  k_transpose_w<<<dim3(32,32), 256, 0, stream>>>(Wq,  wqh, wql);
  k_transpose_w<<<dim3(32,32), 256, 0, stream>>>(Wk,  wkh, wkl);
  k_transpose_w<<<dim3(32,32), 256, 0, stream>>>(Wv,  wvh, wvl);
  k_transpose_w<<<dim3(32,32), 256, 0, stream>>>(Wgt, wgh, wgl);
  k_transpose_w<<<dim3(32,32), 256, 0, stream>>>(Wo,  woh, wol);
  k_transpose_ab<<<128, 256, 0, stream>>>(Wa, Wb, WabTh, WabTl);

  k_gemm1<1><<<dim3(64,8), 256, 0, stream>>>(xh, wqh, qh, nullptr, ql);  // ql may be null (hi-only)
  k_gemm1<2><<<dim3(64,8), 256, 0, stream>>>(xh, wkh, kh, nullptr, kl);
  k_gemm1<0><<<dim3(64,8), 256, 0, stream>>>(xh, wvh, nullptr, vf, nullptr);
  k_gemm1<0><<<dim3(64,8), 256, 0, stream>>>(xh, wgh, gfb, nullptr, nullptr);

  k_ab_gemm<<<256, 256, 0, stream>>>(xh, xl, WabTh, WabTl, A_log, dt_b, logA, betap);

  k_phaseA<<<dim3(64,16,2), 128, 0, stream>>>(kh, kl, vf, logA, betap, Wg, Dg, PgH, PgL, Bg);
  k_phaseB1<<<dim3(8,32), 256, 0, stream>>>(PgH, PgL, Bg, PsegT, BsegF);
  k_phaseB2<<<32, 256, 0, stream>>>(PsegT, BsegF, S0g);
  k_phaseB3<<<dim3(8,32), 256, 0, stream>>>(PgH, PgL, Bg, S0g);
  k_phaseC<<<dim3(64,16,2), 256, 0, stream>>>(qh, ql, kh, kl, gfb, logA, S0g, Wg, Dg, rms_w, yh, yl);

  k_gemm3<<<dim3(64,8), 256, 0, stream>>>(yh, yl, woh, wol, nullptr, (float*)d_out);
}